// Round 10
// baseline (3865.726 us; speedup 1.0000x reference)
//
#include <hip/hip_runtime.h>

#define B_ 2
#define N_ 8192
#define D_ 96
#define L_ 4
#define H_ 192
#define K_ 16
#define NC_ 2
#define EPS_ 1e-5f
#define BIGF 3.402823466e38f

__device__ __forceinline__ float bn1(float x, float g, float b, float m, float v) {
  return (x - m) * (g * (1.0f / sqrtf(v + EPS_))) + b;
}

// ---------------- embed + per-point squared norm ----------------
__global__ void k_embed(const float* __restrict__ pts, const float* __restrict__ w,
                        const float* __restrict__ g, const float* __restrict__ bb,
                        const float* __restrict__ m, const float* __restrict__ v,
                        float* __restrict__ X, float* __restrict__ SQ) {
  int gid = blockIdx.x * 256 + threadIdx.x;
  int b = gid / N_, n = gid % N_;
  float p0 = pts[gid * 3], p1 = pts[gid * 3 + 1], p2 = pts[gid * 3 + 2];
  // exact numpy-order fp32 arithmetic (feeds KNN selection)
  SQ[gid] = __fadd_rn(__fadd_rn(__fmul_rn(p0, p0), __fmul_rn(p1, p1)), __fmul_rn(p2, p2));
  for (int o = 0; o < D_; ++o) {
    float e = w[o * 3] * p0 + w[o * 3 + 1] * p1 + w[o * 3 + 2] * p2;
    X[(b * D_ + o) * N_ + n] = fmaxf(bn1(e, g[o], bb[o], m[o], v[o]), 0.0f);
  }
}

// ---------------- KNN: one wave per query, top-16 by (dist, idx) ----------------
__global__ void k_knn(const float* __restrict__ pts, const float* __restrict__ SQ,
                      int* __restrict__ IDX) {
  int lane = threadIdx.x & 63;
  int g = blockIdx.x * 4 + (threadIdx.x >> 6);
  int b = g / N_, n = g % N_;
  const float* pb = pts + b * N_ * 3;
  const float* sqb = SQ + b * N_;
  float qx = pb[n * 3], qy = pb[n * 3 + 1], qz = pb[n * 3 + 2];
  float sqn = sqb[n];
  float bd[K_]; int bi[K_];
#pragma unroll
  for (int s = 0; s < K_; ++s) { bd[s] = BIGF; bi[s] = 0x7fffffff; }
  float wd = BIGF; int wi = 0x7fffffff; int wslot = 0;
  for (int j = 0; j < N_ / 64; ++j) {
    int cand = lane + j * 64;
    const float* pc = pb + cand * 3;
    float px = pc[0], py = pc[1], pz = pc[2];
    float dot = __fadd_rn(__fadd_rn(__fmul_rn(qx, px), __fmul_rn(qy, py)), __fmul_rn(qz, pz));
    float d = __fsub_rn(__fadd_rn(sqn, sqb[cand]), __fmul_rn(2.0f, dot));
    if (d < wd || (d == wd && cand < wi)) {
#pragma unroll
      for (int s = 0; s < K_; ++s) if (s == wslot) { bd[s] = d; bi[s] = cand; }
      wd = -BIGF; wi = -1;
#pragma unroll
      for (int s = 0; s < K_; ++s) {
        bool worse = (bd[s] > wd) || (bd[s] == wd && bi[s] > wi);
        if (worse) { wd = bd[s]; wi = bi[s]; wslot = s; }
      }
    }
  }
  // merge 64 lanes' top-16 -> global top-16 (ascending (d, idx), matches stable top_k)
  for (int r = 0; r < K_; ++r) {
    float md = BIGF; int mi = 0x7fffffff;
#pragma unroll
    for (int s = 0; s < K_; ++s) {
      bool better = (bd[s] < md) || (bd[s] == md && bi[s] < mi);
      if (better) { md = bd[s]; mi = bi[s]; }
    }
#pragma unroll
    for (int off = 32; off > 0; off >>= 1) {
      float od = __shfl_xor(md, off);
      int oi = __shfl_xor(mi, off);
      bool better = (od < md) || (od == md && oi < mi);
      if (better) { md = od; mi = oi; }
    }
#pragma unroll
    for (int s = 0; s < K_; ++s) if (bi[s] == mi) { bd[s] = BIGF; bi[s] = 0x7fffffff; }
    if (lane == 0) IDX[g * K_ + r] = mi;
  }
}

// ---------------- QKV: thread-per-point, x column in registers ----------------
__global__ void k_qkv(const float* __restrict__ X, const float* __restrict__ wq,
                      const float* __restrict__ wk, const float* __restrict__ wv,
                      float* __restrict__ QT, float* __restrict__ KT, float* __restrict__ VT) {
  int gid = blockIdx.x * 256 + threadIdx.x;
  int b = gid / N_, n = gid % N_;
  const float* xb = X + b * D_ * N_ + n;
  float xr[D_];
#pragma unroll
  for (int c = 0; c < D_; ++c) xr[c] = xb[c * N_];
  float* qo = QT + (size_t)gid * D_;
  float* ko = KT + (size_t)gid * D_;
  float* vo = VT + (size_t)gid * D_;
  for (int o = 0; o < D_; ++o) {
    float aq = 0.f, ak = 0.f, av = 0.f;
#pragma unroll
    for (int c = 0; c < D_; ++c) {
      float xv = xr[c];
      aq += wq[o * D_ + c] * xv;
      ak += wk[o * D_ + c] * xv;
      av += wv[o * D_ + c] * xv;
    }
    qo[o] = aq; ko[o] = ak; vo[o] = av;
  }
}

// 96x96 weight (global) times 96x16 tile (LDS); this thread produces rows r and r+48.
__device__ __forceinline__ void gemm2(const float* __restrict__ W, int r, const float* bin,
                                      float acc0[K_], float acc1[K_]) {
#pragma unroll
  for (int k = 0; k < K_; ++k) { acc0[k] = 0.f; acc1[k] = 0.f; }
  for (int c4 = 0; c4 < D_; c4 += 4) {
    float4 wa = *(const float4*)(W + r * D_ + c4);
    float4 wb = *(const float4*)(W + (r + 48) * D_ + c4);
    const float* wav = (const float*)&wa;
    const float* wbv = (const float*)&wb;
#pragma unroll
    for (int u = 0; u < 4; ++u) {
      float A = wav[u], Bv = wbv[u];
      const float4* ip = (const float4*)(bin + (c4 + u) * K_);
#pragma unroll
      for (int q = 0; q < 4; ++q) {
        float4 iv = ip[q];
        acc0[4 * q + 0] += A * iv.x;  acc0[4 * q + 1] += A * iv.y;
        acc0[4 * q + 2] += A * iv.z;  acc0[4 * q + 3] += A * iv.w;
        acc1[4 * q + 0] += Bv * iv.x; acc1[4 * q + 1] += Bv * iv.y;
        acc1[4 * q + 2] += Bv * iv.z; acc1[4 * q + 3] += Bv * iv.w;
      }
    }
  }
}

// ---------------- fused attention block: 4 points/block, 192 threads ----------------
__global__ void __launch_bounds__(192) k_attn(
    float* __restrict__ X, const float* __restrict__ QT, const float* __restrict__ KT,
    const float* __restrict__ VT, const float* __restrict__ pts, const int* __restrict__ IDX,
    const float* __restrict__ pw1, const float* __restrict__ pg, const float* __restrict__ pb_,
    const float* __restrict__ pm, const float* __restrict__ pv, const float* __restrict__ pw2,
    const float* __restrict__ aw1, const float* __restrict__ ag, const float* __restrict__ ab,
    const float* __restrict__ am, const float* __restrict__ av, const float* __restrict__ aw2,
    const float* __restrict__ g1, const float* __restrict__ b1, const float* __restrict__ m1,
    const float* __restrict__ v1) {
  __shared__ __align__(16) float bufA[4][D_ * K_];
  __shared__ __align__(16) float bufP[4][D_ * K_];
  __shared__ float pd[4][3 * K_];
  __shared__ int sid[4][K_];
  int tid = threadIdx.x;
  int p = tid / 48, r = tid % 48;
  int g = blockIdx.x * 4 + p;
  int b = g / N_, n = g % N_;

  // phase A: neighbor ids + pos_diff
  if (r < K_) {
    int nbr = IDX[g * K_ + r];
    sid[p][r] = nbr;
    const float* pq = pts + (b * N_ + n) * 3;
    const float* pn = pts + (b * N_ + nbr) * 3;
    pd[p][r]          = pq[0] - pn[0];
    pd[p][K_ + r]     = pq[1] - pn[1];
    pd[p][2 * K_ + r] = pq[2] - pn[2];
  }
  __syncthreads();

  // phase B: pe1 = pw1 @ pos_diff ; bn ; relu -> bufA
#pragma unroll
  for (int h = 0; h < 2; ++h) {
    int rr = r + h * 48;
    float w0 = pw1[rr * 3], w1 = pw1[rr * 3 + 1], w2 = pw1[rr * 3 + 2];
    float sc = pg[rr] * (1.0f / sqrtf(pv[rr] + EPS_));
    float mm = pm[rr], bo = pb_[rr];
#pragma unroll
    for (int k4 = 0; k4 < K_; k4 += 4) {
      float4 o; float* ov = (float*)&o;
#pragma unroll
      for (int u = 0; u < 4; ++u) {
        int k = k4 + u;
        float val = w0 * pd[p][k] + w1 * pd[p][K_ + k] + w2 * pd[p][2 * K_ + k];
        ov[u] = fmaxf((val - mm) * sc + bo, 0.0f);
      }
      *(float4*)&bufA[p][rr * K_ + k4] = o;
    }
  }
  __syncthreads();

  // phase C: pe2 = pw2 @ bufA
  float acc0[K_], acc1[K_];
  gemm2(pw2, r, bufA[p], acc0, acc1);
  __syncthreads();

  // phase D: bufP = pe2 ; bufA = q - k_nn + pe2
  {
    float qv0 = QT[(size_t)g * D_ + r];
    float qv1 = QT[(size_t)g * D_ + r + 48];
#pragma unroll
    for (int k4 = 0; k4 < K_; k4 += 4) {
      *(float4*)&bufP[p][r * K_ + k4]        = make_float4(acc0[k4], acc0[k4 + 1], acc0[k4 + 2], acc0[k4 + 3]);
      *(float4*)&bufP[p][(r + 48) * K_ + k4] = make_float4(acc1[k4], acc1[k4 + 1], acc1[k4 + 2], acc1[k4 + 3]);
    }
#pragma unroll
    for (int k = 0; k < K_; ++k) {
      int nbr = sid[p][k];
      const float* kt = KT + (size_t)(b * N_ + nbr) * D_;
      bufA[p][r * K_ + k]        = qv0 - kt[r] + acc0[k];
      bufA[p][(r + 48) * K_ + k] = qv1 - kt[r + 48] + acc1[k];
    }
  }
  __syncthreads();

  // phase E: t = aw1 @ bufA  (then bn+relu back into bufA)
  gemm2(aw1, r, bufA[p], acc0, acc1);
  __syncthreads();
#pragma unroll
  for (int h = 0; h < 2; ++h) {
    int rr = r + h * 48;
    float sc = ag[rr] * (1.0f / sqrtf(av[rr] + EPS_));
    float mm = am[rr], bo = ab[rr];
    float* ac = h ? acc1 : acc0;
#pragma unroll
    for (int k4 = 0; k4 < K_; k4 += 4) {
      float4 o; float* ov = (float*)&o;
#pragma unroll
      for (int u = 0; u < 4; ++u) ov[u] = fmaxf((ac[k4 + u] - mm) * sc + bo, 0.0f);
      *(float4*)&bufA[p][rr * K_ + k4] = o;
    }
  }
  __syncthreads();

  // phase F: a2 = aw2 @ bufA ; softmax over k ; out ; residual + bn -> X
  gemm2(aw2, r, bufA[p], acc0, acc1);
#pragma unroll
  for (int h = 0; h < 2; ++h) {
    int rr = r + h * 48;
    float* s = h ? acc1 : acc0;
    float mx = s[0];
#pragma unroll
    for (int k = 1; k < K_; ++k) mx = fmaxf(mx, s[k]);
    float sum = 0.f;
#pragma unroll
    for (int k = 0; k < K_; ++k) { s[k] = expf(s[k] - mx); sum += s[k]; }
    float inv = 1.0f / sum;
    float out = 0.f;
#pragma unroll
    for (int k = 0; k < K_; ++k) {
      int nbr = sid[p][k];
      out += s[k] * (VT[(size_t)(b * N_ + nbr) * D_ + rr] + bufP[p][rr * K_ + k]);
    }
    out *= inv;
    float t = X[(b * D_ + rr) * N_ + n] + out;
    X[(b * D_ + rr) * N_ + n] = (t - m1[rr]) * (g1[rr] * (1.0f / sqrtf(v1[rr] + EPS_))) + b1[rr];
  }
}

// ---------------- FFN: 2 points/block ----------------
__global__ void __launch_bounds__(192) k_ffn(
    float* __restrict__ X, const float* __restrict__ w1, const float* __restrict__ fg,
    const float* __restrict__ fb, const float* __restrict__ fm, const float* __restrict__ fv,
    const float* __restrict__ w2, const float* __restrict__ g2, const float* __restrict__ b2,
    const float* __restrict__ m2, const float* __restrict__ v2) {
  __shared__ __align__(16) float xc[2][D_];
  __shared__ __align__(16) float hbuf[2][H_];
  int tid = threadIdx.x;
  int p = tid / D_, r = tid % D_;
  int g = blockIdx.x * 2 + p;
  int b = g / N_, n = g % N_;
  xc[p][r] = X[(b * D_ + r) * N_ + n];
  __syncthreads();
#pragma unroll
  for (int h = 0; h < 2; ++h) {
    int j = r + h * D_;
    float acc = 0.f;
#pragma unroll
    for (int c4 = 0; c4 < D_; c4 += 4) {
      float4 wv4 = *(const float4*)(w1 + j * D_ + c4);
      float4 xv4 = *(const float4*)&xc[p][c4];
      acc += wv4.x * xv4.x + wv4.y * xv4.y + wv4.z * xv4.z + wv4.w * xv4.w;
    }
    hbuf[p][j] = fmaxf(bn1(acc, fg[j], fb[j], fm[j], fv[j]), 0.0f);
  }
  __syncthreads();
  float acc = 0.f;
#pragma unroll
  for (int j4 = 0; j4 < H_; j4 += 4) {
    float4 wv4 = *(const float4*)(w2 + r * H_ + j4);
    float4 hv4 = *(const float4*)&hbuf[p][j4];
    acc += wv4.x * hv4.x + wv4.y * hv4.y + wv4.z * hv4.z + wv4.w * hv4.w;
  }
  float t = xc[p][r] + acc;
  X[(b * D_ + r) * N_ + n] = (t - m2[r]) * (g2[r] * (1.0f / sqrtf(v2[r] + EPS_))) + b2[r];
}

// ---------------- head ----------------
__global__ void k_head(const float* __restrict__ X, const float* __restrict__ w1,
                       const float* __restrict__ hg, const float* __restrict__ hbb,
                       const float* __restrict__ hm, const float* __restrict__ hv,
                       const float* __restrict__ w2, const float* __restrict__ hb2,
                       float* __restrict__ OUT) {
  int gid = blockIdx.x * 256 + threadIdx.x;
  int b = gid / N_, n = gid % N_;
  const float* xb = X + b * D_ * N_ + n;
  float xr[D_];
#pragma unroll
  for (int c = 0; c < D_; ++c) xr[c] = xb[c * N_];
  float a0 = 0.f, a1 = 0.f;
  for (int j = 0; j < 128; ++j) {
    float acc = 0.f;
#pragma unroll
    for (int c = 0; c < D_; ++c) acc += w1[j * D_ + c] * xr[c];
    float t = fmaxf((acc - hm[j]) * (hg[j] * (1.0f / sqrtf(hv[j] + EPS_))) + hbb[j], 0.0f);
    a0 += w2[j] * t;
    a1 += w2[128 + j] * t;
  }
  OUT[(b * NC_ + 0) * N_ + n] = a0 + hb2[0];
  OUT[(b * NC_ + 1) * N_ + n] = a1 + hb2[1];
}

extern "C" void kernel_launch(void* const* d_in, const int* in_sizes, int n_in,
                              void* d_out, int out_size, void* d_ws, size_t ws_size,
                              hipStream_t stream) {
  (void)in_sizes; (void)n_in; (void)out_size;
  const float* pts     = (const float*)d_in[0];
  const float* embed_w = (const float*)d_in[1];
  const float* embed_g = (const float*)d_in[2];
  const float* embed_b = (const float*)d_in[3];
  const float* embed_m = (const float*)d_in[4];
  const float* embed_v = (const float*)d_in[5];
  const float* wq      = (const float*)d_in[6];
  const float* wk      = (const float*)d_in[7];
  const float* wv      = (const float*)d_in[8];
  const float* pe_w1   = (const float*)d_in[9];
  const float* pe_g    = (const float*)d_in[10];
  const float* pe_b    = (const float*)d_in[11];
  const float* pe_m    = (const float*)d_in[12];
  const float* pe_v    = (const float*)d_in[13];
  const float* pe_w2   = (const float*)d_in[14];
  const float* am_w1   = (const float*)d_in[15];
  const float* am_g    = (const float*)d_in[16];
  const float* am_b    = (const float*)d_in[17];
  const float* am_m    = (const float*)d_in[18];
  const float* am_v    = (const float*)d_in[19];
  const float* am_w2   = (const float*)d_in[20];
  const float* n1_g    = (const float*)d_in[21];
  const float* n1_b    = (const float*)d_in[22];
  const float* n1_m    = (const float*)d_in[23];
  const float* n1_v    = (const float*)d_in[24];
  const float* ffn_w1  = (const float*)d_in[25];
  const float* f_g     = (const float*)d_in[26];
  const float* f_b     = (const float*)d_in[27];
  const float* f_m     = (const float*)d_in[28];
  const float* f_v     = (const float*)d_in[29];
  const float* ffn_w2  = (const float*)d_in[30];
  const float* n2_g    = (const float*)d_in[31];
  const float* n2_b    = (const float*)d_in[32];
  const float* n2_m    = (const float*)d_in[33];
  const float* n2_v    = (const float*)d_in[34];
  const float* hd_w1   = (const float*)d_in[35];
  const float* hd_g    = (const float*)d_in[36];
  const float* hd_b    = (const float*)d_in[37];
  const float* hd_m    = (const float*)d_in[38];
  const float* hd_v    = (const float*)d_in[39];
  const float* hd_w2   = (const float*)d_in[40];
  const float* hd_b2   = (const float*)d_in[41];

  // ws budget: 4*B*D*N + B*N + B*N*K floats = 26,279,936 B (proven to fit in rounds 1/5)
  const size_t NEED = (size_t)(4 * B_ * D_ * N_ + B_ * N_ + B_ * N_ * K_) * 4;
  if (ws_size < NEED) return;  // diagnostic guard: clean absmax-fail instead of UB

  float* ws = (float*)d_ws;
  float* X  = ws;
  float* QT = X  + (size_t)B_ * D_ * N_;
  float* KT = QT + (size_t)B_ * N_ * D_;
  float* VT = KT + (size_t)B_ * N_ * D_;
  float* SQ = VT + (size_t)B_ * N_ * D_;
  int*   IDX = (int*)(SQ + (size_t)B_ * N_);

  k_embed<<<B_ * N_ / 256, 256, 0, stream>>>(pts, embed_w, embed_g, embed_b, embed_m, embed_v, X, SQ);
  k_knn<<<B_ * N_ / 4, 256, 0, stream>>>(pts, SQ, IDX);
  for (int l = 0; l < L_; ++l) {
    k_qkv<<<B_ * N_ / 256, 256, 0, stream>>>(X, wq + l * D_ * D_, wk + l * D_ * D_, wv + l * D_ * D_, QT, KT, VT);
    k_attn<<<B_ * N_ / 4, 192, 0, stream>>>(X, QT, KT, VT, pts, IDX,
        pe_w1 + l * D_ * 3, pe_g + l * D_, pe_b + l * D_, pe_m + l * D_, pe_v + l * D_, pe_w2 + l * D_ * D_,
        am_w1 + l * D_ * D_, am_g + l * D_, am_b + l * D_, am_m + l * D_, am_v + l * D_, am_w2 + l * D_ * D_,
        n1_g + l * D_, n1_b + l * D_, n1_m + l * D_, n1_v + l * D_);
    k_ffn<<<B_ * N_ / 2, 192, 0, stream>>>(X, ffn_w1 + l * H_ * D_, f_g + l * H_, f_b + l * H_, f_m + l * H_, f_v + l * H_,
        ffn_w2 + l * D_ * H_, n2_g + l * D_, n2_b + l * D_, n2_m + l * D_, n2_v + l * D_);
  }
  k_head<<<B_ * N_ / 256, 256, 0, stream>>>(X, hd_w1, hd_g, hd_b, hd_m, hd_v, hd_w2, hd_b2, (float*)d_out);
}

// Round 12
// 3468.273 us; speedup vs baseline: 1.1146x; 1.1146x over previous
//
#include <hip/hip_runtime.h>

#define B_ 2
#define N_ 8192
#define D_ 96
#define L_ 4
#define H_ 192
#define K_ 16
#define NC_ 2
#define EPS_ 1e-5f
#define BIGF 3.402823466e38f
#define TSTR 104  // padded LDS tile stride (fp16 elems): 8-aligned for b128, non-pow2 bank spread

typedef _Float16 half8 __attribute__((ext_vector_type(8)));
typedef float f32x4 __attribute__((ext_vector_type(4)));

__device__ __forceinline__ float bn1(float x, float g, float b, float m, float v) {
  return (x - m) * (g * (1.0f / sqrtf(v + EPS_))) + b;
}

__device__ __forceinline__ unsigned short f2h(float x) {
  union { _Float16 h; unsigned short u; } c;
  c.h = (_Float16)x;
  return c.u;
}

// ---------------- embed + per-point squared norm (byte-identical to proven baseline) ----------
__global__ void k_embed(const float* __restrict__ pts, const float* __restrict__ w,
                        const float* __restrict__ g, const float* __restrict__ bb,
                        const float* __restrict__ m, const float* __restrict__ v,
                        float* __restrict__ X, float* __restrict__ SQ) {
  int gid = blockIdx.x * 256 + threadIdx.x;
  int b = gid / N_, n = gid % N_;
  float p0 = pts[gid * 3], p1 = pts[gid * 3 + 1], p2 = pts[gid * 3 + 2];
  // exact numpy-order fp32 arithmetic (feeds KNN selection)
  SQ[gid] = __fadd_rn(__fadd_rn(__fmul_rn(p0, p0), __fmul_rn(p1, p1)), __fmul_rn(p2, p2));
  for (int o = 0; o < D_; ++o) {
    float e = w[o * 3] * p0 + w[o * 3 + 1] * p1 + w[o * 3 + 2] * p2;
    X[(b * D_ + o) * N_ + n] = fmaxf(bn1(e, g[o], bb[o], m[o], v[o]), 0.0f);
  }
}

// ---------------- KNN: proven baseline version (frozen) ----------------
__global__ void k_knn(const float* __restrict__ pts, const float* __restrict__ SQ,
                      int* __restrict__ IDX) {
  int lane = threadIdx.x & 63;
  int g = blockIdx.x * 4 + (threadIdx.x >> 6);
  int b = g / N_, n = g % N_;
  const float* pb = pts + b * N_ * 3;
  const float* sqb = SQ + b * N_;
  float qx = pb[n * 3], qy = pb[n * 3 + 1], qz = pb[n * 3 + 2];
  float sqn = sqb[n];
  float bd[K_]; int bi[K_];
#pragma unroll
  for (int s = 0; s < K_; ++s) { bd[s] = BIGF; bi[s] = 0x7fffffff; }
  float wd = BIGF; int wi = 0x7fffffff; int wslot = 0;
  for (int j = 0; j < N_ / 64; ++j) {
    int cand = lane + j * 64;
    const float* pc = pb + cand * 3;
    float px = pc[0], py = pc[1], pz = pc[2];
    float dot = __fadd_rn(__fadd_rn(__fmul_rn(qx, px), __fmul_rn(qy, py)), __fmul_rn(qz, pz));
    float d = __fsub_rn(__fadd_rn(sqn, sqb[cand]), __fmul_rn(2.0f, dot));
    if (d < wd || (d == wd && cand < wi)) {
#pragma unroll
      for (int s = 0; s < K_; ++s) if (s == wslot) { bd[s] = d; bi[s] = cand; }
      wd = -BIGF; wi = -1;
#pragma unroll
      for (int s = 0; s < K_; ++s) {
        bool worse = (bd[s] > wd) || (bd[s] == wd && bi[s] > wi);
        if (worse) { wd = bd[s]; wi = bi[s]; wslot = s; }
      }
    }
  }
  for (int r = 0; r < K_; ++r) {
    float md = BIGF; int mi = 0x7fffffff;
#pragma unroll
    for (int s = 0; s < K_; ++s) {
      bool better = (bd[s] < md) || (bd[s] == md && bi[s] < mi);
      if (better) { md = bd[s]; mi = bi[s]; }
    }
#pragma unroll
    for (int off = 32; off > 0; off >>= 1) {
      float od = __shfl_xor(md, off);
      int oi = __shfl_xor(mi, off);
      bool better = (od < md) || (od == md && oi < mi);
      if (better) { md = od; mi = oi; }
    }
#pragma unroll
    for (int s = 0; s < K_; ++s) if (bi[s] == mi) { bd[s] = BIGF; bi[s] = 0x7fffffff; }
    if (lane == 0) IDX[g * K_ + r] = mi;
  }
}

// ---------------- per-layer weight prep: fp32 -> fp16 into SQ's dead space ----------------
__global__ void k_prep_wl(const float* __restrict__ pw2, const float* __restrict__ aw1,
                          const float* __restrict__ aw2, unsigned short* __restrict__ WH) {
  int i = blockIdx.x * 256 + threadIdx.x;  // 9216 = D_*D_; grid 36
  WH[i]         = f2h(pw2[i]);
  WH[9216 + i]  = f2h(aw1[i]);
  WH[18432 + i] = f2h(aw2[i]);
}

// ---------------- QKV: proven baseline version ----------------
__global__ void k_qkv(const float* __restrict__ X, const float* __restrict__ wq,
                      const float* __restrict__ wk, const float* __restrict__ wv,
                      float* __restrict__ QT, float* __restrict__ KT, float* __restrict__ VT) {
  int gid = blockIdx.x * 256 + threadIdx.x;
  int b = gid / N_, n = gid % N_;
  const float* xb = X + b * D_ * N_ + n;
  float xr[D_];
#pragma unroll
  for (int c = 0; c < D_; ++c) xr[c] = xb[c * N_];
  float* qo = QT + (size_t)gid * D_;
  float* ko = KT + (size_t)gid * D_;
  float* vo = VT + (size_t)gid * D_;
  for (int o = 0; o < D_; ++o) {
    float aq = 0.f, ak = 0.f, av = 0.f;
#pragma unroll
    for (int c = 0; c < D_; ++c) {
      float xv = xr[c];
      aq += wq[o * D_ + c] * xv;
      ak += wk[o * D_ + c] * xv;
      av += wv[o * D_ + c] * xv;
    }
    qo[o] = aq; ko[o] = ak; vo[o] = av;
  }
}

// W(16x32 rows of m-tile) @ Act(32x16) over 3 K-steps, 6 m-tiles; fp16 in, fp32 out.
// A frag: row = lane&15, k = s*32 + (lane>>4)*8 + j   (row-major fp16 W, stride 96)
// B frag: col(slot) = lane&15, k likewise; tile stored [slot][k], stride TSTR
// D frag: col(slot) = lane&15, row(channel) = m*16 + (lane>>4)*4 + r
__device__ __forceinline__ void mfma_stage(const unsigned short* __restrict__ Wh,
                                           const unsigned short* tw,
                                           int n16, int q4, f32x4 acc[6]) {
  half8 bfr[3];
#pragma unroll
  for (int s = 0; s < 3; ++s)
    bfr[s] = *(const half8*)&tw[n16 * TSTR + s * 32 + q4 * 8];
#pragma unroll
  for (int m = 0; m < 6; ++m) {
#pragma unroll
    for (int s = 0; s < 3; ++s) {
      half8 av = *(const half8*)&Wh[(m * 16 + n16) * 96 + s * 32 + q4 * 8];
      acc[m] = __builtin_amdgcn_mfma_f32_16x16x32_f16(av, bfr[s], acc[m], 0, 0, 0);
    }
  }
}

// ---------------- fused attention: 1 wave per point, 4 points/block, MFMA ----------------
__global__ void __launch_bounds__(256) k_attn(
    float* __restrict__ X, const float* __restrict__ QT, const float* __restrict__ KT,
    const float* __restrict__ VT, const float* __restrict__ pts, const int* __restrict__ IDX,
    const float* __restrict__ pw1, const float* __restrict__ pg, const float* __restrict__ pb_,
    const float* __restrict__ pm, const float* __restrict__ pv,
    const unsigned short* __restrict__ WH,
    const float* __restrict__ ag, const float* __restrict__ ab,
    const float* __restrict__ am, const float* __restrict__ av,
    const float* __restrict__ g1, const float* __restrict__ b1,
    const float* __restrict__ m1, const float* __restrict__ v1) {
  __shared__ __align__(16) unsigned short tile[4][16 * TSTR];
  __shared__ float pdif[4][3][16];
  __shared__ int sid[4][16];
  const int tid = threadIdx.x;
  const int l = tid & 63, w = tid >> 6;
  const int g = blockIdx.x * 4 + w;
  const int b = g >> 13, n = g & (N_ - 1);
  const int n16 = l & 15, q4 = l >> 4;
  unsigned short* tw = &tile[w][0];

  // phase A: neighbor ids + pos_diff
  if (l < 16) {
    int nbr = IDX[g * K_ + l];
    sid[w][l] = nbr;
    const float* pq = pts + ((size_t)b * N_ + n) * 3;
    const float* pn = pts + ((size_t)b * N_ + nbr) * 3;
    pdif[w][0][l] = pq[0] - pn[0];
    pdif[w][1][l] = pq[1] - pn[1];
    pdif[w][2][l] = pq[2] - pn[2];
  }
  __syncthreads();

  // phase B: tile[slot][c] = relu(bn_pe(pe_w1 @ pos_diff)) as fp16; lane covers c = q4*24..+23
  {
    float p0 = pdif[w][0][n16], p1 = pdif[w][1][n16], p2 = pdif[w][2][n16];
    int c0 = q4 * 24;
#pragma unroll
    for (int ii = 0; ii < 24; ii += 2) {
      int c = c0 + ii;
      float vA = pw1[c * 3] * p0 + pw1[c * 3 + 1] * p1 + pw1[c * 3 + 2] * p2;
      float vB = pw1[(c + 1) * 3] * p0 + pw1[(c + 1) * 3 + 1] * p1 + pw1[(c + 1) * 3 + 2] * p2;
      vA = fmaxf(bn1(vA, pg[c], pb_[c], pm[c], pv[c]), 0.f);
      vB = fmaxf(bn1(vB, pg[c + 1], pb_[c + 1], pm[c + 1], pv[c + 1]), 0.f);
      unsigned u = (unsigned)f2h(vA) | ((unsigned)f2h(vB) << 16);
      *(unsigned*)&tw[n16 * TSTR + c] = u;
    }
  }
  __syncthreads();

  // phase C: pe2 = pw2 @ tile (registers, D-frag layout)
  f32x4 pe2[6];
#pragma unroll
  for (int m = 0; m < 6; ++m) pe2[m] = (f32x4){0.f, 0.f, 0.f, 0.f};
  mfma_stage(WH, tw, n16, q4, pe2);
  __syncthreads();

  // phase D: tile = q - k_nn + pe2 (fp16)
  const int nbr = sid[w][n16];
  {
    const float* qt = QT + (size_t)g * 96;
    const float* kt = KT + ((size_t)b * N_ + nbr) * 96;
#pragma unroll
    for (int m = 0; m < 6; ++m) {
      int cb = m * 16 + q4 * 4;
      float4 qv = *(const float4*)&qt[cb];
      float4 kv = *(const float4*)&kt[cb];
      float v0 = qv.x - kv.x + pe2[m][0];
      float v1 = qv.y - kv.y + pe2[m][1];
      float v2 = qv.z - kv.z + pe2[m][2];
      float v3 = qv.w - kv.w + pe2[m][3];
      int idx = n16 * TSTR + cb;
      *(unsigned*)&tw[idx]     = (unsigned)f2h(v0) | ((unsigned)f2h(v1) << 16);
      *(unsigned*)&tw[idx + 2] = (unsigned)f2h(v2) | ((unsigned)f2h(v3) << 16);
    }
  }
  __syncthreads();

  // phase E: t1 = aw1 @ tile ; tile = relu(bn_am(t1))
  {
    f32x4 t1[6];
#pragma unroll
    for (int m = 0; m < 6; ++m) t1[m] = (f32x4){0.f, 0.f, 0.f, 0.f};
    mfma_stage(WH + 9216, tw, n16, q4, t1);
    __syncthreads();
#pragma unroll
    for (int m = 0; m < 6; ++m) {
      int cb = m * 16 + q4 * 4;
      float v0 = fmaxf(bn1(t1[m][0], ag[cb], ab[cb], am[cb], av[cb]), 0.f);
      float v1 = fmaxf(bn1(t1[m][1], ag[cb + 1], ab[cb + 1], am[cb + 1], av[cb + 1]), 0.f);
      float v2 = fmaxf(bn1(t1[m][2], ag[cb + 2], ab[cb + 2], am[cb + 2], av[cb + 2]), 0.f);
      float v3 = fmaxf(bn1(t1[m][3], ag[cb + 3], ab[cb + 3], am[cb + 3], av[cb + 3]), 0.f);
      int idx = n16 * TSTR + cb;
      *(unsigned*)&tw[idx]     = (unsigned)f2h(v0) | ((unsigned)f2h(v1) << 16);
      *(unsigned*)&tw[idx + 2] = (unsigned)f2h(v2) | ((unsigned)f2h(v3) << 16);
    }
  }
  __syncthreads();

  // phase F: a2 = aw2 @ tile ; softmax over slots (16-lane groups) ; out ; residual+bn -> X
  {
    f32x4 a2[6];
#pragma unroll
    for (int m = 0; m < 6; ++m) a2[m] = (f32x4){0.f, 0.f, 0.f, 0.f};
    mfma_stage(WH + 18432, tw, n16, q4, a2);
    const float* vt = VT + ((size_t)b * N_ + nbr) * 96;
#pragma unroll
    for (int m = 0; m < 6; ++m) {
      int cb = m * 16 + q4 * 4;
      float4 vv = *(const float4*)&vt[cb];
      const float* vvp = (const float*)&vv;
      float ov[4];
#pragma unroll
      for (int r = 0; r < 4; ++r) {
        float a = a2[m][r];
        float mx = a;
        mx = fmaxf(mx, __shfl_xor(mx, 1));
        mx = fmaxf(mx, __shfl_xor(mx, 2));
        mx = fmaxf(mx, __shfl_xor(mx, 4));
        mx = fmaxf(mx, __shfl_xor(mx, 8));
        float e = expf(a - mx);
        float s = e;
        s += __shfl_xor(s, 1); s += __shfl_xor(s, 2); s += __shfl_xor(s, 4); s += __shfl_xor(s, 8);
        float c = e * (vvp[r] + pe2[m][r]);
        c += __shfl_xor(c, 1); c += __shfl_xor(c, 2); c += __shfl_xor(c, 4); c += __shfl_xor(c, 8);
        ov[r] = c / s;
      }
      if (n16 == 0) {
#pragma unroll
        for (int r = 0; r < 4; ++r) {
          int c = cb + r;
          size_t xi = ((size_t)b * D_ + c) * N_ + n;
          float t = X[xi] + ov[r];
          X[xi] = (t - m1[c]) * (g1[c] * (1.0f / sqrtf(v1[c] + EPS_))) + b1[c];
        }
      }
    }
  }
}

// ---------------- FFN: proven baseline version ----------------
__global__ void __launch_bounds__(192) k_ffn(
    float* __restrict__ X, const float* __restrict__ w1, const float* __restrict__ fg,
    const float* __restrict__ fb, const float* __restrict__ fm, const float* __restrict__ fv,
    const float* __restrict__ w2, const float* __restrict__ g2, const float* __restrict__ b2,
    const float* __restrict__ m2, const float* __restrict__ v2) {
  __shared__ __align__(16) float xc[2][D_];
  __shared__ __align__(16) float hbuf[2][H_];
  int tid = threadIdx.x;
  int p = tid / D_, r = tid % D_;
  int g = blockIdx.x * 2 + p;
  int b = g / N_, n = g % N_;
  xc[p][r] = X[(b * D_ + r) * N_ + n];
  __syncthreads();
#pragma unroll
  for (int h = 0; h < 2; ++h) {
    int j = r + h * D_;
    float acc = 0.f;
#pragma unroll
    for (int c4 = 0; c4 < D_; c4 += 4) {
      float4 wv4 = *(const float4*)(w1 + j * D_ + c4);
      float4 xv4 = *(const float4*)&xc[p][c4];
      acc += wv4.x * xv4.x + wv4.y * xv4.y + wv4.z * xv4.z + wv4.w * xv4.w;
    }
    hbuf[p][j] = fmaxf(bn1(acc, fg[j], fb[j], fm[j], fv[j]), 0.0f);
  }
  __syncthreads();
  float acc = 0.f;
#pragma unroll
  for (int j4 = 0; j4 < H_; j4 += 4) {
    float4 wv4 = *(const float4*)(w2 + r * H_ + j4);
    float4 hv4 = *(const float4*)&hbuf[p][j4];
    acc += wv4.x * hv4.x + wv4.y * hv4.y + wv4.z * hv4.z + wv4.w * hv4.w;
  }
  float t = xc[p][r] + acc;
  X[(b * D_ + r) * N_ + n] = bn1(t, g2[r], b2[r], m2[r], v2[r]);
}

// ---------------- head: proven baseline version ----------------
__global__ void k_head(const float* __restrict__ X, const float* __restrict__ w1,
                       const float* __restrict__ hg, const float* __restrict__ hbb,
                       const float* __restrict__ hm, const float* __restrict__ hv,
                       const float* __restrict__ w2, const float* __restrict__ hb2,
                       float* __restrict__ OUT) {
  int gid = blockIdx.x * 256 + threadIdx.x;
  int b = gid / N_, n = gid % N_;
  const float* xb = X + b * D_ * N_ + n;
  float xr[D_];
#pragma unroll
  for (int c = 0; c < D_; ++c) xr[c] = xb[c * N_];
  float a0 = 0.f, a1 = 0.f;
  for (int j = 0; j < 128; ++j) {
    float acc = 0.f;
#pragma unroll
    for (int c = 0; c < D_; ++c) acc += w1[j * D_ + c] * xr[c];
    float t = fmaxf(bn1(acc, hg[j], hbb[j], hm[j], hv[j]), 0.0f);
    a0 += w2[j] * t;
    a1 += w2[128 + j] * t;
  }
  OUT[(b * NC_ + 0) * N_ + n] = a0 + hb2[0];
  OUT[(b * NC_ + 1) * N_ + n] = a1 + hb2[1];
}

extern "C" void kernel_launch(void* const* d_in, const int* in_sizes, int n_in,
                              void* d_out, int out_size, void* d_ws, size_t ws_size,
                              hipStream_t stream) {
  (void)in_sizes; (void)n_in; (void)out_size;
  const float* pts     = (const float*)d_in[0];
  const float* embed_w = (const float*)d_in[1];
  const float* embed_g = (const float*)d_in[2];
  const float* embed_b = (const float*)d_in[3];
  const float* embed_m = (const float*)d_in[4];
  const float* embed_v = (const float*)d_in[5];
  const float* wq      = (const float*)d_in[6];
  const float* wk      = (const float*)d_in[7];
  const float* wv      = (const float*)d_in[8];
  const float* pe_w1   = (const float*)d_in[9];
  const float* pe_g    = (const float*)d_in[10];
  const float* pe_b    = (const float*)d_in[11];
  const float* pe_m    = (const float*)d_in[12];
  const float* pe_v    = (const float*)d_in[13];
  const float* pe_w2   = (const float*)d_in[14];
  const float* am_w1   = (const float*)d_in[15];
  const float* am_g    = (const float*)d_in[16];
  const float* am_b    = (const float*)d_in[17];
  const float* am_m    = (const float*)d_in[18];
  const float* am_v    = (const float*)d_in[19];
  const float* am_w2   = (const float*)d_in[20];
  const float* n1_g    = (const float*)d_in[21];
  const float* n1_b    = (const float*)d_in[22];
  const float* n1_m    = (const float*)d_in[23];
  const float* n1_v    = (const float*)d_in[24];
  const float* ffn_w1  = (const float*)d_in[25];
  const float* f_g     = (const float*)d_in[26];
  const float* f_b     = (const float*)d_in[27];
  const float* f_m     = (const float*)d_in[28];
  const float* f_v     = (const float*)d_in[29];
  const float* ffn_w2  = (const float*)d_in[30];
  const float* n2_g    = (const float*)d_in[31];
  const float* n2_b    = (const float*)d_in[32];
  const float* n2_m    = (const float*)d_in[33];
  const float* n2_v    = (const float*)d_in[34];
  const float* hd_w1   = (const float*)d_in[35];
  const float* hd_g    = (const float*)d_in[36];
  const float* hd_b    = (const float*)d_in[37];
  const float* hd_m    = (const float*)d_in[38];
  const float* hd_v    = (const float*)d_in[39];
  const float* hd_w2   = (const float*)d_in[40];
  const float* hd_b2   = (const float*)d_in[41];

  // ws budget identical to thrice-proven layout; WH reuses SQ's space (dead after k_knn):
  // per-layer fp16 weights = 3*9216*2 = 55,296 B <= SQ's 65,536 B.
  const size_t NEED = (size_t)(4 * B_ * D_ * N_ + B_ * N_ + B_ * N_ * K_) * 4;
  if (ws_size < NEED) return;

  float* ws = (float*)d_ws;
  float* X  = ws;
  float* QT = X  + (size_t)B_ * D_ * N_;
  float* KT = QT + (size_t)B_ * N_ * D_;
  float* VT = KT + (size_t)B_ * N_ * D_;
  float* SQ = VT + (size_t)B_ * N_ * D_;
  int*   IDX = (int*)(SQ + (size_t)B_ * N_);
  unsigned short* WH = (unsigned short*)SQ;  // alive only after k_knn

  k_embed<<<B_ * N_ / 256, 256, 0, stream>>>(pts, embed_w, embed_g, embed_b, embed_m, embed_v, X, SQ);
  k_knn<<<B_ * N_ / 4, 256, 0, stream>>>(pts, SQ, IDX);
  for (int l = 0; l < L_; ++l) {
    k_prep_wl<<<36, 256, 0, stream>>>(pe_w2 + l * D_ * D_, am_w1 + l * D_ * D_, am_w2 + l * D_ * D_, WH);
    k_qkv<<<B_ * N_ / 256, 256, 0, stream>>>(X, wq + l * D_ * D_, wk + l * D_ * D_, wv + l * D_ * D_, QT, KT, VT);
    k_attn<<<B_ * N_ / 4, 256, 0, stream>>>(X, QT, KT, VT, pts, IDX,
        pe_w1 + l * D_ * 3, pe_g + l * D_, pe_b + l * D_, pe_m + l * D_, pe_v + l * D_,
        WH,
        am_g + l * D_, am_b + l * D_, am_m + l * D_, am_v + l * D_,
        n1_g + l * D_, n1_b + l * D_, n1_m + l * D_, n1_v + l * D_);
    k_ffn<<<B_ * N_ / 2, 192, 0, stream>>>(X, ffn_w1 + l * H_ * D_, f_g + l * H_, f_b + l * H_, f_m + l * H_, f_v + l * H_,
        ffn_w2 + l * D_ * H_, n2_g + l * D_, n2_b + l * D_, n2_m + l * D_, n2_v + l * D_);
  }
  k_head<<<B_ * N_ / 256, 256, 0, stream>>>(X, hd_w1, hd_g, hd_b, hd_m, hd_v, hd_w2, hd_b2, (float*)d_out);
}

// Round 14
// 1811.825 us; speedup vs baseline: 2.1336x; 1.9142x over previous
//
#include <hip/hip_runtime.h>

#define B_ 2
#define N_ 8192
#define D_ 96
#define L_ 4
#define H_ 192
#define K_ 16
#define NC_ 2
#define EPS_ 1e-5f
#define BIGF 3.402823466e38f
#define TSTR 104   // padded LDS stride (fp16 elems) for 96-wide tiles — proven in R12
#define T2STR 200  // padded LDS stride for 192-wide h tile (~2-way conflicts, free)

typedef _Float16 half8 __attribute__((ext_vector_type(8)));
typedef float f32x4 __attribute__((ext_vector_type(4)));

__device__ __forceinline__ float bn1(float x, float g, float b, float m, float v) {
  return (x - m) * (g * (1.0f / sqrtf(v + EPS_))) + b;
}

__device__ __forceinline__ unsigned short f2h(float x) {
  union { _Float16 h; unsigned short u; } c;
  c.h = (_Float16)x;
  return c.u;
}

// ---------------- embed + per-point squared norm (proven baseline) ----------
__global__ void k_embed(const float* __restrict__ pts, const float* __restrict__ w,
                        const float* __restrict__ g, const float* __restrict__ bb,
                        const float* __restrict__ m, const float* __restrict__ v,
                        float* __restrict__ X, float* __restrict__ SQ) {
  int gid = blockIdx.x * 256 + threadIdx.x;
  int b = gid / N_, n = gid % N_;
  float p0 = pts[gid * 3], p1 = pts[gid * 3 + 1], p2 = pts[gid * 3 + 2];
  // exact numpy-order fp32 arithmetic (feeds KNN selection)
  SQ[gid] = __fadd_rn(__fadd_rn(__fmul_rn(p0, p0), __fmul_rn(p1, p1)), __fmul_rn(p2, p2));
  for (int o = 0; o < D_; ++o) {
    float e = w[o * 3] * p0 + w[o * 3 + 1] * p1 + w[o * 3 + 2] * p2;
    X[(b * D_ + o) * N_ + n] = fmaxf(bn1(e, g[o], bb[o], m[o], v[o]), 0.0f);
  }
}

// ---------------- KNN: proven baseline version (frozen) ----------------
__global__ void k_knn(const float* __restrict__ pts, const float* __restrict__ SQ,
                      int* __restrict__ IDX) {
  int lane = threadIdx.x & 63;
  int g = blockIdx.x * 4 + (threadIdx.x >> 6);
  int b = g / N_, n = g % N_;
  const float* pb = pts + b * N_ * 3;
  const float* sqb = SQ + b * N_;
  float qx = pb[n * 3], qy = pb[n * 3 + 1], qz = pb[n * 3 + 2];
  float sqn = sqb[n];
  float bd[K_]; int bi[K_];
#pragma unroll
  for (int s = 0; s < K_; ++s) { bd[s] = BIGF; bi[s] = 0x7fffffff; }
  float wd = BIGF; int wi = 0x7fffffff; int wslot = 0;
  for (int j = 0; j < N_ / 64; ++j) {
    int cand = lane + j * 64;
    const float* pc = pb + cand * 3;
    float px = pc[0], py = pc[1], pz = pc[2];
    float dot = __fadd_rn(__fadd_rn(__fmul_rn(qx, px), __fmul_rn(qy, py)), __fmul_rn(qz, pz));
    float d = __fsub_rn(__fadd_rn(sqn, sqb[cand]), __fmul_rn(2.0f, dot));
    if (d < wd || (d == wd && cand < wi)) {
#pragma unroll
      for (int s = 0; s < K_; ++s) if (s == wslot) { bd[s] = d; bi[s] = cand; }
      wd = -BIGF; wi = -1;
#pragma unroll
      for (int s = 0; s < K_; ++s) {
        bool worse = (bd[s] > wd) || (bd[s] == wd && bi[s] > wi);
        if (worse) { wd = bd[s]; wi = bi[s]; wslot = s; }
      }
    }
  }
  for (int r = 0; r < K_; ++r) {
    float md = BIGF; int mi = 0x7fffffff;
#pragma unroll
    for (int s = 0; s < K_; ++s) {
      bool better = (bd[s] < md) || (bd[s] == md && bi[s] < mi);
      if (better) { md = bd[s]; mi = bi[s]; }
    }
#pragma unroll
    for (int off = 32; off > 0; off >>= 1) {
      float od = __shfl_xor(md, off);
      int oi = __shfl_xor(mi, off);
      bool better = (od < md) || (od == md && oi < mi);
      if (better) { md = od; mi = oi; }
    }
#pragma unroll
    for (int s = 0; s < K_; ++s) if (bi[s] == mi) { bd[s] = BIGF; bi[s] = 0x7fffffff; }
    if (lane == 0) IDX[g * K_ + r] = mi;
  }
}

// ---------------- per-layer attn weight prep: fp32 -> fp16 into SQ dead space ------------
__global__ void k_prep_wl(const float* __restrict__ pw2, const float* __restrict__ aw1,
                          const float* __restrict__ aw2, unsigned short* __restrict__ WH) {
  int i = blockIdx.x * 256 + threadIdx.x;  // 9216 = D_*D_; grid 36
  WH[i]         = f2h(pw2[i]);
  WH[9216 + i]  = f2h(aw1[i]);
  WH[18432 + i] = f2h(aw2[i]);
}

// ---------------- per-layer ffn weight prep: fp32 -> fp16 into KT dead space ------------
__global__ void k_prep_ffn(const float* __restrict__ w1, const float* __restrict__ w2,
                           unsigned short* __restrict__ WF) {
  int i = blockIdx.x * 256 + threadIdx.x;  // 18432 = H_*D_; grid 72
  WF[i]         = f2h(w1[i]);
  WF[18432 + i] = f2h(w2[i]);
}

// ---------------- QKV: 32 pts x 8 o-groups per block (512 blocks) ----------------
__global__ void __launch_bounds__(256) k_qkv(const float* __restrict__ X, const float* __restrict__ wq,
                      const float* __restrict__ wk, const float* __restrict__ wv,
                      float* __restrict__ QT, float* __restrict__ KT, float* __restrict__ VT) {
  int tid = threadIdx.x;
  int pl = tid & 31, og = tid >> 5;
  int g = blockIdx.x * 32 + pl;
  int b = g >> 13, n = g & (N_ - 1);
  const float* xb = X + (size_t)b * D_ * N_ + n;
  float xr[96];
#pragma unroll
  for (int c = 0; c < 96; ++c) xr[c] = xb[(size_t)c * N_];
  int o0 = og * 12;
  const float* Ws[3] = {wq, wk, wv};
  float* Os[3] = {QT, KT, VT};
#pragma unroll
  for (int t = 0; t < 3; ++t) {
    float acc[12];
#pragma unroll
    for (int j = 0; j < 12; ++j) {
      const float* wr = Ws[t] + (o0 + j) * 96;
      float a = 0.f;
#pragma unroll
      for (int c4 = 0; c4 < 96; c4 += 4) {
        float4 wv4 = *(const float4*)&wr[c4];
        a += wv4.x * xr[c4] + wv4.y * xr[c4 + 1] + wv4.z * xr[c4 + 2] + wv4.w * xr[c4 + 3];
      }
      acc[j] = a;
    }
    float* op = Os[t] + (size_t)g * 96 + o0;
    *(float4*)&op[0] = make_float4(acc[0], acc[1], acc[2], acc[3]);
    *(float4*)&op[4] = make_float4(acc[4], acc[5], acc[6], acc[7]);
    *(float4*)&op[8] = make_float4(acc[8], acc[9], acc[10], acc[11]);
  }
}

// W(16x32 rows of m-tile) @ Act(32x16) over 3 K-steps, 6 m-tiles; fp16 in, fp32 out.
// A frag: row = lane&15, k = s*32 + (lane>>4)*8 + j   (row-major fp16 W, stride 96)
// B frag: col(slot) = lane&15, k likewise; tile stored [slot][k], stride TSTR
// D frag: col(slot) = lane&15, row(channel) = m*16 + (lane>>4)*4 + r
__device__ __forceinline__ void mfma_stage(const unsigned short* __restrict__ Wh,
                                           const unsigned short* tw,
                                           int n16, int q4, f32x4 acc[6]) {
  half8 bfr[3];
#pragma unroll
  for (int s = 0; s < 3; ++s)
    bfr[s] = *(const half8*)&tw[n16 * TSTR + s * 32 + q4 * 8];
#pragma unroll
  for (int m = 0; m < 6; ++m) {
#pragma unroll
    for (int s = 0; s < 3; ++s) {
      half8 av = *(const half8*)&Wh[(m * 16 + n16) * 96 + s * 32 + q4 * 8];
      acc[m] = __builtin_amdgcn_mfma_f32_16x16x32_f16(av, bfr[s], acc[m], 0, 0, 0);
    }
  }
}

// ---------------- fused attention: 1 wave per point, 4 points/block, MFMA (proven R12) --------
__global__ void __launch_bounds__(256) k_attn(
    float* __restrict__ X, const float* __restrict__ QT, const float* __restrict__ KT,
    const float* __restrict__ VT, const float* __restrict__ pts, const int* __restrict__ IDX,
    const float* __restrict__ pw1, const float* __restrict__ pg, const float* __restrict__ pb_,
    const float* __restrict__ pm, const float* __restrict__ pv,
    const unsigned short* __restrict__ WH,
    const float* __restrict__ ag, const float* __restrict__ ab,
    const float* __restrict__ am, const float* __restrict__ av,
    const float* __restrict__ g1, const float* __restrict__ b1,
    const float* __restrict__ m1, const float* __restrict__ v1) {
  __shared__ __align__(16) unsigned short tile[4][16 * TSTR];
  __shared__ float pdif[4][3][16];
  __shared__ int sid[4][16];
  const int tid = threadIdx.x;
  const int l = tid & 63, w = tid >> 6;
  const int g = blockIdx.x * 4 + w;
  const int b = g >> 13, n = g & (N_ - 1);
  const int n16 = l & 15, q4 = l >> 4;
  unsigned short* tw = &tile[w][0];

  if (l < 16) {
    int nbr = IDX[g * K_ + l];
    sid[w][l] = nbr;
    const float* pq = pts + ((size_t)b * N_ + n) * 3;
    const float* pn = pts + ((size_t)b * N_ + nbr) * 3;
    pdif[w][0][l] = pq[0] - pn[0];
    pdif[w][1][l] = pq[1] - pn[1];
    pdif[w][2][l] = pq[2] - pn[2];
  }
  __syncthreads();

  {
    float p0 = pdif[w][0][n16], p1 = pdif[w][1][n16], p2 = pdif[w][2][n16];
    int c0 = q4 * 24;
#pragma unroll
    for (int ii = 0; ii < 24; ii += 2) {
      int c = c0 + ii;
      float vA = pw1[c * 3] * p0 + pw1[c * 3 + 1] * p1 + pw1[c * 3 + 2] * p2;
      float vB = pw1[(c + 1) * 3] * p0 + pw1[(c + 1) * 3 + 1] * p1 + pw1[(c + 1) * 3 + 2] * p2;
      vA = fmaxf(bn1(vA, pg[c], pb_[c], pm[c], pv[c]), 0.f);
      vB = fmaxf(bn1(vB, pg[c + 1], pb_[c + 1], pm[c + 1], pv[c + 1]), 0.f);
      unsigned u = (unsigned)f2h(vA) | ((unsigned)f2h(vB) << 16);
      *(unsigned*)&tw[n16 * TSTR + c] = u;
    }
  }
  __syncthreads();

  f32x4 pe2[6];
#pragma unroll
  for (int m = 0; m < 6; ++m) pe2[m] = (f32x4){0.f, 0.f, 0.f, 0.f};
  mfma_stage(WH, tw, n16, q4, pe2);
  __syncthreads();

  const int nbr = sid[w][n16];
  {
    const float* qt = QT + (size_t)g * 96;
    const float* kt = KT + ((size_t)b * N_ + nbr) * 96;
#pragma unroll
    for (int m = 0; m < 6; ++m) {
      int cb = m * 16 + q4 * 4;
      float4 qv = *(const float4*)&qt[cb];
      float4 kv = *(const float4*)&kt[cb];
      float v0 = qv.x - kv.x + pe2[m][0];
      float v1 = qv.y - kv.y + pe2[m][1];
      float v2 = qv.z - kv.z + pe2[m][2];
      float v3 = qv.w - kv.w + pe2[m][3];
      int idx = n16 * TSTR + cb;
      *(unsigned*)&tw[idx]     = (unsigned)f2h(v0) | ((unsigned)f2h(v1) << 16);
      *(unsigned*)&tw[idx + 2] = (unsigned)f2h(v2) | ((unsigned)f2h(v3) << 16);
    }
  }
  __syncthreads();

  {
    f32x4 t1[6];
#pragma unroll
    for (int m = 0; m < 6; ++m) t1[m] = (f32x4){0.f, 0.f, 0.f, 0.f};
    mfma_stage(WH + 9216, tw, n16, q4, t1);
    __syncthreads();
#pragma unroll
    for (int m = 0; m < 6; ++m) {
      int cb = m * 16 + q4 * 4;
      float v0 = fmaxf(bn1(t1[m][0], ag[cb], ab[cb], am[cb], av[cb]), 0.f);
      float v1 = fmaxf(bn1(t1[m][1], ag[cb + 1], ab[cb + 1], am[cb + 1], av[cb + 1]), 0.f);
      float v2 = fmaxf(bn1(t1[m][2], ag[cb + 2], ab[cb + 2], am[cb + 2], av[cb + 2]), 0.f);
      float v3 = fmaxf(bn1(t1[m][3], ag[cb + 3], ab[cb + 3], am[cb + 3], av[cb + 3]), 0.f);
      int idx = n16 * TSTR + cb;
      *(unsigned*)&tw[idx]     = (unsigned)f2h(v0) | ((unsigned)f2h(v1) << 16);
      *(unsigned*)&tw[idx + 2] = (unsigned)f2h(v2) | ((unsigned)f2h(v3) << 16);
    }
  }
  __syncthreads();

  {
    f32x4 a2[6];
#pragma unroll
    for (int m = 0; m < 6; ++m) a2[m] = (f32x4){0.f, 0.f, 0.f, 0.f};
    mfma_stage(WH + 18432, tw, n16, q4, a2);
    const float* vt = VT + ((size_t)b * N_ + nbr) * 96;
#pragma unroll
    for (int m = 0; m < 6; ++m) {
      int cb = m * 16 + q4 * 4;
      float4 vv = *(const float4*)&vt[cb];
      const float* vvp = (const float*)&vv;
      float ov[4];
#pragma unroll
      for (int r = 0; r < 4; ++r) {
        float a = a2[m][r];
        float mx = a;
        mx = fmaxf(mx, __shfl_xor(mx, 1));
        mx = fmaxf(mx, __shfl_xor(mx, 2));
        mx = fmaxf(mx, __shfl_xor(mx, 4));
        mx = fmaxf(mx, __shfl_xor(mx, 8));
        float e = expf(a - mx);
        float s = e;
        s += __shfl_xor(s, 1); s += __shfl_xor(s, 2); s += __shfl_xor(s, 4); s += __shfl_xor(s, 8);
        float c = e * (vvp[r] + pe2[m][r]);
        c += __shfl_xor(c, 1); c += __shfl_xor(c, 2); c += __shfl_xor(c, 4); c += __shfl_xor(c, 8);
        ov[r] = c / s;
      }
      if (n16 == 0) {
#pragma unroll
        for (int r = 0; r < 4; ++r) {
          int c = cb + r;
          size_t xi = ((size_t)b * D_ + c) * N_ + n;
          float t = X[xi] + ov[r];
          X[xi] = (t - m1[c]) * (g1[c] * (1.0f / sqrtf(v1[c] + EPS_))) + b1[c];
        }
      }
    }
  }
}

// ---------------- FFN: MFMA, 1 wave per 16 points, 4 waves/block ----------------
__global__ void __launch_bounds__(256) k_ffn(
    float* __restrict__ X, const unsigned short* __restrict__ WF,
    const float* __restrict__ fg, const float* __restrict__ fb,
    const float* __restrict__ fm, const float* __restrict__ fv,
    const float* __restrict__ g2, const float* __restrict__ b2,
    const float* __restrict__ m2, const float* __restrict__ v2) {
  __shared__ __align__(16) unsigned short t1s[4][16 * TSTR];   // x fp16: [pt][c]
  __shared__ __align__(16) unsigned short t2s[4][16 * T2STR];  // h fp16: [pt][j]
  const int tid = threadIdx.x;
  const int l = tid & 63, w = tid >> 6;
  const int n16 = l & 15, q4 = l >> 4;
  const int p0 = blockIdx.x * 64 + w * 16;   // first point of this wave (64 pts/block, no b crossing)
  const int b = p0 >> 13;
  const int nn = p0 & (N_ - 1);
  unsigned short* x1 = &t1s[w][0];
  unsigned short* h1 = &t2s[w][0];

  // phase 1: x tile -> fp16 LDS [point][channel]
  {
    const float* xb = X + (size_t)b * D_ * N_ + nn + n16;
    int c0 = q4 * 24;
#pragma unroll
    for (int i = 0; i < 24; ++i) {
      int c = c0 + i;
      x1[n16 * TSTR + c] = f2h(xb[(size_t)c * N_]);
    }
  }
  __syncthreads();

  // phase 2: h = relu(bn_f(W1 @ x))  (12 m-tiles x 3 k-steps) -> h tile
  {
    f32x4 acc[12];
#pragma unroll
    for (int m = 0; m < 12; ++m) acc[m] = (f32x4){0.f, 0.f, 0.f, 0.f};
    half8 bfr[3];
#pragma unroll
    for (int s = 0; s < 3; ++s) bfr[s] = *(const half8*)&x1[n16 * TSTR + s * 32 + q4 * 8];
#pragma unroll
    for (int m = 0; m < 12; ++m) {
#pragma unroll
      for (int s = 0; s < 3; ++s) {
        half8 av = *(const half8*)&WF[(m * 16 + n16) * 96 + s * 32 + q4 * 8];
        acc[m] = __builtin_amdgcn_mfma_f32_16x16x32_f16(av, bfr[s], acc[m], 0, 0, 0);
      }
    }
    __syncthreads();  // x tile fully consumed before h writes begin
#pragma unroll
    for (int m = 0; m < 12; ++m) {
      int jb = m * 16 + q4 * 4;
#pragma unroll
      for (int r = 0; r < 4; ++r) {
        int j = jb + r;
        float hv = fmaxf(bn1(acc[m][r], fg[j], fb[j], fm[j], fv[j]), 0.f);
        h1[n16 * T2STR + j] = f2h(hv);
      }
    }
  }
  __syncthreads();

  // phase 3: out = W2 @ h (6 m-tiles x 6 k-steps) ; residual + bn2 -> X
  {
    const unsigned short* W2h = WF + 18432;
    f32x4 acc[6];
#pragma unroll
    for (int m = 0; m < 6; ++m) acc[m] = (f32x4){0.f, 0.f, 0.f, 0.f};
    half8 bfr[6];
#pragma unroll
    for (int s = 0; s < 6; ++s) bfr[s] = *(const half8*)&h1[n16 * T2STR + s * 32 + q4 * 8];
#pragma unroll
    for (int m = 0; m < 6; ++m) {
#pragma unroll
      for (int s = 0; s < 6; ++s) {
        half8 av = *(const half8*)&W2h[(m * 16 + n16) * 192 + s * 32 + q4 * 8];
        acc[m] = __builtin_amdgcn_mfma_f32_16x16x32_f16(av, bfr[s], acc[m], 0, 0, 0);
      }
    }
#pragma unroll
    for (int m = 0; m < 6; ++m) {
      int cb = m * 16 + q4 * 4;
#pragma unroll
      for (int r = 0; r < 4; ++r) {
        int c = cb + r;
        size_t xi = ((size_t)b * D_ + c) * N_ + nn + n16;
        float t = X[xi] + acc[m][r];
        X[xi] = bn1(t, g2[c], b2[c], m2[c], v2[c]);
      }
    }
  }
}

// ---------------- head: proven baseline version ----------------
__global__ void k_head(const float* __restrict__ X, const float* __restrict__ w1,
                       const float* __restrict__ hg, const float* __restrict__ hbb,
                       const float* __restrict__ hm, const float* __restrict__ hv,
                       const float* __restrict__ w2, const float* __restrict__ hb2,
                       float* __restrict__ OUT) {
  int gid = blockIdx.x * 256 + threadIdx.x;
  int b = gid / N_, n = gid % N_;
  const float* xb = X + b * D_ * N_ + n;
  float xr[D_];
#pragma unroll
  for (int c = 0; c < D_; ++c) xr[c] = xb[c * N_];
  float a0 = 0.f, a1 = 0.f;
  for (int j = 0; j < 128; ++j) {
    float acc = 0.f;
#pragma unroll
    for (int c = 0; c < D_; ++c) acc += w1[j * D_ + c] * xr[c];
    float t = fmaxf(bn1(acc, hg[j], hbb[j], hm[j], hv[j]), 0.0f);
    a0 += w2[j] * t;
    a1 += w2[128 + j] * t;
  }
  OUT[(b * NC_ + 0) * N_ + n] = a0 + hb2[0];
  OUT[(b * NC_ + 1) * N_ + n] = a1 + hb2[1];
}

extern "C" void kernel_launch(void* const* d_in, const int* in_sizes, int n_in,
                              void* d_out, int out_size, void* d_ws, size_t ws_size,
                              hipStream_t stream) {
  (void)in_sizes; (void)n_in; (void)out_size;
  const float* pts     = (const float*)d_in[0];
  const float* embed_w = (const float*)d_in[1];
  const float* embed_g = (const float*)d_in[2];
  const float* embed_b = (const float*)d_in[3];
  const float* embed_m = (const float*)d_in[4];
  const float* embed_v = (const float*)d_in[5];
  const float* wq      = (const float*)d_in[6];
  const float* wk      = (const float*)d_in[7];
  const float* wv      = (const float*)d_in[8];
  const float* pe_w1   = (const float*)d_in[9];
  const float* pe_g    = (const float*)d_in[10];
  const float* pe_b    = (const float*)d_in[11];
  const float* pe_m    = (const float*)d_in[12];
  const float* pe_v    = (const float*)d_in[13];
  const float* pe_w2   = (const float*)d_in[14];
  const float* am_w1   = (const float*)d_in[15];
  const float* am_g    = (const float*)d_in[16];
  const float* am_b    = (const float*)d_in[17];
  const float* am_m    = (const float*)d_in[18];
  const float* am_v    = (const float*)d_in[19];
  const float* am_w2   = (const float*)d_in[20];
  const float* n1_g    = (const float*)d_in[21];
  const float* n1_b    = (const float*)d_in[22];
  const float* n1_m    = (const float*)d_in[23];
  const float* n1_v    = (const float*)d_in[24];
  const float* ffn_w1  = (const float*)d_in[25];
  const float* f_g     = (const float*)d_in[26];
  const float* f_b     = (const float*)d_in[27];
  const float* f_m     = (const float*)d_in[28];
  const float* f_v     = (const float*)d_in[29];
  const float* ffn_w2  = (const float*)d_in[30];
  const float* n2_g    = (const float*)d_in[31];
  const float* n2_b    = (const float*)d_in[32];
  const float* n2_m    = (const float*)d_in[33];
  const float* n2_v    = (const float*)d_in[34];
  const float* hd_w1   = (const float*)d_in[35];
  const float* hd_g    = (const float*)d_in[36];
  const float* hd_b    = (const float*)d_in[37];
  const float* hd_m    = (const float*)d_in[38];
  const float* hd_v    = (const float*)d_in[39];
  const float* hd_w2   = (const float*)d_in[40];
  const float* hd_b2   = (const float*)d_in[41];

  // ws budget identical to proven layout. Attn fp16 weights live in SQ's dead space
  // (55,296 B <= 65,536 B, dead after k_knn); ffn fp16 weights live in KT's head
  // (73,728 B << 6.29 MB, dead between k_attn(l) and k_qkv(l+1)).
  const size_t NEED = (size_t)(4 * B_ * D_ * N_ + B_ * N_ + B_ * N_ * K_) * 4;
  if (ws_size < NEED) return;

  float* ws = (float*)d_ws;
  float* X  = ws;
  float* QT = X  + (size_t)B_ * D_ * N_;
  float* KT = QT + (size_t)B_ * N_ * D_;
  float* VT = KT + (size_t)B_ * N_ * D_;
  float* SQ = VT + (size_t)B_ * N_ * D_;
  int*   IDX = (int*)(SQ + (size_t)B_ * N_);
  unsigned short* WH = (unsigned short*)SQ;  // attn weights, alive only after k_knn
  unsigned short* WF = (unsigned short*)KT;  // ffn weights, alive attn(l) -> ffn(l)

  k_embed<<<B_ * N_ / 256, 256, 0, stream>>>(pts, embed_w, embed_g, embed_b, embed_m, embed_v, X, SQ);
  k_knn<<<B_ * N_ / 4, 256, 0, stream>>>(pts, SQ, IDX);
  for (int l = 0; l < L_; ++l) {
    k_prep_wl<<<36, 256, 0, stream>>>(pe_w2 + l * D_ * D_, am_w1 + l * D_ * D_, am_w2 + l * D_ * D_, WH);
    k_qkv<<<B_ * N_ / 32, 256, 0, stream>>>(X, wq + l * D_ * D_, wk + l * D_ * D_, wv + l * D_ * D_, QT, KT, VT);
    k_attn<<<B_ * N_ / 4, 256, 0, stream>>>(X, QT, KT, VT, pts, IDX,
        pe_w1 + l * D_ * 3, pe_g + l * D_, pe_b + l * D_, pe_m + l * D_, pe_v + l * D_,
        WH,
        am_g + l * D_, am_b + l * D_, am_m + l * D_, am_v + l * D_,
        n1_g + l * D_, n1_b + l * D_, n1_m + l * D_, n1_v + l * D_);
    k_prep_ffn<<<72, 256, 0, stream>>>(ffn_w1 + l * H_ * D_, ffn_w2 + l * D_ * H_, WF);
    k_ffn<<<B_ * N_ / 64, 256, 0, stream>>>(X, WF,
        f_g + l * H_, f_b + l * H_, f_m + l * H_, f_v + l * H_,
        n2_g + l * D_, n2_b + l * D_, n2_m + l * D_, n2_v + l * D_);
  }
  k_head<<<B_ * N_ / 256, 256, 0, stream>>>(X, hd_w1, hd_g, hd_b, hd_m, hd_v, hd_w2, hd_b2, (float*)d_out);
}

// Round 15
// 1619.550 us; speedup vs baseline: 2.3869x; 1.1187x over previous
//
#include <hip/hip_runtime.h>

#define B_ 2
#define N_ 8192
#define D_ 96
#define L_ 4
#define H_ 192
#define K_ 16
#define NC_ 2
#define EPS_ 1e-5f
#define BIGF 3.402823466e38f
#define TSTR 104   // padded LDS stride (fp16 elems) for 96-wide tiles — proven in R12
#define T2STR 200  // padded LDS stride for 192-wide h tile (~2-way conflicts, free)

typedef _Float16 half8 __attribute__((ext_vector_type(8)));
typedef float f32x4 __attribute__((ext_vector_type(4)));

__device__ __forceinline__ float bn1(float x, float g, float b, float m, float v) {
  return (x - m) * (g * (1.0f / sqrtf(v + EPS_))) + b;
}

__device__ __forceinline__ unsigned short f2h(float x) {
  union { _Float16 h; unsigned short u; } c;
  c.h = (_Float16)x;
  return c.u;
}

// ---------------- embed + per-point squared norm (proven baseline) ----------
__global__ void k_embed(const float* __restrict__ pts, const float* __restrict__ w,
                        const float* __restrict__ g, const float* __restrict__ bb,
                        const float* __restrict__ m, const float* __restrict__ v,
                        float* __restrict__ X, float* __restrict__ SQ) {
  int gid = blockIdx.x * 256 + threadIdx.x;
  int b = gid / N_, n = gid % N_;
  float p0 = pts[gid * 3], p1 = pts[gid * 3 + 1], p2 = pts[gid * 3 + 2];
  // exact numpy-order fp32 arithmetic (feeds KNN selection)
  SQ[gid] = __fadd_rn(__fadd_rn(__fmul_rn(p0, p0), __fmul_rn(p1, p1)), __fmul_rn(p2, p2));
  for (int o = 0; o < D_; ++o) {
    float e = w[o * 3] * p0 + w[o * 3 + 1] * p1 + w[o * 3 + 2] * p2;
    X[(b * D_ + o) * N_ + n] = fmaxf(bn1(e, g[o], bb[o], m[o], v[o]), 0.0f);
  }
}

// ---------------- KNN v2: R1 insertion structure + group-min threshold gate ----------------
// Pass 1 computes a lossless filter threshold T with 6 branchless shfls:
//   - each lane's running min over its 128 disjoint candidates
//   - min within each 4-lane group (2 shfls)  -> 16 group minima = 16 DISTINCT candidates
//   - T = max over the 16 group minima (4 shfls)
// Since >=16 distinct candidates have d <= T, T >= true 16th-smallest distance, so gating
// the exact insertion network on d <= T drops no true neighbor.  Wave-local: no LDS,
// no ballot, no barriers, fixed-trip loops.
__global__ void k_knn(const float* __restrict__ pts, const float* __restrict__ SQ,
                      int* __restrict__ IDX) {
  int lane = threadIdx.x & 63;
  int g = blockIdx.x * 4 + (threadIdx.x >> 6);
  int b = g / N_, n = g % N_;
  const float* pb = pts + b * N_ * 3;
  const float* sqb = SQ + b * N_;
  float qx = pb[n * 3], qy = pb[n * 3 + 1], qz = pb[n * 3 + 2];
  float sqn = sqb[n];

  // pass 1: branchless per-lane running min (exact numpy-order arithmetic)
  float lmin = BIGF;
  for (int j = 0; j < N_ / 64; ++j) {
    int cand = lane + j * 64;
    const float* pc = pb + cand * 3;
    float dot = __fadd_rn(__fadd_rn(__fmul_rn(qx, pc[0]), __fmul_rn(qy, pc[1])), __fmul_rn(qz, pc[2]));
    float d = __fsub_rn(__fadd_rn(sqn, sqb[cand]), __fmul_rn(2.0f, dot));
    lmin = fminf(lmin, d);
  }
  // group-of-4 min, then max across the 16 groups -> lossless threshold T
  float gm = fminf(lmin, __shfl_xor(lmin, 1));
  gm = fminf(gm, __shfl_xor(gm, 2));
  float T = gm;
  T = fmaxf(T, __shfl_xor(T, 4));
  T = fmaxf(T, __shfl_xor(T, 8));
  T = fmaxf(T, __shfl_xor(T, 16));
  T = fmaxf(T, __shfl_xor(T, 32));

  // pass 2: identical distance arithmetic; proven insertion network gated on d <= T
  float bd[K_]; int bi[K_];
#pragma unroll
  for (int s = 0; s < K_; ++s) { bd[s] = BIGF; bi[s] = 0x7fffffff; }
  float wd = BIGF; int wi = 0x7fffffff; int wslot = 0;
  for (int j = 0; j < N_ / 64; ++j) {
    int cand = lane + j * 64;
    const float* pc = pb + cand * 3;
    float dot = __fadd_rn(__fadd_rn(__fmul_rn(qx, pc[0]), __fmul_rn(qy, pc[1])), __fmul_rn(qz, pc[2]));
    float d = __fsub_rn(__fadd_rn(sqn, sqb[cand]), __fmul_rn(2.0f, dot));
    bool take = (d <= T) && (d < wd || (d == wd && cand < wi));
    if (take) {
#pragma unroll
      for (int s = 0; s < K_; ++s) if (s == wslot) { bd[s] = d; bi[s] = cand; }
      wd = -BIGF; wi = -1;
#pragma unroll
      for (int s = 0; s < K_; ++s) {
        bool worse = (bd[s] > wd) || (bd[s] == wd && bi[s] > wi);
        if (worse) { wd = bd[s]; wi = bi[s]; wslot = s; }
      }
    }
  }

  // merge 64 lanes' candidates -> global top-16 (byte-identical to proven R1 merge)
  for (int r = 0; r < K_; ++r) {
    float md = BIGF; int mi = 0x7fffffff;
#pragma unroll
    for (int s = 0; s < K_; ++s) {
      bool better = (bd[s] < md) || (bd[s] == md && bi[s] < mi);
      if (better) { md = bd[s]; mi = bi[s]; }
    }
#pragma unroll
    for (int off = 32; off > 0; off >>= 1) {
      float od = __shfl_xor(md, off);
      int oi = __shfl_xor(mi, off);
      bool better = (od < md) || (od == md && oi < mi);
      if (better) { md = od; mi = oi; }
    }
#pragma unroll
    for (int s = 0; s < K_; ++s) if (bi[s] == mi) { bd[s] = BIGF; bi[s] = 0x7fffffff; }
    if (lane == 0) IDX[g * K_ + r] = mi;
  }
}

// ---------------- per-layer attn weight prep: fp32 -> fp16 into SQ dead space ------------
__global__ void k_prep_wl(const float* __restrict__ pw2, const float* __restrict__ aw1,
                          const float* __restrict__ aw2, unsigned short* __restrict__ WH) {
  int i = blockIdx.x * 256 + threadIdx.x;  // 9216 = D_*D_; grid 36
  WH[i]         = f2h(pw2[i]);
  WH[9216 + i]  = f2h(aw1[i]);
  WH[18432 + i] = f2h(aw2[i]);
}

// ---------------- per-layer ffn weight prep: fp32 -> fp16 into KT dead space ------------
__global__ void k_prep_ffn(const float* __restrict__ w1, const float* __restrict__ w2,
                           unsigned short* __restrict__ WF) {
  int i = blockIdx.x * 256 + threadIdx.x;  // 18432 = H_*D_; grid 72
  WF[i]         = f2h(w1[i]);
  WF[18432 + i] = f2h(w2[i]);
}

// ---------------- QKV: 32 pts x 8 o-groups per block (512 blocks) ----------------
__global__ void __launch_bounds__(256) k_qkv(const float* __restrict__ X, const float* __restrict__ wq,
                      const float* __restrict__ wk, const float* __restrict__ wv,
                      float* __restrict__ QT, float* __restrict__ KT, float* __restrict__ VT) {
  int tid = threadIdx.x;
  int pl = tid & 31, og = tid >> 5;
  int g = blockIdx.x * 32 + pl;
  int b = g >> 13, n = g & (N_ - 1);
  const float* xb = X + (size_t)b * D_ * N_ + n;
  float xr[96];
#pragma unroll
  for (int c = 0; c < 96; ++c) xr[c] = xb[(size_t)c * N_];
  int o0 = og * 12;
  const float* Ws[3] = {wq, wk, wv};
  float* Os[3] = {QT, KT, VT};
#pragma unroll
  for (int t = 0; t < 3; ++t) {
    float acc[12];
#pragma unroll
    for (int j = 0; j < 12; ++j) {
      const float* wr = Ws[t] + (o0 + j) * 96;
      float a = 0.f;
#pragma unroll
      for (int c4 = 0; c4 < 96; c4 += 4) {
        float4 wv4 = *(const float4*)&wr[c4];
        a += wv4.x * xr[c4] + wv4.y * xr[c4 + 1] + wv4.z * xr[c4 + 2] + wv4.w * xr[c4 + 3];
      }
      acc[j] = a;
    }
    float* op = Os[t] + (size_t)g * 96 + o0;
    *(float4*)&op[0] = make_float4(acc[0], acc[1], acc[2], acc[3]);
    *(float4*)&op[4] = make_float4(acc[4], acc[5], acc[6], acc[7]);
    *(float4*)&op[8] = make_float4(acc[8], acc[9], acc[10], acc[11]);
  }
}

// W(16x32 rows of m-tile) @ Act(32x16) over 3 K-steps, 6 m-tiles; fp16 in, fp32 out.
// A frag: row = lane&15, k = s*32 + (lane>>4)*8 + j   (row-major fp16 W, stride 96)
// B frag: col(slot) = lane&15, k likewise; tile stored [slot][k], stride TSTR
// D frag: col(slot) = lane&15, row(channel) = m*16 + (lane>>4)*4 + r
__device__ __forceinline__ void mfma_stage(const unsigned short* __restrict__ Wh,
                                           const unsigned short* tw,
                                           int n16, int q4, f32x4 acc[6]) {
  half8 bfr[3];
#pragma unroll
  for (int s = 0; s < 3; ++s)
    bfr[s] = *(const half8*)&tw[n16 * TSTR + s * 32 + q4 * 8];
#pragma unroll
  for (int m = 0; m < 6; ++m) {
#pragma unroll
    for (int s = 0; s < 3; ++s) {
      half8 av = *(const half8*)&Wh[(m * 16 + n16) * 96 + s * 32 + q4 * 8];
      acc[m] = __builtin_amdgcn_mfma_f32_16x16x32_f16(av, bfr[s], acc[m], 0, 0, 0);
    }
  }
}

// ---------------- fused attention: 1 wave per point, 4 points/block, MFMA (proven R12) --------
__global__ void __launch_bounds__(256) k_attn(
    float* __restrict__ X, const float* __restrict__ QT, const float* __restrict__ KT,
    const float* __restrict__ VT, const float* __restrict__ pts, const int* __restrict__ IDX,
    const float* __restrict__ pw1, const float* __restrict__ pg, const float* __restrict__ pb_,
    const float* __restrict__ pm, const float* __restrict__ pv,
    const unsigned short* __restrict__ WH,
    const float* __restrict__ ag, const float* __restrict__ ab,
    const float* __restrict__ am, const float* __restrict__ av,
    const float* __restrict__ g1, const float* __restrict__ b1,
    const float* __restrict__ m1, const float* __restrict__ v1) {
  __shared__ __align__(16) unsigned short tile[4][16 * TSTR];
  __shared__ float pdif[4][3][16];
  __shared__ int sid[4][16];
  const int tid = threadIdx.x;
  const int l = tid & 63, w = tid >> 6;
  const int g = blockIdx.x * 4 + w;
  const int b = g >> 13, n = g & (N_ - 1);
  const int n16 = l & 15, q4 = l >> 4;
  unsigned short* tw = &tile[w][0];

  if (l < 16) {
    int nbr = IDX[g * K_ + l];
    sid[w][l] = nbr;
    const float* pq = pts + ((size_t)b * N_ + n) * 3;
    const float* pn = pts + ((size_t)b * N_ + nbr) * 3;
    pdif[w][0][l] = pq[0] - pn[0];
    pdif[w][1][l] = pq[1] - pn[1];
    pdif[w][2][l] = pq[2] - pn[2];
  }
  __syncthreads();

  {
    float p0 = pdif[w][0][n16], p1 = pdif[w][1][n16], p2 = pdif[w][2][n16];
    int c0 = q4 * 24;
#pragma unroll
    for (int ii = 0; ii < 24; ii += 2) {
      int c = c0 + ii;
      float vA = pw1[c * 3] * p0 + pw1[c * 3 + 1] * p1 + pw1[c * 3 + 2] * p2;
      float vB = pw1[(c + 1) * 3] * p0 + pw1[(c + 1) * 3 + 1] * p1 + pw1[(c + 1) * 3 + 2] * p2;
      vA = fmaxf(bn1(vA, pg[c], pb_[c], pm[c], pv[c]), 0.f);
      vB = fmaxf(bn1(vB, pg[c + 1], pb_[c + 1], pm[c + 1], pv[c + 1]), 0.f);
      unsigned u = (unsigned)f2h(vA) | ((unsigned)f2h(vB) << 16);
      *(unsigned*)&tw[n16 * TSTR + c] = u;
    }
  }
  __syncthreads();

  f32x4 pe2[6];
#pragma unroll
  for (int m = 0; m < 6; ++m) pe2[m] = (f32x4){0.f, 0.f, 0.f, 0.f};
  mfma_stage(WH, tw, n16, q4, pe2);
  __syncthreads();

  const int nbr = sid[w][n16];
  {
    const float* qt = QT + (size_t)g * 96;
    const float* kt = KT + ((size_t)b * N_ + nbr) * 96;
#pragma unroll
    for (int m = 0; m < 6; ++m) {
      int cb = m * 16 + q4 * 4;
      float4 qv = *(const float4*)&qt[cb];
      float4 kv = *(const float4*)&kt[cb];
      float v0 = qv.x - kv.x + pe2[m][0];
      float v1 = qv.y - kv.y + pe2[m][1];
      float v2 = qv.z - kv.z + pe2[m][2];
      float v3 = qv.w - kv.w + pe2[m][3];
      int idx = n16 * TSTR + cb;
      *(unsigned*)&tw[idx]     = (unsigned)f2h(v0) | ((unsigned)f2h(v1) << 16);
      *(unsigned*)&tw[idx + 2] = (unsigned)f2h(v2) | ((unsigned)f2h(v3) << 16);
    }
  }
  __syncthreads();

  {
    f32x4 t1[6];
#pragma unroll
    for (int m = 0; m < 6; ++m) t1[m] = (f32x4){0.f, 0.f, 0.f, 0.f};
    mfma_stage(WH + 9216, tw, n16, q4, t1);
    __syncthreads();
#pragma unroll
    for (int m = 0; m < 6; ++m) {
      int cb = m * 16 + q4 * 4;
      float v0 = fmaxf(bn1(t1[m][0], ag[cb], ab[cb], am[cb], av[cb]), 0.f);
      float v1 = fmaxf(bn1(t1[m][1], ag[cb + 1], ab[cb + 1], am[cb + 1], av[cb + 1]), 0.f);
      float v2 = fmaxf(bn1(t1[m][2], ag[cb + 2], ab[cb + 2], am[cb + 2], av[cb + 2]), 0.f);
      float v3 = fmaxf(bn1(t1[m][3], ag[cb + 3], ab[cb + 3], am[cb + 3], av[cb + 3]), 0.f);
      int idx = n16 * TSTR + cb;
      *(unsigned*)&tw[idx]     = (unsigned)f2h(v0) | ((unsigned)f2h(v1) << 16);
      *(unsigned*)&tw[idx + 2] = (unsigned)f2h(v2) | ((unsigned)f2h(v3) << 16);
    }
  }
  __syncthreads();

  {
    f32x4 a2[6];
#pragma unroll
    for (int m = 0; m < 6; ++m) a2[m] = (f32x4){0.f, 0.f, 0.f, 0.f};
    mfma_stage(WH + 18432, tw, n16, q4, a2);
    const float* vt = VT + ((size_t)b * N_ + nbr) * 96;
#pragma unroll
    for (int m = 0; m < 6; ++m) {
      int cb = m * 16 + q4 * 4;
      float4 vv = *(const float4*)&vt[cb];
      const float* vvp = (const float*)&vv;
      float ov[4];
#pragma unroll
      for (int r = 0; r < 4; ++r) {
        float a = a2[m][r];
        float mx = a;
        mx = fmaxf(mx, __shfl_xor(mx, 1));
        mx = fmaxf(mx, __shfl_xor(mx, 2));
        mx = fmaxf(mx, __shfl_xor(mx, 4));
        mx = fmaxf(mx, __shfl_xor(mx, 8));
        float e = expf(a - mx);
        float s = e;
        s += __shfl_xor(s, 1); s += __shfl_xor(s, 2); s += __shfl_xor(s, 4); s += __shfl_xor(s, 8);
        float c = e * (vvp[r] + pe2[m][r]);
        c += __shfl_xor(c, 1); c += __shfl_xor(c, 2); c += __shfl_xor(c, 4); c += __shfl_xor(c, 8);
        ov[r] = c / s;
      }
      if (n16 == 0) {
#pragma unroll
        for (int r = 0; r < 4; ++r) {
          int c = cb + r;
          size_t xi = ((size_t)b * D_ + c) * N_ + n;
          float t = X[xi] + ov[r];
          X[xi] = (t - m1[c]) * (g1[c] * (1.0f / sqrtf(v1[c] + EPS_))) + b1[c];
        }
      }
    }
  }
}

// ---------------- FFN: MFMA, 1 wave per 16 points, 4 waves/block (proven R14) ----------------
__global__ void __launch_bounds__(256) k_ffn(
    float* __restrict__ X, const unsigned short* __restrict__ WF,
    const float* __restrict__ fg, const float* __restrict__ fb,
    const float* __restrict__ fm, const float* __restrict__ fv,
    const float* __restrict__ g2, const float* __restrict__ b2,
    const float* __restrict__ m2, const float* __restrict__ v2) {
  __shared__ __align__(16) unsigned short t1s[4][16 * TSTR];   // x fp16: [pt][c]
  __shared__ __align__(16) unsigned short t2s[4][16 * T2STR];  // h fp16: [pt][j]
  const int tid = threadIdx.x;
  const int l = tid & 63, w = tid >> 6;
  const int n16 = l & 15, q4 = l >> 4;
  const int p0 = blockIdx.x * 64 + w * 16;   // first point of this wave (64 pts/block, no b crossing)
  const int b = p0 >> 13;
  const int nn = p0 & (N_ - 1);
  unsigned short* x1 = &t1s[w][0];
  unsigned short* h1 = &t2s[w][0];

  // phase 1: x tile -> fp16 LDS [point][channel]
  {
    const float* xb = X + (size_t)b * D_ * N_ + nn + n16;
    int c0 = q4 * 24;
#pragma unroll
    for (int i = 0; i < 24; ++i) {
      int c = c0 + i;
      x1[n16 * TSTR + c] = f2h(xb[(size_t)c * N_]);
    }
  }
  __syncthreads();

  // phase 2: h = relu(bn_f(W1 @ x))  (12 m-tiles x 3 k-steps) -> h tile
  {
    f32x4 acc[12];
#pragma unroll
    for (int m = 0; m < 12; ++m) acc[m] = (f32x4){0.f, 0.f, 0.f, 0.f};
    half8 bfr[3];
#pragma unroll
    for (int s = 0; s < 3; ++s) bfr[s] = *(const half8*)&x1[n16 * TSTR + s * 32 + q4 * 8];
#pragma unroll
    for (int m = 0; m < 12; ++m) {
#pragma unroll
      for (int s = 0; s < 3; ++s) {
        half8 av = *(const half8*)&WF[(m * 16 + n16) * 96 + s * 32 + q4 * 8];
        acc[m] = __builtin_amdgcn_mfma_f32_16x16x32_f16(av, bfr[s], acc[m], 0, 0, 0);
      }
    }
    __syncthreads();  // x tile fully consumed before h writes begin
#pragma unroll
    for (int m = 0; m < 12; ++m) {
      int jb = m * 16 + q4 * 4;
#pragma unroll
      for (int r = 0; r < 4; ++r) {
        int j = jb + r;
        float hv = fmaxf(bn1(acc[m][r], fg[j], fb[j], fm[j], fv[j]), 0.f);
        h1[n16 * T2STR + j] = f2h(hv);
      }
    }
  }
  __syncthreads();

  // phase 3: out = W2 @ h (6 m-tiles x 6 k-steps) ; residual + bn2 -> X
  {
    const unsigned short* W2h = WF + 18432;
    f32x4 acc[6];
#pragma unroll
    for (int m = 0; m < 6; ++m) acc[m] = (f32x4){0.f, 0.f, 0.f, 0.f};
    half8 bfr[6];
#pragma unroll
    for (int s = 0; s < 6; ++s) bfr[s] = *(const half8*)&h1[n16 * T2STR + s * 32 + q4 * 8];
#pragma unroll
    for (int m = 0; m < 6; ++m) {
#pragma unroll
      for (int s = 0; s < 6; ++s) {
        half8 av = *(const half8*)&W2h[(m * 16 + n16) * 192 + s * 32 + q4 * 8];
        acc[m] = __builtin_amdgcn_mfma_f32_16x16x32_f16(av, bfr[s], acc[m], 0, 0, 0);
      }
    }
#pragma unroll
    for (int m = 0; m < 6; ++m) {
      int cb = m * 16 + q4 * 4;
#pragma unroll
      for (int r = 0; r < 4; ++r) {
        int c = cb + r;
        size_t xi = ((size_t)b * D_ + c) * N_ + nn + n16;
        float t = X[xi] + acc[m][r];
        X[xi] = bn1(t, g2[c], b2[c], m2[c], v2[c]);
      }
    }
  }
}

// ---------------- head: proven baseline version ----------------
__global__ void k_head(const float* __restrict__ X, const float* __restrict__ w1,
                       const float* __restrict__ hg, const float* __restrict__ hbb,
                       const float* __restrict__ hm, const float* __restrict__ hv,
                       const float* __restrict__ w2, const float* __restrict__ hb2,
                       float* __restrict__ OUT) {
  int gid = blockIdx.x * 256 + threadIdx.x;
  int b = gid / N_, n = gid % N_;
  const float* xb = X + b * D_ * N_ + n;
  float xr[D_];
#pragma unroll
  for (int c = 0; c < D_; ++c) xr[c] = xb[c * N_];
  float a0 = 0.f, a1 = 0.f;
  for (int j = 0; j < 128; ++j) {
    float acc = 0.f;
#pragma unroll
    for (int c = 0; c < D_; ++c) acc += w1[j * D_ + c] * xr[c];
    float t = fmaxf(bn1(acc, hg[j], hbb[j], hm[j], hv[j]), 0.0f);
    a0 += w2[j] * t;
    a1 += w2[128 + j] * t;
  }
  OUT[(b * NC_ + 0) * N_ + n] = a0 + hb2[0];
  OUT[(b * NC_ + 1) * N_ + n] = a1 + hb2[1];
}

extern "C" void kernel_launch(void* const* d_in, const int* in_sizes, int n_in,
                              void* d_out, int out_size, void* d_ws, size_t ws_size,
                              hipStream_t stream) {
  (void)in_sizes; (void)n_in; (void)out_size;
  const float* pts     = (const float*)d_in[0];
  const float* embed_w = (const float*)d_in[1];
  const float* embed_g = (const float*)d_in[2];
  const float* embed_b = (const float*)d_in[3];
  const float* embed_m = (const float*)d_in[4];
  const float* embed_v = (const float*)d_in[5];
  const float* wq      = (const float*)d_in[6];
  const float* wk      = (const float*)d_in[7];
  const float* wv      = (const float*)d_in[8];
  const float* pe_w1   = (const float*)d_in[9];
  const float* pe_g    = (const float*)d_in[10];
  const float* pe_b    = (const float*)d_in[11];
  const float* pe_m    = (const float*)d_in[12];
  const float* pe_v    = (const float*)d_in[13];
  const float* pe_w2   = (const float*)d_in[14];
  const float* am_w1   = (const float*)d_in[15];
  const float* am_g    = (const float*)d_in[16];
  const float* am_b    = (const float*)d_in[17];
  const float* am_m    = (const float*)d_in[18];
  const float* am_v    = (const float*)d_in[19];
  const float* am_w2   = (const float*)d_in[20];
  const float* n1_g    = (const float*)d_in[21];
  const float* n1_b    = (const float*)d_in[22];
  const float* n1_m    = (const float*)d_in[23];
  const float* n1_v    = (const float*)d_in[24];
  const float* ffn_w1  = (const float*)d_in[25];
  const float* f_g     = (const float*)d_in[26];
  const float* f_b     = (const float*)d_in[27];
  const float* f_m     = (const float*)d_in[28];
  const float* f_v     = (const float*)d_in[29];
  const float* ffn_w2  = (const float*)d_in[30];
  const float* n2_g    = (const float*)d_in[31];
  const float* n2_b    = (const float*)d_in[32];
  const float* n2_m    = (const float*)d_in[33];
  const float* n2_v    = (const float*)d_in[34];
  const float* hd_w1   = (const float*)d_in[35];
  const float* hd_g    = (const float*)d_in[36];
  const float* hd_b    = (const float*)d_in[37];
  const float* hd_m    = (const float*)d_in[38];
  const float* hd_v    = (const float*)d_in[39];
  const float* hd_w2   = (const float*)d_in[40];
  const float* hd_b2   = (const float*)d_in[41];

  // ws budget identical to proven layout. Attn fp16 weights live in SQ's dead space
  // (55,296 B <= 65,536 B, dead after k_knn); ffn fp16 weights live in KT's head
  // (73,728 B << 6.29 MB, dead between k_attn(l) and k_qkv(l+1)).
  const size_t NEED = (size_t)(4 * B_ * D_ * N_ + B_ * N_ + B_ * N_ * K_) * 4;
  if (ws_size < NEED) return;

  float* ws = (float*)d_ws;
  float* X  = ws;
  float* QT = X  + (size_t)B_ * D_ * N_;
  float* KT = QT + (size_t)B_ * N_ * D_;
  float* VT = KT + (size_t)B_ * N_ * D_;
  float* SQ = VT + (size_t)B_ * N_ * D_;
  int*   IDX = (int*)(SQ + (size_t)B_ * N_);
  unsigned short* WH = (unsigned short*)SQ;  // attn weights, alive only after k_knn
  unsigned short* WF = (unsigned short*)KT;  // ffn weights, alive attn(l) -> ffn(l)

  k_embed<<<B_ * N_ / 256, 256, 0, stream>>>(pts, embed_w, embed_g, embed_b, embed_m, embed_v, X, SQ);
  k_knn<<<B_ * N_ / 4, 256, 0, stream>>>(pts, SQ, IDX);
  for (int l = 0; l < L_; ++l) {
    k_prep_wl<<<36, 256, 0, stream>>>(pe_w2 + l * D_ * D_, am_w1 + l * D_ * D_, am_w2 + l * D_ * D_, WH);
    k_qkv<<<B_ * N_ / 32, 256, 0, stream>>>(X, wq + l * D_ * D_, wk + l * D_ * D_, wv + l * D_ * D_, QT, KT, VT);
    k_attn<<<B_ * N_ / 4, 256, 0, stream>>>(X, QT, KT, VT, pts, IDX,
        pe_w1 + l * D_ * 3, pe_g + l * D_, pe_b + l * D_, pe_m + l * D_, pe_v + l * D_,
        WH,
        am_g + l * D_, am_b + l * D_, am_m + l * D_, am_v + l * D_,
        n1_g + l * D_, n1_b + l * D_, n1_m + l * D_, n1_v + l * D_);
    k_prep_ffn<<<72, 256, 0, stream>>>(ffn_w1 + l * H_ * D_, ffn_w2 + l * D_ * H_, WF);
    k_ffn<<<B_ * N_ / 64, 256, 0, stream>>>(X, WF,
        f_g + l * H_, f_b + l * H_, f_m + l * H_, f_v + l * H_,
        n2_g + l * D_, n2_b + l * D_, n2_m + l * D_, n2_v + l * D_);
  }
  k_head<<<B_ * N_ / 256, 256, 0, stream>>>(X, hd_w1, hd_g, hd_b, hd_m, hd_v, hd_w2, hd_b2, (float*)d_out);
}

// Round 16
// 1614.878 us; speedup vs baseline: 2.3938x; 1.0029x over previous
//
#include <hip/hip_runtime.h>

#define B_ 2
#define N_ 8192
#define D_ 96
#define L_ 4
#define H_ 192
#define K_ 16
#define NC_ 2
#define EPS_ 1e-5f
#define BIGF 3.402823466e38f
#define TSTR 104   // padded LDS stride (fp16 elems) for 96-wide tiles — proven in R12
#define T2STR 200  // padded LDS stride for 192-wide h tile (~2-way conflicts, free)

typedef _Float16 half8 __attribute__((ext_vector_type(8)));
typedef float f32x4 __attribute__((ext_vector_type(4)));

__device__ __forceinline__ float bn1(float x, float g, float b, float m, float v) {
  return (x - m) * (g * (1.0f / sqrtf(v + EPS_))) + b;
}

__device__ __forceinline__ unsigned short f2h(float x) {
  union { _Float16 h; unsigned short u; } c;
  c.h = (_Float16)x;
  return c.u;
}

// ---------------- embed + packed candidate data (xyz + squared norm) ----------
__global__ void k_embed(const float* __restrict__ pts, const float* __restrict__ w,
                        const float* __restrict__ g, const float* __restrict__ bb,
                        const float* __restrict__ m, const float* __restrict__ v,
                        float* __restrict__ X, float4* __restrict__ P4) {
  int gid = blockIdx.x * 256 + threadIdx.x;
  int b = gid / N_, n = gid % N_;
  float p0 = pts[gid * 3], p1 = pts[gid * 3 + 1], p2 = pts[gid * 3 + 2];
  // exact numpy-order fp32 arithmetic (feeds KNN selection)
  float sq = __fadd_rn(__fadd_rn(__fmul_rn(p0, p0), __fmul_rn(p1, p1)), __fmul_rn(p2, p2));
  P4[gid] = make_float4(p0, p1, p2, sq);
  for (int o = 0; o < D_; ++o) {
    float e = w[o * 3] * p0 + w[o * 3 + 1] * p1 + w[o * 3 + 2] * p2;
    X[(b * D_ + o) * N_ + n] = fmaxf(bn1(e, g[o], bb[o], m[o], v[o]), 0.0f);
  }
}

// ---------------- KNN v2 + float4 candidate loads (one dwordx4 per candidate) -------------
// Threshold T via 6 branchless shfls: group-of-4 min (2) then max over 16 groups (4).
// The 16 group minima are 16 DISTINCT candidates with d <= T  =>  T >= true 16th-smallest
// distance  =>  gating the exact insertion network on d <= T is lossless.
__global__ void k_knn(const float4* __restrict__ P4, int* __restrict__ IDX) {
  int lane = threadIdx.x & 63;
  int g = blockIdx.x * 4 + (threadIdx.x >> 6);
  int b = g / N_, n = g % N_;
  const float4* Pb = P4 + (size_t)b * N_;
  float4 qp = Pb[n];
  const float qx = qp.x, qy = qp.y, qz = qp.z, sqn = qp.w;

  // pass 1: branchless per-lane running min (exact numpy-order arithmetic)
  float lmin = BIGF;
  for (int j = 0; j < N_ / 64; ++j) {
    float4 cp = Pb[lane + j * 64];
    float dot = __fadd_rn(__fadd_rn(__fmul_rn(qx, cp.x), __fmul_rn(qy, cp.y)), __fmul_rn(qz, cp.z));
    float d = __fsub_rn(__fadd_rn(sqn, cp.w), __fmul_rn(2.0f, dot));
    lmin = fminf(lmin, d);
  }
  // group-of-4 min, then max across the 16 groups -> lossless threshold T
  float gm = fminf(lmin, __shfl_xor(lmin, 1));
  gm = fminf(gm, __shfl_xor(gm, 2));
  float T = gm;
  T = fmaxf(T, __shfl_xor(T, 4));
  T = fmaxf(T, __shfl_xor(T, 8));
  T = fmaxf(T, __shfl_xor(T, 16));
  T = fmaxf(T, __shfl_xor(T, 32));

  // pass 2: identical distance arithmetic; proven insertion network gated on d <= T
  float bd[K_]; int bi[K_];
#pragma unroll
  for (int s = 0; s < K_; ++s) { bd[s] = BIGF; bi[s] = 0x7fffffff; }
  float wd = BIGF; int wi = 0x7fffffff; int wslot = 0;
  for (int j = 0; j < N_ / 64; ++j) {
    int cand = lane + j * 64;
    float4 cp = Pb[cand];
    float dot = __fadd_rn(__fadd_rn(__fmul_rn(qx, cp.x), __fmul_rn(qy, cp.y)), __fmul_rn(qz, cp.z));
    float d = __fsub_rn(__fadd_rn(sqn, cp.w), __fmul_rn(2.0f, dot));
    bool take = (d <= T) && (d < wd || (d == wd && cand < wi));
    if (take) {
#pragma unroll
      for (int s = 0; s < K_; ++s) if (s == wslot) { bd[s] = d; bi[s] = cand; }
      wd = -BIGF; wi = -1;
#pragma unroll
      for (int s = 0; s < K_; ++s) {
        bool worse = (bd[s] > wd) || (bd[s] == wd && bi[s] > wi);
        if (worse) { wd = bd[s]; wi = bi[s]; wslot = s; }
      }
    }
  }

  // merge 64 lanes' candidates -> global top-16 (byte-identical to proven R1 merge)
  for (int r = 0; r < K_; ++r) {
    float md = BIGF; int mi = 0x7fffffff;
#pragma unroll
    for (int s = 0; s < K_; ++s) {
      bool better = (bd[s] < md) || (bd[s] == md && bi[s] < mi);
      if (better) { md = bd[s]; mi = bi[s]; }
    }
#pragma unroll
    for (int off = 32; off > 0; off >>= 1) {
      float od = __shfl_xor(md, off);
      int oi = __shfl_xor(mi, off);
      bool better = (od < md) || (od == md && oi < mi);
      if (better) { md = od; mi = oi; }
    }
#pragma unroll
    for (int s = 0; s < K_; ++s) if (bi[s] == mi) { bd[s] = BIGF; bi[s] = 0x7fffffff; }
    if (lane == 0) IDX[g * K_ + r] = mi;
  }
}

// ---------------- per-layer attn weight prep: fp32 -> fp16 into SQ dead space ------------
__global__ void k_prep_wl(const float* __restrict__ pw2, const float* __restrict__ aw1,
                          const float* __restrict__ aw2, unsigned short* __restrict__ WH) {
  int i = blockIdx.x * 256 + threadIdx.x;  // 9216 = D_*D_; grid 36
  WH[i]         = f2h(pw2[i]);
  WH[9216 + i]  = f2h(aw1[i]);
  WH[18432 + i] = f2h(aw2[i]);
}

// ---------------- per-layer ffn weight prep: fp32 -> fp16 into KT dead space ------------
__global__ void k_prep_ffn(const float* __restrict__ w1, const float* __restrict__ w2,
                           unsigned short* __restrict__ WF) {
  int i = blockIdx.x * 256 + threadIdx.x;  // 18432 = H_*D_; grid 72
  WF[i]         = f2h(w1[i]);
  WF[18432 + i] = f2h(w2[i]);
}

// ---------------- QKV: 32 pts x 8 o-groups per block (512 blocks) ----------------
__global__ void __launch_bounds__(256) k_qkv(const float* __restrict__ X, const float* __restrict__ wq,
                      const float* __restrict__ wk, const float* __restrict__ wv,
                      float* __restrict__ QT, float* __restrict__ KT, float* __restrict__ VT) {
  int tid = threadIdx.x;
  int pl = tid & 31, og = tid >> 5;
  int g = blockIdx.x * 32 + pl;
  int b = g >> 13, n = g & (N_ - 1);
  const float* xb = X + (size_t)b * D_ * N_ + n;
  float xr[96];
#pragma unroll
  for (int c = 0; c < 96; ++c) xr[c] = xb[(size_t)c * N_];
  int o0 = og * 12;
  const float* Ws[3] = {wq, wk, wv};
  float* Os[3] = {QT, KT, VT};
#pragma unroll
  for (int t = 0; t < 3; ++t) {
    float acc[12];
#pragma unroll
    for (int j = 0; j < 12; ++j) {
      const float* wr = Ws[t] + (o0 + j) * 96;
      float a = 0.f;
#pragma unroll
      for (int c4 = 0; c4 < 96; c4 += 4) {
        float4 wv4 = *(const float4*)&wr[c4];
        a += wv4.x * xr[c4] + wv4.y * xr[c4 + 1] + wv4.z * xr[c4 + 2] + wv4.w * xr[c4 + 3];
      }
      acc[j] = a;
    }
    float* op = Os[t] + (size_t)g * 96 + o0;
    *(float4*)&op[0] = make_float4(acc[0], acc[1], acc[2], acc[3]);
    *(float4*)&op[4] = make_float4(acc[4], acc[5], acc[6], acc[7]);
    *(float4*)&op[8] = make_float4(acc[8], acc[9], acc[10], acc[11]);
  }
}

// W(16x32 rows of m-tile) @ Act(32x16) over 3 K-steps, 6 m-tiles; fp16 in, fp32 out.
// A frag: row = lane&15, k = s*32 + (lane>>4)*8 + j   (row-major fp16 W, stride 96)
// B frag: col(slot) = lane&15, k likewise; tile stored [slot][k], stride TSTR
// D frag: col(slot) = lane&15, row(channel) = m*16 + (lane>>4)*4 + r
__device__ __forceinline__ void mfma_stage(const unsigned short* __restrict__ Wh,
                                           const unsigned short* tw,
                                           int n16, int q4, f32x4 acc[6]) {
  half8 bfr[3];
#pragma unroll
  for (int s = 0; s < 3; ++s)
    bfr[s] = *(const half8*)&tw[n16 * TSTR + s * 32 + q4 * 8];
#pragma unroll
  for (int m = 0; m < 6; ++m) {
#pragma unroll
    for (int s = 0; s < 3; ++s) {
      half8 av = *(const half8*)&Wh[(m * 16 + n16) * 96 + s * 32 + q4 * 8];
      acc[m] = __builtin_amdgcn_mfma_f32_16x16x32_f16(av, bfr[s], acc[m], 0, 0, 0);
    }
  }
}

// ---------------- fused attention: 1 wave per point, 4 points/block, MFMA (proven R12) --------
__global__ void __launch_bounds__(256) k_attn(
    float* __restrict__ X, const float* __restrict__ QT, const float* __restrict__ KT,
    const float* __restrict__ VT, const float* __restrict__ pts, const int* __restrict__ IDX,
    const float* __restrict__ pw1, const float* __restrict__ pg, const float* __restrict__ pb_,
    const float* __restrict__ pm, const float* __restrict__ pv,
    const unsigned short* __restrict__ WH,
    const float* __restrict__ ag, const float* __restrict__ ab,
    const float* __restrict__ am, const float* __restrict__ av,
    const float* __restrict__ g1, const float* __restrict__ b1,
    const float* __restrict__ m1, const float* __restrict__ v1) {
  __shared__ __align__(16) unsigned short tile[4][16 * TSTR];
  __shared__ float pdif[4][3][16];
  __shared__ int sid[4][16];
  const int tid = threadIdx.x;
  const int l = tid & 63, w = tid >> 6;
  const int g = blockIdx.x * 4 + w;
  const int b = g >> 13, n = g & (N_ - 1);
  const int n16 = l & 15, q4 = l >> 4;
  unsigned short* tw = &tile[w][0];

  if (l < 16) {
    int nbr = IDX[g * K_ + l];
    sid[w][l] = nbr;
    const float* pq = pts + ((size_t)b * N_ + n) * 3;
    const float* pn = pts + ((size_t)b * N_ + nbr) * 3;
    pdif[w][0][l] = pq[0] - pn[0];
    pdif[w][1][l] = pq[1] - pn[1];
    pdif[w][2][l] = pq[2] - pn[2];
  }
  __syncthreads();

  {
    float p0 = pdif[w][0][n16], p1 = pdif[w][1][n16], p2 = pdif[w][2][n16];
    int c0 = q4 * 24;
#pragma unroll
    for (int ii = 0; ii < 24; ii += 2) {
      int c = c0 + ii;
      float vA = pw1[c * 3] * p0 + pw1[c * 3 + 1] * p1 + pw1[c * 3 + 2] * p2;
      float vB = pw1[(c + 1) * 3] * p0 + pw1[(c + 1) * 3 + 1] * p1 + pw1[(c + 1) * 3 + 2] * p2;
      vA = fmaxf(bn1(vA, pg[c], pb_[c], pm[c], pv[c]), 0.f);
      vB = fmaxf(bn1(vB, pg[c + 1], pb_[c + 1], pm[c + 1], pv[c + 1]), 0.f);
      unsigned u = (unsigned)f2h(vA) | ((unsigned)f2h(vB) << 16);
      *(unsigned*)&tw[n16 * TSTR + c] = u;
    }
  }
  __syncthreads();

  f32x4 pe2[6];
#pragma unroll
  for (int m = 0; m < 6; ++m) pe2[m] = (f32x4){0.f, 0.f, 0.f, 0.f};
  mfma_stage(WH, tw, n16, q4, pe2);
  __syncthreads();

  const int nbr = sid[w][n16];
  {
    const float* qt = QT + (size_t)g * 96;
    const float* kt = KT + ((size_t)b * N_ + nbr) * 96;
#pragma unroll
    for (int m = 0; m < 6; ++m) {
      int cb = m * 16 + q4 * 4;
      float4 qv = *(const float4*)&qt[cb];
      float4 kv = *(const float4*)&kt[cb];
      float v0 = qv.x - kv.x + pe2[m][0];
      float v1 = qv.y - kv.y + pe2[m][1];
      float v2 = qv.z - kv.z + pe2[m][2];
      float v3 = qv.w - kv.w + pe2[m][3];
      int idx = n16 * TSTR + cb;
      *(unsigned*)&tw[idx]     = (unsigned)f2h(v0) | ((unsigned)f2h(v1) << 16);
      *(unsigned*)&tw[idx + 2] = (unsigned)f2h(v2) | ((unsigned)f2h(v3) << 16);
    }
  }
  __syncthreads();

  {
    f32x4 t1[6];
#pragma unroll
    for (int m = 0; m < 6; ++m) t1[m] = (f32x4){0.f, 0.f, 0.f, 0.f};
    mfma_stage(WH + 9216, tw, n16, q4, t1);
    __syncthreads();
#pragma unroll
    for (int m = 0; m < 6; ++m) {
      int cb = m * 16 + q4 * 4;
      float v0 = fmaxf(bn1(t1[m][0], ag[cb], ab[cb], am[cb], av[cb]), 0.f);
      float v1 = fmaxf(bn1(t1[m][1], ag[cb + 1], ab[cb + 1], am[cb + 1], av[cb + 1]), 0.f);
      float v2 = fmaxf(bn1(t1[m][2], ag[cb + 2], ab[cb + 2], am[cb + 2], av[cb + 2]), 0.f);
      float v3 = fmaxf(bn1(t1[m][3], ag[cb + 3], ab[cb + 3], am[cb + 3], av[cb + 3]), 0.f);
      int idx = n16 * TSTR + cb;
      *(unsigned*)&tw[idx]     = (unsigned)f2h(v0) | ((unsigned)f2h(v1) << 16);
      *(unsigned*)&tw[idx + 2] = (unsigned)f2h(v2) | ((unsigned)f2h(v3) << 16);
    }
  }
  __syncthreads();

  {
    f32x4 a2[6];
#pragma unroll
    for (int m = 0; m < 6; ++m) a2[m] = (f32x4){0.f, 0.f, 0.f, 0.f};
    mfma_stage(WH + 18432, tw, n16, q4, a2);
    const float* vt = VT + ((size_t)b * N_ + nbr) * 96;
#pragma unroll
    for (int m = 0; m < 6; ++m) {
      int cb = m * 16 + q4 * 4;
      float4 vv = *(const float4*)&vt[cb];
      const float* vvp = (const float*)&vv;
      float ov[4];
#pragma unroll
      for (int r = 0; r < 4; ++r) {
        float a = a2[m][r];
        float mx = a;
        mx = fmaxf(mx, __shfl_xor(mx, 1));
        mx = fmaxf(mx, __shfl_xor(mx, 2));
        mx = fmaxf(mx, __shfl_xor(mx, 4));
        mx = fmaxf(mx, __shfl_xor(mx, 8));
        float e = expf(a - mx);
        float s = e;
        s += __shfl_xor(s, 1); s += __shfl_xor(s, 2); s += __shfl_xor(s, 4); s += __shfl_xor(s, 8);
        float c = e * (vvp[r] + pe2[m][r]);
        c += __shfl_xor(c, 1); c += __shfl_xor(c, 2); c += __shfl_xor(c, 4); c += __shfl_xor(c, 8);
        ov[r] = c / s;
      }
      if (n16 == 0) {
#pragma unroll
        for (int r = 0; r < 4; ++r) {
          int c = cb + r;
          size_t xi = ((size_t)b * D_ + c) * N_ + n;
          float t = X[xi] + ov[r];
          X[xi] = (t - m1[c]) * (g1[c] * (1.0f / sqrtf(v1[c] + EPS_))) + b1[c];
        }
      }
    }
  }
}

// ---------------- FFN: MFMA, 1 wave per 16 points, 4 waves/block (proven R14) ----------------
__global__ void __launch_bounds__(256) k_ffn(
    float* __restrict__ X, const unsigned short* __restrict__ WF,
    const float* __restrict__ fg, const float* __restrict__ fb,
    const float* __restrict__ fm, const float* __restrict__ fv,
    const float* __restrict__ g2, const float* __restrict__ b2,
    const float* __restrict__ m2, const float* __restrict__ v2) {
  __shared__ __align__(16) unsigned short t1s[4][16 * TSTR];   // x fp16: [pt][c]
  __shared__ __align__(16) unsigned short t2s[4][16 * T2STR];  // h fp16: [pt][j]
  const int tid = threadIdx.x;
  const int l = tid & 63, w = tid >> 6;
  const int n16 = l & 15, q4 = l >> 4;
  const int p0 = blockIdx.x * 64 + w * 16;   // first point of this wave (64 pts/block, no b crossing)
  const int b = p0 >> 13;
  const int nn = p0 & (N_ - 1);
  unsigned short* x1 = &t1s[w][0];
  unsigned short* h1 = &t2s[w][0];

  // phase 1: x tile -> fp16 LDS [point][channel]
  {
    const float* xb = X + (size_t)b * D_ * N_ + nn + n16;
    int c0 = q4 * 24;
#pragma unroll
    for (int i = 0; i < 24; ++i) {
      int c = c0 + i;
      x1[n16 * TSTR + c] = f2h(xb[(size_t)c * N_]);
    }
  }
  __syncthreads();

  // phase 2: h = relu(bn_f(W1 @ x))  (12 m-tiles x 3 k-steps) -> h tile
  {
    f32x4 acc[12];
#pragma unroll
    for (int m = 0; m < 12; ++m) acc[m] = (f32x4){0.f, 0.f, 0.f, 0.f};
    half8 bfr[3];
#pragma unroll
    for (int s = 0; s < 3; ++s) bfr[s] = *(const half8*)&x1[n16 * TSTR + s * 32 + q4 * 8];
#pragma unroll
    for (int m = 0; m < 12; ++m) {
#pragma unroll
      for (int s = 0; s < 3; ++s) {
        half8 av = *(const half8*)&WF[(m * 16 + n16) * 96 + s * 32 + q4 * 8];
        acc[m] = __builtin_amdgcn_mfma_f32_16x16x32_f16(av, bfr[s], acc[m], 0, 0, 0);
      }
    }
    __syncthreads();  // x tile fully consumed before h writes begin
#pragma unroll
    for (int m = 0; m < 12; ++m) {
      int jb = m * 16 + q4 * 4;
#pragma unroll
      for (int r = 0; r < 4; ++r) {
        int j = jb + r;
        float hv = fmaxf(bn1(acc[m][r], fg[j], fb[j], fm[j], fv[j]), 0.f);
        h1[n16 * T2STR + j] = f2h(hv);
      }
    }
  }
  __syncthreads();

  // phase 3: out = W2 @ h (6 m-tiles x 6 k-steps) ; residual + bn2 -> X
  {
    const unsigned short* W2h = WF + 18432;
    f32x4 acc[6];
#pragma unroll
    for (int m = 0; m < 6; ++m) acc[m] = (f32x4){0.f, 0.f, 0.f, 0.f};
    half8 bfr[6];
#pragma unroll
    for (int s = 0; s < 6; ++s) bfr[s] = *(const half8*)&h1[n16 * T2STR + s * 32 + q4 * 8];
#pragma unroll
    for (int m = 0; m < 6; ++m) {
#pragma unroll
      for (int s = 0; s < 6; ++s) {
        half8 av = *(const half8*)&W2h[(m * 16 + n16) * 192 + s * 32 + q4 * 8];
        acc[m] = __builtin_amdgcn_mfma_f32_16x16x32_f16(av, bfr[s], acc[m], 0, 0, 0);
      }
    }
#pragma unroll
    for (int m = 0; m < 6; ++m) {
      int cb = m * 16 + q4 * 4;
#pragma unroll
      for (int r = 0; r < 4; ++r) {
        int c = cb + r;
        size_t xi = ((size_t)b * D_ + c) * N_ + nn + n16;
        float t = X[xi] + acc[m][r];
        X[xi] = bn1(t, g2[c], b2[c], m2[c], v2[c]);
      }
    }
  }
}

// ---------------- head: proven baseline version ----------------
__global__ void k_head(const float* __restrict__ X, const float* __restrict__ w1,
                       const float* __restrict__ hg, const float* __restrict__ hbb,
                       const float* __restrict__ hm, const float* __restrict__ hv,
                       const float* __restrict__ w2, const float* __restrict__ hb2,
                       float* __restrict__ OUT) {
  int gid = blockIdx.x * 256 + threadIdx.x;
  int b = gid / N_, n = gid % N_;
  const float* xb = X + b * D_ * N_ + n;
  float xr[D_];
#pragma unroll
  for (int c = 0; c < D_; ++c) xr[c] = xb[c * N_];
  float a0 = 0.f, a1 = 0.f;
  for (int j = 0; j < 128; ++j) {
    float acc = 0.f;
#pragma unroll
    for (int c = 0; c < D_; ++c) acc += w1[j * D_ + c] * xr[c];
    float t = fmaxf(bn1(acc, hg[j], hbb[j], hm[j], hv[j]), 0.0f);
    a0 += w2[j] * t;
    a1 += w2[128 + j] * t;
  }
  OUT[(b * NC_ + 0) * N_ + n] = a0 + hb2[0];
  OUT[(b * NC_ + 1) * N_ + n] = a1 + hb2[1];
}

extern "C" void kernel_launch(void* const* d_in, const int* in_sizes, int n_in,
                              void* d_out, int out_size, void* d_ws, size_t ws_size,
                              hipStream_t stream) {
  (void)in_sizes; (void)n_in; (void)out_size;
  const float* pts     = (const float*)d_in[0];
  const float* embed_w = (const float*)d_in[1];
  const float* embed_g = (const float*)d_in[2];
  const float* embed_b = (const float*)d_in[3];
  const float* embed_m = (const float*)d_in[4];
  const float* embed_v = (const float*)d_in[5];
  const float* wq      = (const float*)d_in[6];
  const float* wk      = (const float*)d_in[7];
  const float* wv      = (const float*)d_in[8];
  const float* pe_w1   = (const float*)d_in[9];
  const float* pe_g    = (const float*)d_in[10];
  const float* pe_b    = (const float*)d_in[11];
  const float* pe_m    = (const float*)d_in[12];
  const float* pe_v    = (const float*)d_in[13];
  const float* pe_w2   = (const float*)d_in[14];
  const float* am_w1   = (const float*)d_in[15];
  const float* am_g    = (const float*)d_in[16];
  const float* am_b    = (const float*)d_in[17];
  const float* am_m    = (const float*)d_in[18];
  const float* am_v    = (const float*)d_in[19];
  const float* am_w2   = (const float*)d_in[20];
  const float* n1_g    = (const float*)d_in[21];
  const float* n1_b    = (const float*)d_in[22];
  const float* n1_m    = (const float*)d_in[23];
  const float* n1_v    = (const float*)d_in[24];
  const float* ffn_w1  = (const float*)d_in[25];
  const float* f_g     = (const float*)d_in[26];
  const float* f_b     = (const float*)d_in[27];
  const float* f_m     = (const float*)d_in[28];
  const float* f_v     = (const float*)d_in[29];
  const float* ffn_w2  = (const float*)d_in[30];
  const float* n2_g    = (const float*)d_in[31];
  const float* n2_b    = (const float*)d_in[32];
  const float* n2_m    = (const float*)d_in[33];
  const float* n2_v    = (const float*)d_in[34];
  const float* hd_w1   = (const float*)d_in[35];
  const float* hd_g    = (const float*)d_in[36];
  const float* hd_b    = (const float*)d_in[37];
  const float* hd_m    = (const float*)d_in[38];
  const float* hd_v    = (const float*)d_in[39];
  const float* hd_w2   = (const float*)d_in[40];
  const float* hd_b2   = (const float*)d_in[41];

  // ws layout identical to proven R14/R15. Aliases (all liveness-disjoint, proven pattern):
  //   P4 (262,144 B) in QT head: written by k_embed, read by k_knn, dead at first k_qkv.
  //   WH (55,296 B) in SQ space: attn fp16 weights, alive after k_knn.
  //   WF (73,728 B) in KT head: ffn fp16 weights, alive attn(l) -> ffn(l).
  const size_t NEED = (size_t)(4 * B_ * D_ * N_ + B_ * N_ + B_ * N_ * K_) * 4;
  if (ws_size < NEED) return;

  float* ws = (float*)d_ws;
  float* X  = ws;
  float* QT = X  + (size_t)B_ * D_ * N_;
  float* KT = QT + (size_t)B_ * N_ * D_;
  float* VT = KT + (size_t)B_ * N_ * D_;
  float* SQ = VT + (size_t)B_ * N_ * D_;
  int*   IDX = (int*)(SQ + (size_t)B_ * N_);
  unsigned short* WH = (unsigned short*)SQ;  // attn weights, alive only after k_knn
  unsigned short* WF = (unsigned short*)KT;  // ffn weights, alive attn(l) -> ffn(l)
  float4* P4 = (float4*)QT;                  // packed candidates, alive embed -> knn

  k_embed<<<B_ * N_ / 256, 256, 0, stream>>>(pts, embed_w, embed_g, embed_b, embed_m, embed_v, X, P4);
  k_knn<<<B_ * N_ / 4, 256, 0, stream>>>(P4, IDX);
  for (int l = 0; l < L_; ++l) {
    k_prep_wl<<<36, 256, 0, stream>>>(pe_w2 + l * D_ * D_, am_w1 + l * D_ * D_, am_w2 + l * D_ * D_, WH);
    k_qkv<<<B_ * N_ / 32, 256, 0, stream>>>(X, wq + l * D_ * D_, wk + l * D_ * D_, wv + l * D_ * D_, QT, KT, VT);
    k_attn<<<B_ * N_ / 4, 256, 0, stream>>>(X, QT, KT, VT, pts, IDX,
        pe_w1 + l * D_ * 3, pe_g + l * D_, pe_b + l * D_, pe_m + l * D_, pe_v + l * D_,
        WH,
        am_g + l * D_, am_b + l * D_, am_m + l * D_, am_v + l * D_,
        n1_g + l * D_, n1_b + l * D_, n1_m + l * D_, n1_v + l * D_);
    k_prep_ffn<<<72, 256, 0, stream>>>(ffn_w1 + l * H_ * D_, ffn_w2 + l * D_ * H_, WF);
    k_ffn<<<B_ * N_ / 64, 256, 0, stream>>>(X, WF,
        f_g + l * H_, f_b + l * H_, f_m + l * H_, f_v + l * H_,
        n2_g + l * D_, n2_b + l * D_, n2_m + l * D_, n2_v + l * D_);
  }
  k_head<<<B_ * N_ / 256, 256, 0, stream>>>(X, hd_w1, hd_g, hd_b, hd_m, hd_v, hd_w2, hd_b2, (float*)d_out);
}

// Round 17
// 1312.618 us; speedup vs baseline: 2.9450x; 1.2303x over previous
//
#include <hip/hip_runtime.h>

#define B_ 2
#define N_ 8192
#define D_ 96
#define L_ 4
#define H_ 192
#define K_ 16
#define NC_ 2
#define EPS_ 1e-5f
#define BIGF 3.402823466e38f
#define TSTR 104   // padded LDS stride (fp16 elems) for 96-wide tiles — proven in R12
#define T2STR 200  // padded LDS stride for 192-wide h tile (~2-way conflicts, free)

typedef _Float16 half8 __attribute__((ext_vector_type(8)));
typedef float f32x4 __attribute__((ext_vector_type(4)));

__device__ __forceinline__ float bn1(float x, float g, float b, float m, float v) {
  return (x - m) * (g * (1.0f / sqrtf(v + EPS_))) + b;
}

__device__ __forceinline__ unsigned short f2h(float x) {
  union { _Float16 h; unsigned short u; } c;
  c.h = (_Float16)x;
  return c.u;
}

__device__ __forceinline__ float h2f(unsigned u16) {
  union { _Float16 h; unsigned short u; } c;
  c.u = (unsigned short)u16;
  return (float)c.h;
}

// ---------------- embed + packed candidate data (xyz + squared norm) ----------
__global__ void k_embed(const float* __restrict__ pts, const float* __restrict__ w,
                        const float* __restrict__ g, const float* __restrict__ bb,
                        const float* __restrict__ m, const float* __restrict__ v,
                        float* __restrict__ X, float4* __restrict__ P4) {
  int gid = blockIdx.x * 256 + threadIdx.x;
  int b = gid / N_, n = gid % N_;
  float p0 = pts[gid * 3], p1 = pts[gid * 3 + 1], p2 = pts[gid * 3 + 2];
  // exact numpy-order fp32 arithmetic (feeds KNN selection)
  float sq = __fadd_rn(__fadd_rn(__fmul_rn(p0, p0), __fmul_rn(p1, p1)), __fmul_rn(p2, p2));
  P4[gid] = make_float4(p0, p1, p2, sq);
  for (int o = 0; o < D_; ++o) {
    float e = w[o * 3] * p0 + w[o * 3 + 1] * p1 + w[o * 3 + 2] * p2;
    X[(b * D_ + o) * N_ + n] = fmaxf(bn1(e, g[o], bb[o], m[o], v[o]), 0.0f);
  }
}

// ---------------- KNN v3: proven v2 structure, 2 candidates per lane per iteration ---------
// Threshold T via 6 branchless shfls (group-of-4 min, then max over 16 groups).  The 16
// group minima are 16 DISTINCT candidates with d <= T  =>  T >= true 16th-smallest distance
// =>  gating the exact insertion network on d <= T is lossless.  The insertion network's
// final contents are the exact top-16 by (d, idx) regardless of processing order.
__global__ void k_knn(const float4* __restrict__ P4, int* __restrict__ IDX) {
  int lane = threadIdx.x & 63;
  int g = blockIdx.x * 4 + (threadIdx.x >> 6);
  int b = g / N_, n = g % N_;
  const float4* Pb = P4 + (size_t)b * N_;
  float4 qp = Pb[n];
  const float qx = qp.x, qy = qp.y, qz = qp.z, sqn = qp.w;

  // pass 1: branchless per-lane running min, 2 independent chains per iteration
  float lmin = BIGF;
  for (int j = 0; j < N_ / 64; j += 2) {
    float4 c0 = Pb[lane + j * 64];
    float4 c1 = Pb[lane + j * 64 + 64];
    float dot0 = __fadd_rn(__fadd_rn(__fmul_rn(qx, c0.x), __fmul_rn(qy, c0.y)), __fmul_rn(qz, c0.z));
    float dot1 = __fadd_rn(__fadd_rn(__fmul_rn(qx, c1.x), __fmul_rn(qy, c1.y)), __fmul_rn(qz, c1.z));
    float d0 = __fsub_rn(__fadd_rn(sqn, c0.w), __fmul_rn(2.0f, dot0));
    float d1 = __fsub_rn(__fadd_rn(sqn, c1.w), __fmul_rn(2.0f, dot1));
    lmin = fminf(lmin, fminf(d0, d1));
  }
  // group-of-4 min, then max across the 16 groups -> lossless threshold T
  float gm = fminf(lmin, __shfl_xor(lmin, 1));
  gm = fminf(gm, __shfl_xor(gm, 2));
  float T = gm;
  T = fmaxf(T, __shfl_xor(T, 4));
  T = fmaxf(T, __shfl_xor(T, 8));
  T = fmaxf(T, __shfl_xor(T, 16));
  T = fmaxf(T, __shfl_xor(T, 32));

  // pass 2: identical distance arithmetic; proven insertion network gated on d <= T
  float bd[K_]; int bi[K_];
#pragma unroll
  for (int s = 0; s < K_; ++s) { bd[s] = BIGF; bi[s] = 0x7fffffff; }
  float wd = BIGF; int wi = 0x7fffffff; int wslot = 0;
  for (int j = 0; j < N_ / 64; j += 2) {
    int cand0 = lane + j * 64;
    int cand1 = cand0 + 64;
    float4 c0 = Pb[cand0];
    float4 c1 = Pb[cand1];
    float dot0 = __fadd_rn(__fadd_rn(__fmul_rn(qx, c0.x), __fmul_rn(qy, c0.y)), __fmul_rn(qz, c0.z));
    float dot1 = __fadd_rn(__fadd_rn(__fmul_rn(qx, c1.x), __fmul_rn(qy, c1.y)), __fmul_rn(qz, c1.z));
    float d0 = __fsub_rn(__fadd_rn(sqn, c0.w), __fmul_rn(2.0f, dot0));
    float d1 = __fsub_rn(__fadd_rn(sqn, c1.w), __fmul_rn(2.0f, dot1));
    if (d0 <= T && (d0 < wd || (d0 == wd && cand0 < wi))) {
#pragma unroll
      for (int s = 0; s < K_; ++s) if (s == wslot) { bd[s] = d0; bi[s] = cand0; }
      wd = -BIGF; wi = -1;
#pragma unroll
      for (int s = 0; s < K_; ++s) {
        bool worse = (bd[s] > wd) || (bd[s] == wd && bi[s] > wi);
        if (worse) { wd = bd[s]; wi = bi[s]; wslot = s; }
      }
    }
    if (d1 <= T && (d1 < wd || (d1 == wd && cand1 < wi))) {
#pragma unroll
      for (int s = 0; s < K_; ++s) if (s == wslot) { bd[s] = d1; bi[s] = cand1; }
      wd = -BIGF; wi = -1;
#pragma unroll
      for (int s = 0; s < K_; ++s) {
        bool worse = (bd[s] > wd) || (bd[s] == wd && bi[s] > wi);
        if (worse) { wd = bd[s]; wi = bi[s]; wslot = s; }
      }
    }
  }

  // merge 64 lanes' candidates -> global top-16 (byte-identical to proven R1 merge)
  for (int r = 0; r < K_; ++r) {
    float md = BIGF; int mi = 0x7fffffff;
#pragma unroll
    for (int s = 0; s < K_; ++s) {
      bool better = (bd[s] < md) || (bd[s] == md && bi[s] < mi);
      if (better) { md = bd[s]; mi = bi[s]; }
    }
#pragma unroll
    for (int off = 32; off > 0; off >>= 1) {
      float od = __shfl_xor(md, off);
      int oi = __shfl_xor(mi, off);
      bool better = (od < md) || (od == md && oi < mi);
      if (better) { md = od; mi = oi; }
    }
#pragma unroll
    for (int s = 0; s < K_; ++s) if (bi[s] == mi) { bd[s] = BIGF; bi[s] = 0x7fffffff; }
    if (lane == 0) IDX[g * K_ + r] = mi;
  }
}

// ---------------- one-shot weight prep: all layers fp32 -> fp16 (dedicated regions) --------
__global__ void k_prep_attn(const float* __restrict__ pw2, const float* __restrict__ aw1,
                            const float* __restrict__ aw2, unsigned short* __restrict__ WHa) {
  int i = blockIdx.x * 256 + threadIdx.x;  // L*9216 = 36864; grid 144
  int l = i / 9216, r = i - l * 9216;
  WHa[l * 27648 + r]         = f2h(pw2[i]);
  WHa[l * 27648 + 9216 + r]  = f2h(aw1[i]);
  WHa[l * 27648 + 18432 + r] = f2h(aw2[i]);
}

__global__ void k_prep_qkv(const float* __restrict__ wq, const float* __restrict__ wk,
                           const float* __restrict__ wv, unsigned short* __restrict__ WQa) {
  int i = blockIdx.x * 256 + threadIdx.x;  // L*9216 = 36864; grid 144
  int l = i / 9216, r = i - l * 9216;
  WQa[l * 27648 + r]         = f2h(wq[i]);
  WQa[l * 27648 + 9216 + r]  = f2h(wk[i]);
  WQa[l * 27648 + 18432 + r] = f2h(wv[i]);
}

__global__ void k_prep_ffn(const float* __restrict__ w1, const float* __restrict__ w2,
                           unsigned short* __restrict__ WFa) {
  int i = blockIdx.x * 256 + threadIdx.x;  // L*18432 = 73728; grid 288
  int l = i / 18432, r = i - l * 18432;
  WFa[l * 36864 + r]         = f2h(w1[i]);
  WFa[l * 36864 + 18432 + r] = f2h(w2[i]);
}

// ---------------- QKV: MFMA, 1 wave per 16 points, fp16 outputs ----------------
__global__ void __launch_bounds__(256) k_qkv(const float* __restrict__ X,
                      const unsigned short* __restrict__ WQ,  // [3][9216] fp16
                      unsigned short* __restrict__ QTh, unsigned short* __restrict__ KTh,
                      unsigned short* __restrict__ VTh) {
  __shared__ __align__(16) unsigned short t1s[4][16 * TSTR];
  const int tid = threadIdx.x;
  const int l = tid & 63, w = tid >> 6;
  const int n16 = l & 15, q4 = l >> 4;
  const int p0 = blockIdx.x * 64 + w * 16;
  const int b = p0 >> 13;
  const int nn = p0 & (N_ - 1);
  unsigned short* x1 = &t1s[w][0];

  // phase 1: x tile -> fp16 LDS [point][channel]
  {
    const float* xb = X + (size_t)b * D_ * N_ + nn + n16;
    int c0 = q4 * 24;
#pragma unroll
    for (int i = 0; i < 24; ++i) {
      int c = c0 + i;
      x1[n16 * TSTR + c] = f2h(xb[(size_t)c * N_]);
    }
  }
  __syncthreads();

  half8 bfr[3];
#pragma unroll
  for (int s = 0; s < 3; ++s) bfr[s] = *(const half8*)&x1[n16 * TSTR + s * 32 + q4 * 8];
  unsigned short* Os[3] = {QTh, KTh, VTh};
#pragma unroll
  for (int t = 0; t < 3; ++t) {
    f32x4 acc[6];
#pragma unroll
    for (int m = 0; m < 6; ++m) acc[m] = (f32x4){0.f, 0.f, 0.f, 0.f};
    const unsigned short* Wt = WQ + t * 9216;
#pragma unroll
    for (int m = 0; m < 6; ++m) {
#pragma unroll
      for (int s = 0; s < 3; ++s) {
        half8 av = *(const half8*)&Wt[(m * 16 + n16) * 96 + s * 32 + q4 * 8];
        acc[m] = __builtin_amdgcn_mfma_f32_16x16x32_f16(av, bfr[s], acc[m], 0, 0, 0);
      }
    }
    unsigned short* op = Os[t] + (size_t)(p0 + n16) * 96;
#pragma unroll
    for (int m = 0; m < 6; ++m) {
      int cb = m * 16 + q4 * 4;
      uint2 u;
      u.x = (unsigned)f2h(acc[m][0]) | ((unsigned)f2h(acc[m][1]) << 16);
      u.y = (unsigned)f2h(acc[m][2]) | ((unsigned)f2h(acc[m][3]) << 16);
      *(uint2*)&op[cb] = u;
    }
  }
}

// W(16x32 rows of m-tile) @ Act(32x16) over 3 K-steps, 6 m-tiles; fp16 in, fp32 out.
// A frag: row = lane&15, k = s*32 + (lane>>4)*8 + j   (row-major fp16 W, stride 96)
// B frag: col(slot) = lane&15, k likewise; tile stored [slot][k], stride TSTR
// D frag: col(slot) = lane&15, row(channel) = m*16 + (lane>>4)*4 + r
__device__ __forceinline__ void mfma_stage(const unsigned short* __restrict__ Wh,
                                           const unsigned short* tw,
                                           int n16, int q4, f32x4 acc[6]) {
  half8 bfr[3];
#pragma unroll
  for (int s = 0; s < 3; ++s)
    bfr[s] = *(const half8*)&tw[n16 * TSTR + s * 32 + q4 * 8];
#pragma unroll
  for (int m = 0; m < 6; ++m) {
#pragma unroll
    for (int s = 0; s < 3; ++s) {
      half8 av = *(const half8*)&Wh[(m * 16 + n16) * 96 + s * 32 + q4 * 8];
      acc[m] = __builtin_amdgcn_mfma_f32_16x16x32_f16(av, bfr[s], acc[m], 0, 0, 0);
    }
  }
}

// ---------------- fused attention: 1 wave per point, 4 points/block, MFMA, fp16 Q/K/V --------
__global__ void __launch_bounds__(256) k_attn(
    float* __restrict__ X, const unsigned short* __restrict__ QTh,
    const unsigned short* __restrict__ KTh, const unsigned short* __restrict__ VTh,
    const float* __restrict__ pts, const int* __restrict__ IDX,
    const float* __restrict__ pw1, const float* __restrict__ pg, const float* __restrict__ pb_,
    const float* __restrict__ pm, const float* __restrict__ pv,
    const unsigned short* __restrict__ WH,
    const float* __restrict__ ag, const float* __restrict__ ab,
    const float* __restrict__ am, const float* __restrict__ av,
    const float* __restrict__ g1, const float* __restrict__ b1,
    const float* __restrict__ m1, const float* __restrict__ v1) {
  __shared__ __align__(16) unsigned short tile[4][16 * TSTR];
  __shared__ float pdif[4][3][16];
  __shared__ int sid[4][16];
  const int tid = threadIdx.x;
  const int l = tid & 63, w = tid >> 6;
  const int g = blockIdx.x * 4 + w;
  const int b = g >> 13, n = g & (N_ - 1);
  const int n16 = l & 15, q4 = l >> 4;
  unsigned short* tw = &tile[w][0];

  if (l < 16) {
    int nbr = IDX[g * K_ + l];
    sid[w][l] = nbr;
    const float* pq = pts + ((size_t)b * N_ + n) * 3;
    const float* pn = pts + ((size_t)b * N_ + nbr) * 3;
    pdif[w][0][l] = pq[0] - pn[0];
    pdif[w][1][l] = pq[1] - pn[1];
    pdif[w][2][l] = pq[2] - pn[2];
  }
  __syncthreads();

  {
    float p0 = pdif[w][0][n16], p1 = pdif[w][1][n16], p2 = pdif[w][2][n16];
    int c0 = q4 * 24;
#pragma unroll
    for (int ii = 0; ii < 24; ii += 2) {
      int c = c0 + ii;
      float vA = pw1[c * 3] * p0 + pw1[c * 3 + 1] * p1 + pw1[c * 3 + 2] * p2;
      float vB = pw1[(c + 1) * 3] * p0 + pw1[(c + 1) * 3 + 1] * p1 + pw1[(c + 1) * 3 + 2] * p2;
      vA = fmaxf(bn1(vA, pg[c], pb_[c], pm[c], pv[c]), 0.f);
      vB = fmaxf(bn1(vB, pg[c + 1], pb_[c + 1], pm[c + 1], pv[c + 1]), 0.f);
      unsigned u = (unsigned)f2h(vA) | ((unsigned)f2h(vB) << 16);
      *(unsigned*)&tw[n16 * TSTR + c] = u;
    }
  }
  __syncthreads();

  f32x4 pe2[6];
#pragma unroll
  for (int m = 0; m < 6; ++m) pe2[m] = (f32x4){0.f, 0.f, 0.f, 0.f};
  mfma_stage(WH, tw, n16, q4, pe2);
  __syncthreads();

  const int nbr = sid[w][n16];
  {
    const unsigned short* qt = QTh + (size_t)g * 96;
    const unsigned short* kt = KTh + ((size_t)b * N_ + nbr) * 96;
#pragma unroll
    for (int m = 0; m < 6; ++m) {
      int cb = m * 16 + q4 * 4;
      uint2 qu = *(const uint2*)&qt[cb];
      uint2 ku = *(const uint2*)&kt[cb];
      float v0 = h2f(qu.x & 0xffffu) - h2f(ku.x & 0xffffu) + pe2[m][0];
      float v1 = h2f(qu.x >> 16)     - h2f(ku.x >> 16)     + pe2[m][1];
      float v2 = h2f(qu.y & 0xffffu) - h2f(ku.y & 0xffffu) + pe2[m][2];
      float v3 = h2f(qu.y >> 16)     - h2f(ku.y >> 16)     + pe2[m][3];
      int idx = n16 * TSTR + cb;
      *(unsigned*)&tw[idx]     = (unsigned)f2h(v0) | ((unsigned)f2h(v1) << 16);
      *(unsigned*)&tw[idx + 2] = (unsigned)f2h(v2) | ((unsigned)f2h(v3) << 16);
    }
  }
  __syncthreads();

  {
    f32x4 t1[6];
#pragma unroll
    for (int m = 0; m < 6; ++m) t1[m] = (f32x4){0.f, 0.f, 0.f, 0.f};
    mfma_stage(WH + 9216, tw, n16, q4, t1);
    __syncthreads();
#pragma unroll
    for (int m = 0; m < 6; ++m) {
      int cb = m * 16 + q4 * 4;
      float v0 = fmaxf(bn1(t1[m][0], ag[cb], ab[cb], am[cb], av[cb]), 0.f);
      float v1 = fmaxf(bn1(t1[m][1], ag[cb + 1], ab[cb + 1], am[cb + 1], av[cb + 1]), 0.f);
      float v2 = fmaxf(bn1(t1[m][2], ag[cb + 2], ab[cb + 2], am[cb + 2], av[cb + 2]), 0.f);
      float v3 = fmaxf(bn1(t1[m][3], ag[cb + 3], ab[cb + 3], am[cb + 3], av[cb + 3]), 0.f);
      int idx = n16 * TSTR + cb;
      *(unsigned*)&tw[idx]     = (unsigned)f2h(v0) | ((unsigned)f2h(v1) << 16);
      *(unsigned*)&tw[idx + 2] = (unsigned)f2h(v2) | ((unsigned)f2h(v3) << 16);
    }
  }
  __syncthreads();

  {
    f32x4 a2[6];
#pragma unroll
    for (int m = 0; m < 6; ++m) a2[m] = (f32x4){0.f, 0.f, 0.f, 0.f};
    mfma_stage(WH + 18432, tw, n16, q4, a2);
    const unsigned short* vt = VTh + ((size_t)b * N_ + nbr) * 96;
#pragma unroll
    for (int m = 0; m < 6; ++m) {
      int cb = m * 16 + q4 * 4;
      uint2 vu = *(const uint2*)&vt[cb];
      float vvp[4];
      vvp[0] = h2f(vu.x & 0xffffu);
      vvp[1] = h2f(vu.x >> 16);
      vvp[2] = h2f(vu.y & 0xffffu);
      vvp[3] = h2f(vu.y >> 16);
      float ov[4];
#pragma unroll
      for (int r = 0; r < 4; ++r) {
        float a = a2[m][r];
        float mx = a;
        mx = fmaxf(mx, __shfl_xor(mx, 1));
        mx = fmaxf(mx, __shfl_xor(mx, 2));
        mx = fmaxf(mx, __shfl_xor(mx, 4));
        mx = fmaxf(mx, __shfl_xor(mx, 8));
        float e = expf(a - mx);
        float s = e;
        s += __shfl_xor(s, 1); s += __shfl_xor(s, 2); s += __shfl_xor(s, 4); s += __shfl_xor(s, 8);
        float c = e * (vvp[r] + pe2[m][r]);
        c += __shfl_xor(c, 1); c += __shfl_xor(c, 2); c += __shfl_xor(c, 4); c += __shfl_xor(c, 8);
        ov[r] = c / s;
      }
      if (n16 == 0) {
#pragma unroll
        for (int r = 0; r < 4; ++r) {
          int c = cb + r;
          size_t xi = ((size_t)b * D_ + c) * N_ + n;
          float t = X[xi] + ov[r];
          X[xi] = (t - m1[c]) * (g1[c] * (1.0f / sqrtf(v1[c] + EPS_))) + b1[c];
        }
      }
    }
  }
}

// ---------------- FFN: MFMA, 1 wave per 16 points, 4 waves/block (proven R14) ----------------
__global__ void __launch_bounds__(256) k_ffn(
    float* __restrict__ X, const unsigned short* __restrict__ WF,
    const float* __restrict__ fg, const float* __restrict__ fb,
    const float* __restrict__ fm, const float* __restrict__ fv,
    const float* __restrict__ g2, const float* __restrict__ b2,
    const float* __restrict__ m2, const float* __restrict__ v2) {
  __shared__ __align__(16) unsigned short t1s[4][16 * TSTR];   // x fp16: [pt][c]
  __shared__ __align__(16) unsigned short t2s[4][16 * T2STR];  // h fp16: [pt][j]
  const int tid = threadIdx.x;
  const int l = tid & 63, w = tid >> 6;
  const int n16 = l & 15, q4 = l >> 4;
  const int p0 = blockIdx.x * 64 + w * 16;
  const int b = p0 >> 13;
  const int nn = p0 & (N_ - 1);
  unsigned short* x1 = &t1s[w][0];
  unsigned short* h1 = &t2s[w][0];

  // phase 1: x tile -> fp16 LDS [point][channel]
  {
    const float* xb = X + (size_t)b * D_ * N_ + nn + n16;
    int c0 = q4 * 24;
#pragma unroll
    for (int i = 0; i < 24; ++i) {
      int c = c0 + i;
      x1[n16 * TSTR + c] = f2h(xb[(size_t)c * N_]);
    }
  }
  __syncthreads();

  // phase 2: h = relu(bn_f(W1 @ x))  (12 m-tiles x 3 k-steps) -> h tile
  {
    f32x4 acc[12];
#pragma unroll
    for (int m = 0; m < 12; ++m) acc[m] = (f32x4){0.f, 0.f, 0.f, 0.f};
    half8 bfr[3];
#pragma unroll
    for (int s = 0; s < 3; ++s) bfr[s] = *(const half8*)&x1[n16 * TSTR + s * 32 + q4 * 8];
#pragma unroll
    for (int m = 0; m < 12; ++m) {
#pragma unroll
      for (int s = 0; s < 3; ++s) {
        half8 av = *(const half8*)&WF[(m * 16 + n16) * 96 + s * 32 + q4 * 8];
        acc[m] = __builtin_amdgcn_mfma_f32_16x16x32_f16(av, bfr[s], acc[m], 0, 0, 0);
      }
    }
    __syncthreads();  // x tile fully consumed before h writes begin
#pragma unroll
    for (int m = 0; m < 12; ++m) {
      int jb = m * 16 + q4 * 4;
#pragma unroll
      for (int r = 0; r < 4; ++r) {
        int j = jb + r;
        float hv = fmaxf(bn1(acc[m][r], fg[j], fb[j], fm[j], fv[j]), 0.f);
        h1[n16 * T2STR + j] = f2h(hv);
      }
    }
  }
  __syncthreads();

  // phase 3: out = W2 @ h (6 m-tiles x 6 k-steps) ; residual + bn2 -> X
  {
    const unsigned short* W2h = WF + 18432;
    f32x4 acc[6];
#pragma unroll
    for (int m = 0; m < 6; ++m) acc[m] = (f32x4){0.f, 0.f, 0.f, 0.f};
    half8 bfr[6];
#pragma unroll
    for (int s = 0; s < 6; ++s) bfr[s] = *(const half8*)&h1[n16 * T2STR + s * 32 + q4 * 8];
#pragma unroll
    for (int m = 0; m < 6; ++m) {
#pragma unroll
      for (int s = 0; s < 6; ++s) {
        half8 av = *(const half8*)&W2h[(m * 16 + n16) * 192 + s * 32 + q4 * 8];
        acc[m] = __builtin_amdgcn_mfma_f32_16x16x32_f16(av, bfr[s], acc[m], 0, 0, 0);
      }
    }
#pragma unroll
    for (int m = 0; m < 6; ++m) {
      int cb = m * 16 + q4 * 4;
#pragma unroll
      for (int r = 0; r < 4; ++r) {
        int c = cb + r;
        size_t xi = ((size_t)b * D_ + c) * N_ + nn + n16;
        float t = X[xi] + acc[m][r];
        X[xi] = bn1(t, g2[c], b2[c], m2[c], v2[c]);
      }
    }
  }
}

// ---------------- head: proven baseline version ----------------
__global__ void k_head(const float* __restrict__ X, const float* __restrict__ w1,
                       const float* __restrict__ hg, const float* __restrict__ hbb,
                       const float* __restrict__ hm, const float* __restrict__ hv,
                       const float* __restrict__ w2, const float* __restrict__ hb2,
                       float* __restrict__ OUT) {
  int gid = blockIdx.x * 256 + threadIdx.x;
  int b = gid / N_, n = gid % N_;
  const float* xb = X + b * D_ * N_ + n;
  float xr[D_];
#pragma unroll
  for (int c = 0; c < D_; ++c) xr[c] = xb[c * N_];
  float a0 = 0.f, a1 = 0.f;
  for (int j = 0; j < 128; ++j) {
    float acc = 0.f;
#pragma unroll
    for (int c = 0; c < D_; ++c) acc += w1[j * D_ + c] * xr[c];
    float t = fmaxf(bn1(acc, hg[j], hbb[j], hm[j], hv[j]), 0.0f);
    a0 += w2[j] * t;
    a1 += w2[128 + j] * t;
  }
  OUT[(b * NC_ + 0) * N_ + n] = a0 + hb2[0];
  OUT[(b * NC_ + 1) * N_ + n] = a1 + hb2[1];
}

extern "C" void kernel_launch(void* const* d_in, const int* in_sizes, int n_in,
                              void* d_out, int out_size, void* d_ws, size_t ws_size,
                              hipStream_t stream) {
  (void)in_sizes; (void)n_in; (void)out_size;
  const float* pts     = (const float*)d_in[0];
  const float* embed_w = (const float*)d_in[1];
  const float* embed_g = (const float*)d_in[2];
  const float* embed_b = (const float*)d_in[3];
  const float* embed_m = (const float*)d_in[4];
  const float* embed_v = (const float*)d_in[5];
  const float* wq      = (const float*)d_in[6];
  const float* wk      = (const float*)d_in[7];
  const float* wv      = (const float*)d_in[8];
  const float* pe_w1   = (const float*)d_in[9];
  const float* pe_g    = (const float*)d_in[10];
  const float* pe_b    = (const float*)d_in[11];
  const float* pe_m    = (const float*)d_in[12];
  const float* pe_v    = (const float*)d_in[13];
  const float* pe_w2   = (const float*)d_in[14];
  const float* am_w1   = (const float*)d_in[15];
  const float* am_g    = (const float*)d_in[16];
  const float* am_b    = (const float*)d_in[17];
  const float* am_m    = (const float*)d_in[18];
  const float* am_v    = (const float*)d_in[19];
  const float* am_w2   = (const float*)d_in[20];
  const float* n1_g    = (const float*)d_in[21];
  const float* n1_b    = (const float*)d_in[22];
  const float* n1_m    = (const float*)d_in[23];
  const float* n1_v    = (const float*)d_in[24];
  const float* ffn_w1  = (const float*)d_in[25];
  const float* f_g     = (const float*)d_in[26];
  const float* f_b     = (const float*)d_in[27];
  const float* f_m     = (const float*)d_in[28];
  const float* f_v     = (const float*)d_in[29];
  const float* ffn_w2  = (const float*)d_in[30];
  const float* n2_g    = (const float*)d_in[31];
  const float* n2_b    = (const float*)d_in[32];
  const float* n2_m    = (const float*)d_in[33];
  const float* n2_v    = (const float*)d_in[34];
  const float* hd_w1   = (const float*)d_in[35];
  const float* hd_g    = (const float*)d_in[36];
  const float* hd_b    = (const float*)d_in[37];
  const float* hd_m    = (const float*)d_in[38];
  const float* hd_v    = (const float*)d_in[39];
  const float* hd_w2   = (const float*)d_in[40];
  const float* hd_b2   = (const float*)d_in[41];

  // ws layout (bytes, 16B-aligned, NO aliasing):
  //  X    fp32 B*D*N   @ 0           (6,291,456)
  //  QTh  fp16 B*N*D   @ 6,291,456   (3,145,728)
  //  KTh  fp16 B*N*D   @ 9,437,184   (3,145,728)
  //  VTh  fp16 B*N*D   @ 12,582,912  (3,145,728)
  //  P4   f4   B*N     @ 15,728,640  (  262,144)
  //  IDX  i32  B*N*K   @ 15,990,784  (1,048,576)
  //  WHa  fp16 L*3*D*D @ 17,039,360  (  221,184)
  //  WQa  fp16 L*3*D*D @ 17,260,544  (  221,184)
  //  WFa  fp16 L*2*H*D @ 17,481,728  (  294,912)
  //  total 17,776,640 B < 26,279,936 proven
  const size_t NEED = 17776640;
  if (ws_size < NEED) return;

  char* wsb = (char*)d_ws;
  float* X            = (float*)wsb;
  unsigned short* QTh = (unsigned short*)(wsb + 6291456);
  unsigned short* KTh = (unsigned short*)(wsb + 9437184);
  unsigned short* VTh = (unsigned short*)(wsb + 12582912);
  float4* P4          = (float4*)(wsb + 15728640);
  int* IDX            = (int*)(wsb + 15990784);
  unsigned short* WHa = (unsigned short*)(wsb + 17039360);
  unsigned short* WQa = (unsigned short*)(wsb + 17260544);
  unsigned short* WFa = (unsigned short*)(wsb + 17481728);

  k_prep_attn<<<144, 256, 0, stream>>>(pe_w2, am_w1, am_w2, WHa);
  k_prep_qkv<<<144, 256, 0, stream>>>(wq, wk, wv, WQa);
  k_prep_ffn<<<288, 256, 0, stream>>>(ffn_w1, ffn_w2, WFa);
  k_embed<<<B_ * N_ / 256, 256, 0, stream>>>(pts, embed_w, embed_g, embed_b, embed_m, embed_v, X, P4);
  k_knn<<<B_ * N_ / 4, 256, 0, stream>>>(P4, IDX);
  for (int l = 0; l < L_; ++l) {
    k_qkv<<<B_ * N_ / 64, 256, 0, stream>>>(X, WQa + l * 27648, QTh, KTh, VTh);
    k_attn<<<B_ * N_ / 4, 256, 0, stream>>>(X, QTh, KTh, VTh, pts, IDX,
        pe_w1 + l * D_ * 3, pe_g + l * D_, pe_b + l * D_, pe_m + l * D_, pe_v + l * D_,
        WHa + l * 27648,
        am_g + l * D_, am_b + l * D_, am_m + l * D_, am_v + l * D_,
        n1_g + l * D_, n1_b + l * D_, n1_m + l * D_, n1_v + l * D_);
    k_ffn<<<B_ * N_ / 64, 256, 0, stream>>>(X, WFa + l * 36864,
        f_g + l * H_, f_b + l * H_, f_m + l * H_, f_v + l * H_,
        n2_g + l * D_, n2_b + l * D_, n2_m + l * D_, n2_v + l * D_);
  }
  k_head<<<B_ * N_ / 256, 256, 0, stream>>>(X, hd_w1, hd_g, hd_b, hd_m, hd_v, hd_w2, hd_b2,
                                            (float*)d_out);
}

// Round 18
// 1189.762 us; speedup vs baseline: 3.2492x; 1.1033x over previous
//
#include <hip/hip_runtime.h>

#define B_ 2
#define N_ 8192
#define D_ 96
#define L_ 4
#define H_ 192
#define K_ 16
#define NC_ 2
#define EPS_ 1e-5f
#define BIGF 3.402823466e38f
#define TSTR 104   // padded LDS stride (fp16 elems) for 96-wide tiles — proven in R12
#define T2STR 200  // padded LDS stride for 192-wide h tile (~2-way conflicts, free)

typedef _Float16 half8 __attribute__((ext_vector_type(8)));
typedef float f32x4 __attribute__((ext_vector_type(4)));

__device__ __forceinline__ float bn1(float x, float g, float b, float m, float v) {
  return (x - m) * (g * (1.0f / sqrtf(v + EPS_))) + b;
}

__device__ __forceinline__ unsigned short f2h(float x) {
  union { _Float16 h; unsigned short u; } c;
  c.h = (_Float16)x;
  return c.u;
}

__device__ __forceinline__ float h2f(unsigned u16) {
  union { _Float16 h; unsigned short u; } c;
  c.u = (unsigned short)u16;
  return (float)c.h;
}

// ---------------- embed + packed candidate data (xyz + squared norm) ----------
__global__ void k_embed(const float* __restrict__ pts, const float* __restrict__ w,
                        const float* __restrict__ g, const float* __restrict__ bb,
                        const float* __restrict__ m, const float* __restrict__ v,
                        float* __restrict__ X, float4* __restrict__ P4) {
  int gid = blockIdx.x * 256 + threadIdx.x;
  int b = gid / N_, n = gid % N_;
  float p0 = pts[gid * 3], p1 = pts[gid * 3 + 1], p2 = pts[gid * 3 + 2];
  // exact numpy-order fp32 arithmetic (feeds KNN selection)
  float sq = __fadd_rn(__fadd_rn(__fmul_rn(p0, p0), __fmul_rn(p1, p1)), __fmul_rn(p2, p2));
  P4[gid] = make_float4(p0, p1, p2, sq);
  for (int o = 0; o < D_; ++o) {
    float e = w[o * 3] * p0 + w[o * 3 + 1] * p1 + w[o * 3 + 2] * p2;
    X[(b * D_ + o) * N_ + n] = fmaxf(bn1(e, g[o], bb[o], m[o], v[o]), 0.0f);
  }
}

// ---------------- KNN v4: threshold gate + cheap 8-slot append, rare exact fallback --------
// T (6 branchless shfls): group-of-4 min then max over 16 groups. The 16 group minima are
// 16 DISTINCT candidates <= T  =>  T >= true 16th-smallest distance  =>  any candidate NOT
// passing d <= T cannot be a true neighbor.  Survivors per lane are few (mean ~0.85), so the
// fast path appends up to 8 per lane; if any lane overflows (wave-uniform __any, P~1e-5),
// the byte-identical proven 16-deep insertion network recomputes exactly.  Both paths feed
// the proven 16-round merge; the final (d, idx)-lexicographic top-16 is exact either way.
__global__ void k_knn(const float4* __restrict__ P4, int* __restrict__ IDX) {
  int lane = threadIdx.x & 63;
  int g = blockIdx.x * 4 + (threadIdx.x >> 6);
  int b = g / N_, n = g % N_;
  const float4* Pb = P4 + (size_t)b * N_;
  float4 qp = Pb[n];
  const float qx = qp.x, qy = qp.y, qz = qp.z, sqn = qp.w;

  // pass 1: branchless per-lane running min, 2 independent chains per iteration
  float lmin = BIGF;
  for (int j = 0; j < N_ / 64; j += 2) {
    float4 c0 = Pb[lane + j * 64];
    float4 c1 = Pb[lane + j * 64 + 64];
    float dot0 = __fadd_rn(__fadd_rn(__fmul_rn(qx, c0.x), __fmul_rn(qy, c0.y)), __fmul_rn(qz, c0.z));
    float dot1 = __fadd_rn(__fadd_rn(__fmul_rn(qx, c1.x), __fmul_rn(qy, c1.y)), __fmul_rn(qz, c1.z));
    float d0 = __fsub_rn(__fadd_rn(sqn, c0.w), __fmul_rn(2.0f, dot0));
    float d1 = __fsub_rn(__fadd_rn(sqn, c1.w), __fmul_rn(2.0f, dot1));
    lmin = fminf(lmin, fminf(d0, d1));
  }
  // group-of-4 min, then max across the 16 groups -> lossless threshold T
  float gm = fminf(lmin, __shfl_xor(lmin, 1));
  gm = fminf(gm, __shfl_xor(gm, 2));
  float T = gm;
  T = fmaxf(T, __shfl_xor(T, 4));
  T = fmaxf(T, __shfl_xor(T, 8));
  T = fmaxf(T, __shfl_xor(T, 16));
  T = fmaxf(T, __shfl_xor(T, 32));

  float bd[K_]; int bi[K_];
#pragma unroll
  for (int s = 0; s < K_; ++s) { bd[s] = BIGF; bi[s] = 0x7fffffff; }

  // pass 2 fast path: append survivors (d <= T) into 8 static slots, count them all
  float sd[8]; int si[8];
#pragma unroll
  for (int s = 0; s < 8; ++s) { sd[s] = BIGF; si[s] = 0x7fffffff; }
  int cnt = 0;
  for (int j = 0; j < N_ / 64; j += 2) {
    int cand0 = lane + j * 64;
    int cand1 = cand0 + 64;
    float4 c0 = Pb[cand0];
    float4 c1 = Pb[cand1];
    float dot0 = __fadd_rn(__fadd_rn(__fmul_rn(qx, c0.x), __fmul_rn(qy, c0.y)), __fmul_rn(qz, c0.z));
    float dot1 = __fadd_rn(__fadd_rn(__fmul_rn(qx, c1.x), __fmul_rn(qy, c1.y)), __fmul_rn(qz, c1.z));
    float d0 = __fsub_rn(__fadd_rn(sqn, c0.w), __fmul_rn(2.0f, dot0));
    float d1 = __fsub_rn(__fadd_rn(sqn, c1.w), __fmul_rn(2.0f, dot1));
    if (d0 <= T) {
#pragma unroll
      for (int s = 0; s < 8; ++s) if (cnt == s) { sd[s] = d0; si[s] = cand0; }
      ++cnt;
    }
    if (d1 <= T) {
#pragma unroll
      for (int s = 0; s < 8; ++s) if (cnt == s) { sd[s] = d1; si[s] = cand1; }
      ++cnt;
    }
  }

  if (!__any(cnt > 8)) {
    // all survivors captured: move into merge slots 0..7
#pragma unroll
    for (int s = 0; s < 8; ++s) { bd[s] = sd[s]; bi[s] = si[s]; }
  } else {
    // rare exact fallback: proven 16-deep insertion network gated on d <= T
    float wd = BIGF; int wi = 0x7fffffff; int wslot = 0;
    for (int j = 0; j < N_ / 64; j += 2) {
      int cand0 = lane + j * 64;
      int cand1 = cand0 + 64;
      float4 c0 = Pb[cand0];
      float4 c1 = Pb[cand1];
      float dot0 = __fadd_rn(__fadd_rn(__fmul_rn(qx, c0.x), __fmul_rn(qy, c0.y)), __fmul_rn(qz, c0.z));
      float dot1 = __fadd_rn(__fadd_rn(__fmul_rn(qx, c1.x), __fmul_rn(qy, c1.y)), __fmul_rn(qz, c1.z));
      float d0 = __fsub_rn(__fadd_rn(sqn, c0.w), __fmul_rn(2.0f, dot0));
      float d1 = __fsub_rn(__fadd_rn(sqn, c1.w), __fmul_rn(2.0f, dot1));
      if (d0 <= T && (d0 < wd || (d0 == wd && cand0 < wi))) {
#pragma unroll
        for (int s = 0; s < K_; ++s) if (s == wslot) { bd[s] = d0; bi[s] = cand0; }
        wd = -BIGF; wi = -1;
#pragma unroll
        for (int s = 0; s < K_; ++s) {
          bool worse = (bd[s] > wd) || (bd[s] == wd && bi[s] > wi);
          if (worse) { wd = bd[s]; wi = bi[s]; wslot = s; }
        }
      }
      if (d1 <= T && (d1 < wd || (d1 == wd && cand1 < wi))) {
#pragma unroll
        for (int s = 0; s < K_; ++s) if (s == wslot) { bd[s] = d1; bi[s] = cand1; }
        wd = -BIGF; wi = -1;
#pragma unroll
        for (int s = 0; s < K_; ++s) {
          bool worse = (bd[s] > wd) || (bd[s] == wd && bi[s] > wi);
          if (worse) { wd = bd[s]; wi = bi[s]; wslot = s; }
        }
      }
    }
  }

  // merge 64 lanes' candidates -> global top-16 (byte-identical to proven R1 merge)
  for (int r = 0; r < K_; ++r) {
    float md = BIGF; int mi = 0x7fffffff;
#pragma unroll
    for (int s = 0; s < K_; ++s) {
      bool better = (bd[s] < md) || (bd[s] == md && bi[s] < mi);
      if (better) { md = bd[s]; mi = bi[s]; }
    }
#pragma unroll
    for (int off = 32; off > 0; off >>= 1) {
      float od = __shfl_xor(md, off);
      int oi = __shfl_xor(mi, off);
      bool better = (od < md) || (od == md && oi < mi);
      if (better) { md = od; mi = oi; }
    }
#pragma unroll
    for (int s = 0; s < K_; ++s) if (bi[s] == mi) { bd[s] = BIGF; bi[s] = 0x7fffffff; }
    if (lane == 0) IDX[g * K_ + r] = mi;
  }
}

// ---------------- one-shot weight prep: all layers fp32 -> fp16 (dedicated regions) --------
__global__ void k_prep_attn(const float* __restrict__ pw2, const float* __restrict__ aw1,
                            const float* __restrict__ aw2, unsigned short* __restrict__ WHa) {
  int i = blockIdx.x * 256 + threadIdx.x;  // L*9216 = 36864; grid 144
  int l = i / 9216, r = i - l * 9216;
  WHa[l * 27648 + r]         = f2h(pw2[i]);
  WHa[l * 27648 + 9216 + r]  = f2h(aw1[i]);
  WHa[l * 27648 + 18432 + r] = f2h(aw2[i]);
}

__global__ void k_prep_qkv(const float* __restrict__ wq, const float* __restrict__ wk,
                           const float* __restrict__ wv, unsigned short* __restrict__ WQa) {
  int i = blockIdx.x * 256 + threadIdx.x;  // L*9216 = 36864; grid 144
  int l = i / 9216, r = i - l * 9216;
  WQa[l * 27648 + r]         = f2h(wq[i]);
  WQa[l * 27648 + 9216 + r]  = f2h(wk[i]);
  WQa[l * 27648 + 18432 + r] = f2h(wv[i]);
}

__global__ void k_prep_ffn(const float* __restrict__ w1, const float* __restrict__ w2,
                           unsigned short* __restrict__ WFa) {
  int i = blockIdx.x * 256 + threadIdx.x;  // L*18432 = 73728; grid 288
  int l = i / 18432, r = i - l * 18432;
  WFa[l * 36864 + r]         = f2h(w1[i]);
  WFa[l * 36864 + 18432 + r] = f2h(w2[i]);
}

// ---------------- QKV: MFMA, 1 wave per 16 points, fp16 outputs ----------------
__global__ void __launch_bounds__(256) k_qkv(const float* __restrict__ X,
                      const unsigned short* __restrict__ WQ,  // [3][9216] fp16
                      unsigned short* __restrict__ QTh, unsigned short* __restrict__ KTh,
                      unsigned short* __restrict__ VTh) {
  __shared__ __align__(16) unsigned short t1s[4][16 * TSTR];
  const int tid = threadIdx.x;
  const int l = tid & 63, w = tid >> 6;
  const int n16 = l & 15, q4 = l >> 4;
  const int p0 = blockIdx.x * 64 + w * 16;
  const int b = p0 >> 13;
  const int nn = p0 & (N_ - 1);
  unsigned short* x1 = &t1s[w][0];

  // phase 1: x tile -> fp16 LDS [point][channel]
  {
    const float* xb = X + (size_t)b * D_ * N_ + nn + n16;
    int c0 = q4 * 24;
#pragma unroll
    for (int i = 0; i < 24; ++i) {
      int c = c0 + i;
      x1[n16 * TSTR + c] = f2h(xb[(size_t)c * N_]);
    }
  }
  __syncthreads();

  half8 bfr[3];
#pragma unroll
  for (int s = 0; s < 3; ++s) bfr[s] = *(const half8*)&x1[n16 * TSTR + s * 32 + q4 * 8];
  unsigned short* Os[3] = {QTh, KTh, VTh};
#pragma unroll
  for (int t = 0; t < 3; ++t) {
    f32x4 acc[6];
#pragma unroll
    for (int m = 0; m < 6; ++m) acc[m] = (f32x4){0.f, 0.f, 0.f, 0.f};
    const unsigned short* Wt = WQ + t * 9216;
#pragma unroll
    for (int m = 0; m < 6; ++m) {
#pragma unroll
      for (int s = 0; s < 3; ++s) {
        half8 av = *(const half8*)&Wt[(m * 16 + n16) * 96 + s * 32 + q4 * 8];
        acc[m] = __builtin_amdgcn_mfma_f32_16x16x32_f16(av, bfr[s], acc[m], 0, 0, 0);
      }
    }
    unsigned short* op = Os[t] + (size_t)(p0 + n16) * 96;
#pragma unroll
    for (int m = 0; m < 6; ++m) {
      int cb = m * 16 + q4 * 4;
      uint2 u;
      u.x = (unsigned)f2h(acc[m][0]) | ((unsigned)f2h(acc[m][1]) << 16);
      u.y = (unsigned)f2h(acc[m][2]) | ((unsigned)f2h(acc[m][3]) << 16);
      *(uint2*)&op[cb] = u;
    }
  }
}

// W(16x32 rows of m-tile) @ Act(32x16) over 3 K-steps, 6 m-tiles; fp16 in, fp32 out.
// A frag: row = lane&15, k = s*32 + (lane>>4)*8 + j   (row-major fp16 W, stride 96)
// B frag: col(slot) = lane&15, k likewise; tile stored [slot][k], stride TSTR
// D frag: col(slot) = lane&15, row(channel) = m*16 + (lane>>4)*4 + r
__device__ __forceinline__ void mfma_stage(const unsigned short* __restrict__ Wh,
                                           const unsigned short* tw,
                                           int n16, int q4, f32x4 acc[6]) {
  half8 bfr[3];
#pragma unroll
  for (int s = 0; s < 3; ++s)
    bfr[s] = *(const half8*)&tw[n16 * TSTR + s * 32 + q4 * 8];
#pragma unroll
  for (int m = 0; m < 6; ++m) {
#pragma unroll
    for (int s = 0; s < 3; ++s) {
      half8 av = *(const half8*)&Wh[(m * 16 + n16) * 96 + s * 32 + q4 * 8];
      acc[m] = __builtin_amdgcn_mfma_f32_16x16x32_f16(av, bfr[s], acc[m], 0, 0, 0);
    }
  }
}

// ---------------- fused attention: 1 wave per point, 4 points/block, MFMA, fp16 Q/K/V --------
__global__ void __launch_bounds__(256) k_attn(
    float* __restrict__ X, const unsigned short* __restrict__ QTh,
    const unsigned short* __restrict__ KTh, const unsigned short* __restrict__ VTh,
    const float* __restrict__ pts, const int* __restrict__ IDX,
    const float* __restrict__ pw1, const float* __restrict__ pg, const float* __restrict__ pb_,
    const float* __restrict__ pm, const float* __restrict__ pv,
    const unsigned short* __restrict__ WH,
    const float* __restrict__ ag, const float* __restrict__ ab,
    const float* __restrict__ am, const float* __restrict__ av,
    const float* __restrict__ g1, const float* __restrict__ b1,
    const float* __restrict__ m1, const float* __restrict__ v1) {
  __shared__ __align__(16) unsigned short tile[4][16 * TSTR];
  __shared__ float pdif[4][3][16];
  __shared__ int sid[4][16];
  const int tid = threadIdx.x;
  const int l = tid & 63, w = tid >> 6;
  const int g = blockIdx.x * 4 + w;
  const int b = g >> 13, n = g & (N_ - 1);
  const int n16 = l & 15, q4 = l >> 4;
  unsigned short* tw = &tile[w][0];

  if (l < 16) {
    int nbr = IDX[g * K_ + l];
    sid[w][l] = nbr;
    const float* pq = pts + ((size_t)b * N_ + n) * 3;
    const float* pn = pts + ((size_t)b * N_ + nbr) * 3;
    pdif[w][0][l] = pq[0] - pn[0];
    pdif[w][1][l] = pq[1] - pn[1];
    pdif[w][2][l] = pq[2] - pn[2];
  }
  __syncthreads();

  {
    float p0 = pdif[w][0][n16], p1 = pdif[w][1][n16], p2 = pdif[w][2][n16];
    int c0 = q4 * 24;
#pragma unroll
    for (int ii = 0; ii < 24; ii += 2) {
      int c = c0 + ii;
      float vA = pw1[c * 3] * p0 + pw1[c * 3 + 1] * p1 + pw1[c * 3 + 2] * p2;
      float vB = pw1[(c + 1) * 3] * p0 + pw1[(c + 1) * 3 + 1] * p1 + pw1[(c + 1) * 3 + 2] * p2;
      vA = fmaxf(bn1(vA, pg[c], pb_[c], pm[c], pv[c]), 0.f);
      vB = fmaxf(bn1(vB, pg[c + 1], pb_[c + 1], pm[c + 1], pv[c + 1]), 0.f);
      unsigned u = (unsigned)f2h(vA) | ((unsigned)f2h(vB) << 16);
      *(unsigned*)&tw[n16 * TSTR + c] = u;
    }
  }
  __syncthreads();

  f32x4 pe2[6];
#pragma unroll
  for (int m = 0; m < 6; ++m) pe2[m] = (f32x4){0.f, 0.f, 0.f, 0.f};
  mfma_stage(WH, tw, n16, q4, pe2);
  __syncthreads();

  const int nbr = sid[w][n16];
  {
    const unsigned short* qt = QTh + (size_t)g * 96;
    const unsigned short* kt = KTh + ((size_t)b * N_ + nbr) * 96;
#pragma unroll
    for (int m = 0; m < 6; ++m) {
      int cb = m * 16 + q4 * 4;
      uint2 qu = *(const uint2*)&qt[cb];
      uint2 ku = *(const uint2*)&kt[cb];
      float v0 = h2f(qu.x & 0xffffu) - h2f(ku.x & 0xffffu) + pe2[m][0];
      float v1 = h2f(qu.x >> 16)     - h2f(ku.x >> 16)     + pe2[m][1];
      float v2 = h2f(qu.y & 0xffffu) - h2f(ku.y & 0xffffu) + pe2[m][2];
      float v3 = h2f(qu.y >> 16)     - h2f(ku.y >> 16)     + pe2[m][3];
      int idx = n16 * TSTR + cb;
      *(unsigned*)&tw[idx]     = (unsigned)f2h(v0) | ((unsigned)f2h(v1) << 16);
      *(unsigned*)&tw[idx + 2] = (unsigned)f2h(v2) | ((unsigned)f2h(v3) << 16);
    }
  }
  __syncthreads();

  {
    f32x4 t1[6];
#pragma unroll
    for (int m = 0; m < 6; ++m) t1[m] = (f32x4){0.f, 0.f, 0.f, 0.f};
    mfma_stage(WH + 9216, tw, n16, q4, t1);
    __syncthreads();
#pragma unroll
    for (int m = 0; m < 6; ++m) {
      int cb = m * 16 + q4 * 4;
      float v0 = fmaxf(bn1(t1[m][0], ag[cb], ab[cb], am[cb], av[cb]), 0.f);
      float v1 = fmaxf(bn1(t1[m][1], ag[cb + 1], ab[cb + 1], am[cb + 1], av[cb + 1]), 0.f);
      float v2 = fmaxf(bn1(t1[m][2], ag[cb + 2], ab[cb + 2], am[cb + 2], av[cb + 2]), 0.f);
      float v3 = fmaxf(bn1(t1[m][3], ag[cb + 3], ab[cb + 3], am[cb + 3], av[cb + 3]), 0.f);
      int idx = n16 * TSTR + cb;
      *(unsigned*)&tw[idx]     = (unsigned)f2h(v0) | ((unsigned)f2h(v1) << 16);
      *(unsigned*)&tw[idx + 2] = (unsigned)f2h(v2) | ((unsigned)f2h(v3) << 16);
    }
  }
  __syncthreads();

  {
    f32x4 a2[6];
#pragma unroll
    for (int m = 0; m < 6; ++m) a2[m] = (f32x4){0.f, 0.f, 0.f, 0.f};
    mfma_stage(WH + 18432, tw, n16, q4, a2);
    const unsigned short* vt = VTh + ((size_t)b * N_ + nbr) * 96;
#pragma unroll
    for (int m = 0; m < 6; ++m) {
      int cb = m * 16 + q4 * 4;
      uint2 vu = *(const uint2*)&vt[cb];
      float vvp[4];
      vvp[0] = h2f(vu.x & 0xffffu);
      vvp[1] = h2f(vu.x >> 16);
      vvp[2] = h2f(vu.y & 0xffffu);
      vvp[3] = h2f(vu.y >> 16);
      float ov[4];
#pragma unroll
      for (int r = 0; r < 4; ++r) {
        float a = a2[m][r];
        float mx = a;
        mx = fmaxf(mx, __shfl_xor(mx, 1));
        mx = fmaxf(mx, __shfl_xor(mx, 2));
        mx = fmaxf(mx, __shfl_xor(mx, 4));
        mx = fmaxf(mx, __shfl_xor(mx, 8));
        float e = expf(a - mx);
        float s = e;
        s += __shfl_xor(s, 1); s += __shfl_xor(s, 2); s += __shfl_xor(s, 4); s += __shfl_xor(s, 8);
        float c = e * (vvp[r] + pe2[m][r]);
        c += __shfl_xor(c, 1); c += __shfl_xor(c, 2); c += __shfl_xor(c, 4); c += __shfl_xor(c, 8);
        ov[r] = c / s;
      }
      if (n16 == 0) {
#pragma unroll
        for (int r = 0; r < 4; ++r) {
          int c = cb + r;
          size_t xi = ((size_t)b * D_ + c) * N_ + n;
          float t = X[xi] + ov[r];
          X[xi] = (t - m1[c]) * (g1[c] * (1.0f / sqrtf(v1[c] + EPS_))) + b1[c];
        }
      }
    }
  }
}

// ---------------- FFN: MFMA, 1 wave per 16 points, 4 waves/block (proven R14) ----------------
__global__ void __launch_bounds__(256) k_ffn(
    float* __restrict__ X, const unsigned short* __restrict__ WF,
    const float* __restrict__ fg, const float* __restrict__ fb,
    const float* __restrict__ fm, const float* __restrict__ fv,
    const float* __restrict__ g2, const float* __restrict__ b2,
    const float* __restrict__ m2, const float* __restrict__ v2) {
  __shared__ __align__(16) unsigned short t1s[4][16 * TSTR];   // x fp16: [pt][c]
  __shared__ __align__(16) unsigned short t2s[4][16 * T2STR];  // h fp16: [pt][j]
  const int tid = threadIdx.x;
  const int l = tid & 63, w = tid >> 6;
  const int n16 = l & 15, q4 = l >> 4;
  const int p0 = blockIdx.x * 64 + w * 16;
  const int b = p0 >> 13;
  const int nn = p0 & (N_ - 1);
  unsigned short* x1 = &t1s[w][0];
  unsigned short* h1 = &t2s[w][0];

  // phase 1: x tile -> fp16 LDS [point][channel]
  {
    const float* xb = X + (size_t)b * D_ * N_ + nn + n16;
    int c0 = q4 * 24;
#pragma unroll
    for (int i = 0; i < 24; ++i) {
      int c = c0 + i;
      x1[n16 * TSTR + c] = f2h(xb[(size_t)c * N_]);
    }
  }
  __syncthreads();

  // phase 2: h = relu(bn_f(W1 @ x))  (12 m-tiles x 3 k-steps) -> h tile
  {
    f32x4 acc[12];
#pragma unroll
    for (int m = 0; m < 12; ++m) acc[m] = (f32x4){0.f, 0.f, 0.f, 0.f};
    half8 bfr[3];
#pragma unroll
    for (int s = 0; s < 3; ++s) bfr[s] = *(const half8*)&x1[n16 * TSTR + s * 32 + q4 * 8];
#pragma unroll
    for (int m = 0; m < 12; ++m) {
#pragma unroll
      for (int s = 0; s < 3; ++s) {
        half8 av = *(const half8*)&WF[(m * 16 + n16) * 96 + s * 32 + q4 * 8];
        acc[m] = __builtin_amdgcn_mfma_f32_16x16x32_f16(av, bfr[s], acc[m], 0, 0, 0);
      }
    }
    __syncthreads();  // x tile fully consumed before h writes begin
#pragma unroll
    for (int m = 0; m < 12; ++m) {
      int jb = m * 16 + q4 * 4;
#pragma unroll
      for (int r = 0; r < 4; ++r) {
        int j = jb + r;
        float hv = fmaxf(bn1(acc[m][r], fg[j], fb[j], fm[j], fv[j]), 0.f);
        h1[n16 * T2STR + j] = f2h(hv);
      }
    }
  }
  __syncthreads();

  // phase 3: out = W2 @ h (6 m-tiles x 6 k-steps) ; residual + bn2 -> X
  {
    const unsigned short* W2h = WF + 18432;
    f32x4 acc[6];
#pragma unroll
    for (int m = 0; m < 6; ++m) acc[m] = (f32x4){0.f, 0.f, 0.f, 0.f};
    half8 bfr[6];
#pragma unroll
    for (int s = 0; s < 6; ++s) bfr[s] = *(const half8*)&h1[n16 * T2STR + s * 32 + q4 * 8];
#pragma unroll
    for (int m = 0; m < 6; ++m) {
#pragma unroll
      for (int s = 0; s < 6; ++s) {
        half8 av = *(const half8*)&W2h[(m * 16 + n16) * 192 + s * 32 + q4 * 8];
        acc[m] = __builtin_amdgcn_mfma_f32_16x16x32_f16(av, bfr[s], acc[m], 0, 0, 0);
      }
    }
#pragma unroll
    for (int m = 0; m < 6; ++m) {
      int cb = m * 16 + q4 * 4;
#pragma unroll
      for (int r = 0; r < 4; ++r) {
        int c = cb + r;
        size_t xi = ((size_t)b * D_ + c) * N_ + nn + n16;
        float t = X[xi] + acc[m][r];
        X[xi] = bn1(t, g2[c], b2[c], m2[c], v2[c]);
      }
    }
  }
}

// ---------------- head: proven baseline version ----------------
__global__ void k_head(const float* __restrict__ X, const float* __restrict__ w1,
                       const float* __restrict__ hg, const float* __restrict__ hbb,
                       const float* __restrict__ hm, const float* __restrict__ hv,
                       const float* __restrict__ w2, const float* __restrict__ hb2,
                       float* __restrict__ OUT) {
  int gid = blockIdx.x * 256 + threadIdx.x;
  int b = gid / N_, n = gid % N_;
  const float* xb = X + b * D_ * N_ + n;
  float xr[D_];
#pragma unroll
  for (int c = 0; c < D_; ++c) xr[c] = xb[c * N_];
  float a0 = 0.f, a1 = 0.f;
  for (int j = 0; j < 128; ++j) {
    float acc = 0.f;
#pragma unroll
    for (int c = 0; c < D_; ++c) acc += w1[j * D_ + c] * xr[c];
    float t = fmaxf(bn1(acc, hg[j], hbb[j], hm[j], hv[j]), 0.0f);
    a0 += w2[j] * t;
    a1 += w2[128 + j] * t;
  }
  OUT[(b * NC_ + 0) * N_ + n] = a0 + hb2[0];
  OUT[(b * NC_ + 1) * N_ + n] = a1 + hb2[1];
}

extern "C" void kernel_launch(void* const* d_in, const int* in_sizes, int n_in,
                              void* d_out, int out_size, void* d_ws, size_t ws_size,
                              hipStream_t stream) {
  (void)in_sizes; (void)n_in; (void)out_size;
  const float* pts     = (const float*)d_in[0];
  const float* embed_w = (const float*)d_in[1];
  const float* embed_g = (const float*)d_in[2];
  const float* embed_b = (const float*)d_in[3];
  const float* embed_m = (const float*)d_in[4];
  const float* embed_v = (const float*)d_in[5];
  const float* wq      = (const float*)d_in[6];
  const float* wk      = (const float*)d_in[7];
  const float* wv      = (const float*)d_in[8];
  const float* pe_w1   = (const float*)d_in[9];
  const float* pe_g    = (const float*)d_in[10];
  const float* pe_b    = (const float*)d_in[11];
  const float* pe_m    = (const float*)d_in[12];
  const float* pe_v    = (const float*)d_in[13];
  const float* pe_w2   = (const float*)d_in[14];
  const float* am_w1   = (const float*)d_in[15];
  const float* am_g    = (const float*)d_in[16];
  const float* am_b    = (const float*)d_in[17];
  const float* am_m    = (const float*)d_in[18];
  const float* am_v    = (const float*)d_in[19];
  const float* am_w2   = (const float*)d_in[20];
  const float* n1_g    = (const float*)d_in[21];
  const float* n1_b    = (const float*)d_in[22];
  const float* n1_m    = (const float*)d_in[23];
  const float* n1_v    = (const float*)d_in[24];
  const float* ffn_w1  = (const float*)d_in[25];
  const float* f_g     = (const float*)d_in[26];
  const float* f_b     = (const float*)d_in[27];
  const float* f_m     = (const float*)d_in[28];
  const float* f_v     = (const float*)d_in[29];
  const float* ffn_w2  = (const float*)d_in[30];
  const float* n2_g    = (const float*)d_in[31];
  const float* n2_b    = (const float*)d_in[32];
  const float* n2_m    = (const float*)d_in[33];
  const float* n2_v    = (const float*)d_in[34];
  const float* hd_w1   = (const float*)d_in[35];
  const float* hd_g    = (const float*)d_in[36];
  const float* hd_b    = (const float*)d_in[37];
  const float* hd_m    = (const float*)d_in[38];
  const float* hd_v    = (const float*)d_in[39];
  const float* hd_w2   = (const float*)d_in[40];
  const float* hd_b2   = (const float*)d_in[41];

  // ws layout (bytes, 16B-aligned, NO aliasing):
  //  X    fp32 B*D*N   @ 0           (6,291,456)
  //  QTh  fp16 B*N*D   @ 6,291,456   (3,145,728)
  //  KTh  fp16 B*N*D   @ 9,437,184   (3,145,728)
  //  VTh  fp16 B*N*D   @ 12,582,912  (3,145,728)
  //  P4   f4   B*N     @ 15,728,640  (  262,144)
  //  IDX  i32  B*N*K   @ 15,990,784  (1,048,576)
  //  WHa  fp16 L*3*D*D @ 17,039,360  (  221,184)
  //  WQa  fp16 L*3*D*D @ 17,260,544  (  221,184)
  //  WFa  fp16 L*2*H*D @ 17,481,728  (  294,912)
  //  total 17,776,640 B < 26,279,936 proven
  const size_t NEED = 17776640;
  if (ws_size < NEED) return;

  char* wsb = (char*)d_ws;
  float* X            = (float*)wsb;
  unsigned short* QTh = (unsigned short*)(wsb + 6291456);
  unsigned short* KTh = (unsigned short*)(wsb + 9437184);
  unsigned short* VTh = (unsigned short*)(wsb + 12582912);
  float4* P4          = (float4*)(wsb + 15728640);
  int* IDX            = (int*)(wsb + 15990784);
  unsigned short* WHa = (unsigned short*)(wsb + 17039360);
  unsigned short* WQa = (unsigned short*)(wsb + 17260544);
  unsigned short* WFa = (unsigned short*)(wsb + 17481728);

  k_prep_attn<<<144, 256, 0, stream>>>(pe_w2, am_w1, am_w2, WHa);
  k_prep_qkv<<<144, 256, 0, stream>>>(wq, wk, wv, WQa);
  k_prep_ffn<<<288, 256, 0, stream>>>(ffn_w1, ffn_w2, WFa);
  k_embed<<<B_ * N_ / 256, 256, 0, stream>>>(pts, embed_w, embed_g, embed_b, embed_m, embed_v, X, P4);
  k_knn<<<B_ * N_ / 4, 256, 0, stream>>>(P4, IDX);
  for (int l = 0; l < L_; ++l) {
    k_qkv<<<B_ * N_ / 64, 256, 0, stream>>>(X, WQa + l * 27648, QTh, KTh, VTh);
    k_attn<<<B_ * N_ / 4, 256, 0, stream>>>(X, QTh, KTh, VTh, pts, IDX,
        pe_w1 + l * D_ * 3, pe_g + l * D_, pe_b + l * D_, pe_m + l * D_, pe_v + l * D_,
        WHa + l * 27648,
        am_g + l * D_, am_b + l * D_, am_m + l * D_, am_v + l * D_,
        n1_g + l * D_, n1_b + l * D_, n1_m + l * D_, n1_v + l * D_);
    k_ffn<<<B_ * N_ / 64, 256, 0, stream>>>(X, WFa + l * 36864,
        f_g + l * H_, f_b + l * H_, f_m + l * H_, f_v + l * H_,
        n2_g + l * D_, n2_b + l * D_, n2_m + l * D_, n2_v + l * D_);
  }
  k_head<<<B_ * N_ / 256, 256, 0, stream>>>(X, hd_w1, hd_g, hd_b, hd_m, hd_v, hd_w2, hd_b2,
                                            (float*)d_out);
}

// Round 19
// 1179.086 us; speedup vs baseline: 3.2786x; 1.0091x over previous
//
#include <hip/hip_runtime.h>

#define B_ 2
#define N_ 8192
#define D_ 96
#define L_ 4
#define H_ 192
#define K_ 16
#define NC_ 2
#define EPS_ 1e-5f
#define BIGF 3.402823466e38f
#define TSTR 104   // padded LDS stride (fp16 elems) for 96-wide tiles — proven in R12
#define T2STR 200  // padded LDS stride for 192-wide h tile (~2-way conflicts, free)

typedef _Float16 half8 __attribute__((ext_vector_type(8)));
typedef float f32x4 __attribute__((ext_vector_type(4)));

__device__ __forceinline__ float bn1(float x, float g, float b, float m, float v) {
  return (x - m) * (g * (1.0f / sqrtf(v + EPS_))) + b;
}

__device__ __forceinline__ unsigned short f2h(float x) {
  union { _Float16 h; unsigned short u; } c;
  c.h = (_Float16)x;
  return c.u;
}

__device__ __forceinline__ float h2f(unsigned u16) {
  union { _Float16 h; unsigned short u; } c;
  c.u = (unsigned short)u16;
  return (float)c.h;
}

// ---------------- embed + packed candidate data (xyz + squared norm) ----------
__global__ void k_embed(const float* __restrict__ pts, const float* __restrict__ w,
                        const float* __restrict__ g, const float* __restrict__ bb,
                        const float* __restrict__ m, const float* __restrict__ v,
                        float* __restrict__ X, float4* __restrict__ P4) {
  int gid = blockIdx.x * 256 + threadIdx.x;
  int b = gid / N_, n = gid % N_;
  float p0 = pts[gid * 3], p1 = pts[gid * 3 + 1], p2 = pts[gid * 3 + 2];
  // exact numpy-order fp32 arithmetic (feeds KNN selection)
  float sq = __fadd_rn(__fadd_rn(__fmul_rn(p0, p0), __fmul_rn(p1, p1)), __fmul_rn(p2, p2));
  P4[gid] = make_float4(p0, p1, p2, sq);
  for (int o = 0; o < D_; ++o) {
    float e = w[o * 3] * p0 + w[o * 3 + 1] * p1 + w[o * 3 + 2] * p2;
    X[(b * D_ + o) * N_ + n] = fmaxf(bn1(e, g[o], bb[o], m[o], v[o]), 0.0f);
  }
}

// ---------------- KNN v5: v4 structure with 4 independent chains per iteration -------------
// T (6 branchless shfls): group-of-4 min then max over 16 groups. The 16 group minima are
// 16 DISTINCT candidates <= T  =>  T >= true 16th-smallest distance  =>  gate is lossless.
// Fast path appends survivors (<=8/lane, mean ~0.85); wave-uniform overflow check falls back
// to the proven exact insertion network.  Both paths feed the proven 16-round merge.
__global__ void k_knn(const float4* __restrict__ P4, int* __restrict__ IDX) {
  int lane = threadIdx.x & 63;
  int g = blockIdx.x * 4 + (threadIdx.x >> 6);
  int b = g / N_, n = g % N_;
  const float4* Pb = P4 + (size_t)b * N_;
  float4 qp = Pb[n];
  const float qx = qp.x, qy = qp.y, qz = qp.z, sqn = qp.w;

  // pass 1: branchless per-lane running min, 4 independent chains per iteration
  float lmin = BIGF;
  for (int j = 0; j < N_ / 64; j += 4) {
    float4 c0 = Pb[lane + (j + 0) * 64];
    float4 c1 = Pb[lane + (j + 1) * 64];
    float4 c2 = Pb[lane + (j + 2) * 64];
    float4 c3 = Pb[lane + (j + 3) * 64];
    float dot0 = __fadd_rn(__fadd_rn(__fmul_rn(qx, c0.x), __fmul_rn(qy, c0.y)), __fmul_rn(qz, c0.z));
    float dot1 = __fadd_rn(__fadd_rn(__fmul_rn(qx, c1.x), __fmul_rn(qy, c1.y)), __fmul_rn(qz, c1.z));
    float dot2 = __fadd_rn(__fadd_rn(__fmul_rn(qx, c2.x), __fmul_rn(qy, c2.y)), __fmul_rn(qz, c2.z));
    float dot3 = __fadd_rn(__fadd_rn(__fmul_rn(qx, c3.x), __fmul_rn(qy, c3.y)), __fmul_rn(qz, c3.z));
    float d0 = __fsub_rn(__fadd_rn(sqn, c0.w), __fmul_rn(2.0f, dot0));
    float d1 = __fsub_rn(__fadd_rn(sqn, c1.w), __fmul_rn(2.0f, dot1));
    float d2 = __fsub_rn(__fadd_rn(sqn, c2.w), __fmul_rn(2.0f, dot2));
    float d3 = __fsub_rn(__fadd_rn(sqn, c3.w), __fmul_rn(2.0f, dot3));
    lmin = fminf(lmin, fminf(fminf(d0, d1), fminf(d2, d3)));
  }
  // group-of-4 min, then max across the 16 groups -> lossless threshold T
  float gm = fminf(lmin, __shfl_xor(lmin, 1));
  gm = fminf(gm, __shfl_xor(gm, 2));
  float T = gm;
  T = fmaxf(T, __shfl_xor(T, 4));
  T = fmaxf(T, __shfl_xor(T, 8));
  T = fmaxf(T, __shfl_xor(T, 16));
  T = fmaxf(T, __shfl_xor(T, 32));

  float bd[K_]; int bi[K_];
#pragma unroll
  for (int s = 0; s < K_; ++s) { bd[s] = BIGF; bi[s] = 0x7fffffff; }

  // pass 2 fast path: append survivors (d <= T) into 8 static slots, count them all
  float sd[8]; int si[8];
#pragma unroll
  for (int s = 0; s < 8; ++s) { sd[s] = BIGF; si[s] = 0x7fffffff; }
  int cnt = 0;
  for (int j = 0; j < N_ / 64; j += 4) {
    int cand0 = lane + (j + 0) * 64;
    int cand1 = lane + (j + 1) * 64;
    int cand2 = lane + (j + 2) * 64;
    int cand3 = lane + (j + 3) * 64;
    float4 c0 = Pb[cand0];
    float4 c1 = Pb[cand1];
    float4 c2 = Pb[cand2];
    float4 c3 = Pb[cand3];
    float dot0 = __fadd_rn(__fadd_rn(__fmul_rn(qx, c0.x), __fmul_rn(qy, c0.y)), __fmul_rn(qz, c0.z));
    float dot1 = __fadd_rn(__fadd_rn(__fmul_rn(qx, c1.x), __fmul_rn(qy, c1.y)), __fmul_rn(qz, c1.z));
    float dot2 = __fadd_rn(__fadd_rn(__fmul_rn(qx, c2.x), __fmul_rn(qy, c2.y)), __fmul_rn(qz, c2.z));
    float dot3 = __fadd_rn(__fadd_rn(__fmul_rn(qx, c3.x), __fmul_rn(qy, c3.y)), __fmul_rn(qz, c3.z));
    float d0 = __fsub_rn(__fadd_rn(sqn, c0.w), __fmul_rn(2.0f, dot0));
    float d1 = __fsub_rn(__fadd_rn(sqn, c1.w), __fmul_rn(2.0f, dot1));
    float d2 = __fsub_rn(__fadd_rn(sqn, c2.w), __fmul_rn(2.0f, dot2));
    float d3 = __fsub_rn(__fadd_rn(sqn, c3.w), __fmul_rn(2.0f, dot3));
    if (d0 <= T) {
#pragma unroll
      for (int s = 0; s < 8; ++s) if (cnt == s) { sd[s] = d0; si[s] = cand0; }
      ++cnt;
    }
    if (d1 <= T) {
#pragma unroll
      for (int s = 0; s < 8; ++s) if (cnt == s) { sd[s] = d1; si[s] = cand1; }
      ++cnt;
    }
    if (d2 <= T) {
#pragma unroll
      for (int s = 0; s < 8; ++s) if (cnt == s) { sd[s] = d2; si[s] = cand2; }
      ++cnt;
    }
    if (d3 <= T) {
#pragma unroll
      for (int s = 0; s < 8; ++s) if (cnt == s) { sd[s] = d3; si[s] = cand3; }
      ++cnt;
    }
  }

  if (!__any(cnt > 8)) {
    // all survivors captured: move into merge slots 0..7
#pragma unroll
    for (int s = 0; s < 8; ++s) { bd[s] = sd[s]; bi[s] = si[s]; }
  } else {
    // rare exact fallback: proven 16-deep insertion network gated on d <= T
    float wd = BIGF; int wi = 0x7fffffff; int wslot = 0;
    for (int j = 0; j < N_ / 64; ++j) {
      int cand = lane + j * 64;
      float4 cp = Pb[cand];
      float dot = __fadd_rn(__fadd_rn(__fmul_rn(qx, cp.x), __fmul_rn(qy, cp.y)), __fmul_rn(qz, cp.z));
      float d = __fsub_rn(__fadd_rn(sqn, cp.w), __fmul_rn(2.0f, dot));
      if (d <= T && (d < wd || (d == wd && cand < wi))) {
#pragma unroll
        for (int s = 0; s < K_; ++s) if (s == wslot) { bd[s] = d; bi[s] = cand; }
        wd = -BIGF; wi = -1;
#pragma unroll
        for (int s = 0; s < K_; ++s) {
          bool worse = (bd[s] > wd) || (bd[s] == wd && bi[s] > wi);
          if (worse) { wd = bd[s]; wi = bi[s]; wslot = s; }
        }
      }
    }
  }

  // merge 64 lanes' candidates -> global top-16 (byte-identical to proven R1 merge)
  for (int r = 0; r < K_; ++r) {
    float md = BIGF; int mi = 0x7fffffff;
#pragma unroll
    for (int s = 0; s < K_; ++s) {
      bool better = (bd[s] < md) || (bd[s] == md && bi[s] < mi);
      if (better) { md = bd[s]; mi = bi[s]; }
    }
#pragma unroll
    for (int off = 32; off > 0; off >>= 1) {
      float od = __shfl_xor(md, off);
      int oi = __shfl_xor(mi, off);
      bool better = (od < md) || (od == md && oi < mi);
      if (better) { md = od; mi = oi; }
    }
#pragma unroll
    for (int s = 0; s < K_; ++s) if (bi[s] == mi) { bd[s] = BIGF; bi[s] = 0x7fffffff; }
    if (lane == 0) IDX[g * K_ + r] = mi;
  }
}

// ---------------- one-shot weight prep: all layers fp32 -> fp16 (dedicated regions) --------
__global__ void k_prep_attn(const float* __restrict__ pw2, const float* __restrict__ aw1,
                            const float* __restrict__ aw2, unsigned short* __restrict__ WHa) {
  int i = blockIdx.x * 256 + threadIdx.x;  // L*9216 = 36864; grid 144
  int l = i / 9216, r = i - l * 9216;
  WHa[l * 27648 + r]         = f2h(pw2[i]);
  WHa[l * 27648 + 9216 + r]  = f2h(aw1[i]);
  WHa[l * 27648 + 18432 + r] = f2h(aw2[i]);
}

__global__ void k_prep_qkv(const float* __restrict__ wq, const float* __restrict__ wk,
                           const float* __restrict__ wv, unsigned short* __restrict__ WQa) {
  int i = blockIdx.x * 256 + threadIdx.x;  // L*9216 = 36864; grid 144
  int l = i / 9216, r = i - l * 9216;
  WQa[l * 27648 + r]         = f2h(wq[i]);
  WQa[l * 27648 + 9216 + r]  = f2h(wk[i]);
  WQa[l * 27648 + 18432 + r] = f2h(wv[i]);
}

__global__ void k_prep_ffn(const float* __restrict__ w1, const float* __restrict__ w2,
                           unsigned short* __restrict__ WFa) {
  int i = blockIdx.x * 256 + threadIdx.x;  // L*18432 = 73728; grid 288
  int l = i / 18432, r = i - l * 18432;
  WFa[l * 36864 + r]         = f2h(w1[i]);
  WFa[l * 36864 + 18432 + r] = f2h(w2[i]);
}

// ---------------- QKV: MFMA, 1 wave per 16 points, fp16 outputs ----------------
__global__ void __launch_bounds__(256) k_qkv(const float* __restrict__ X,
                      const unsigned short* __restrict__ WQ,  // [3][9216] fp16
                      unsigned short* __restrict__ QTh, unsigned short* __restrict__ KTh,
                      unsigned short* __restrict__ VTh) {
  __shared__ __align__(16) unsigned short t1s[4][16 * TSTR];
  const int tid = threadIdx.x;
  const int l = tid & 63, w = tid >> 6;
  const int n16 = l & 15, q4 = l >> 4;
  const int p0 = blockIdx.x * 64 + w * 16;
  const int b = p0 >> 13;
  const int nn = p0 & (N_ - 1);
  unsigned short* x1 = &t1s[w][0];

  // phase 1: x tile -> fp16 LDS [point][channel]
  {
    const float* xb = X + (size_t)b * D_ * N_ + nn + n16;
    int c0 = q4 * 24;
#pragma unroll
    for (int i = 0; i < 24; ++i) {
      int c = c0 + i;
      x1[n16 * TSTR + c] = f2h(xb[(size_t)c * N_]);
    }
  }
  __syncthreads();

  half8 bfr[3];
#pragma unroll
  for (int s = 0; s < 3; ++s) bfr[s] = *(const half8*)&x1[n16 * TSTR + s * 32 + q4 * 8];
  unsigned short* Os[3] = {QTh, KTh, VTh};
#pragma unroll
  for (int t = 0; t < 3; ++t) {
    f32x4 acc[6];
#pragma unroll
    for (int m = 0; m < 6; ++m) acc[m] = (f32x4){0.f, 0.f, 0.f, 0.f};
    const unsigned short* Wt = WQ + t * 9216;
#pragma unroll
    for (int m = 0; m < 6; ++m) {
#pragma unroll
      for (int s = 0; s < 3; ++s) {
        half8 av = *(const half8*)&Wt[(m * 16 + n16) * 96 + s * 32 + q4 * 8];
        acc[m] = __builtin_amdgcn_mfma_f32_16x16x32_f16(av, bfr[s], acc[m], 0, 0, 0);
      }
    }
    unsigned short* op = Os[t] + (size_t)(p0 + n16) * 96;
#pragma unroll
    for (int m = 0; m < 6; ++m) {
      int cb = m * 16 + q4 * 4;
      uint2 u;
      u.x = (unsigned)f2h(acc[m][0]) | ((unsigned)f2h(acc[m][1]) << 16);
      u.y = (unsigned)f2h(acc[m][2]) | ((unsigned)f2h(acc[m][3]) << 16);
      *(uint2*)&op[cb] = u;
    }
  }
}

// W(16x32 rows of m-tile) @ Act(32x16) over 3 K-steps, 6 m-tiles; fp16 in, fp32 out.
// A frag: row = lane&15, k = s*32 + (lane>>4)*8 + j   (row-major fp16 W, stride 96)
// B frag: col(slot) = lane&15, k likewise; tile stored [slot][k], stride TSTR
// D frag: col(slot) = lane&15, row(channel) = m*16 + (lane>>4)*4 + r
__device__ __forceinline__ void mfma_stage(const unsigned short* __restrict__ Wh,
                                           const unsigned short* tw,
                                           int n16, int q4, f32x4 acc[6]) {
  half8 bfr[3];
#pragma unroll
  for (int s = 0; s < 3; ++s)
    bfr[s] = *(const half8*)&tw[n16 * TSTR + s * 32 + q4 * 8];
#pragma unroll
  for (int m = 0; m < 6; ++m) {
#pragma unroll
    for (int s = 0; s < 3; ++s) {
      half8 av = *(const half8*)&Wh[(m * 16 + n16) * 96 + s * 32 + q4 * 8];
      acc[m] = __builtin_amdgcn_mfma_f32_16x16x32_f16(av, bfr[s], acc[m], 0, 0, 0);
    }
  }
}

// ---------------- fused attention: 1 wave per point, 4 points/block, MFMA, fp16 Q/K/V --------
__global__ void __launch_bounds__(256) k_attn(
    float* __restrict__ X, const unsigned short* __restrict__ QTh,
    const unsigned short* __restrict__ KTh, const unsigned short* __restrict__ VTh,
    const float* __restrict__ pts, const int* __restrict__ IDX,
    const float* __restrict__ pw1, const float* __restrict__ pg, const float* __restrict__ pb_,
    const float* __restrict__ pm, const float* __restrict__ pv,
    const unsigned short* __restrict__ WH,
    const float* __restrict__ ag, const float* __restrict__ ab,
    const float* __restrict__ am, const float* __restrict__ av,
    const float* __restrict__ g1, const float* __restrict__ b1,
    const float* __restrict__ m1, const float* __restrict__ v1) {
  __shared__ __align__(16) unsigned short tile[4][16 * TSTR];
  __shared__ float pdif[4][3][16];
  __shared__ int sid[4][16];
  const int tid = threadIdx.x;
  const int l = tid & 63, w = tid >> 6;
  const int g = blockIdx.x * 4 + w;
  const int b = g >> 13, n = g & (N_ - 1);
  const int n16 = l & 15, q4 = l >> 4;
  unsigned short* tw = &tile[w][0];

  if (l < 16) {
    int nbr = IDX[g * K_ + l];
    sid[w][l] = nbr;
    const float* pq = pts + ((size_t)b * N_ + n) * 3;
    const float* pn = pts + ((size_t)b * N_ + nbr) * 3;
    pdif[w][0][l] = pq[0] - pn[0];
    pdif[w][1][l] = pq[1] - pn[1];
    pdif[w][2][l] = pq[2] - pn[2];
  }
  __syncthreads();

  {
    float p0 = pdif[w][0][n16], p1 = pdif[w][1][n16], p2 = pdif[w][2][n16];
    int c0 = q4 * 24;
#pragma unroll
    for (int ii = 0; ii < 24; ii += 2) {
      int c = c0 + ii;
      float vA = pw1[c * 3] * p0 + pw1[c * 3 + 1] * p1 + pw1[c * 3 + 2] * p2;
      float vB = pw1[(c + 1) * 3] * p0 + pw1[(c + 1) * 3 + 1] * p1 + pw1[(c + 1) * 3 + 2] * p2;
      vA = fmaxf(bn1(vA, pg[c], pb_[c], pm[c], pv[c]), 0.f);
      vB = fmaxf(bn1(vB, pg[c + 1], pb_[c + 1], pm[c + 1], pv[c + 1]), 0.f);
      unsigned u = (unsigned)f2h(vA) | ((unsigned)f2h(vB) << 16);
      *(unsigned*)&tw[n16 * TSTR + c] = u;
    }
  }
  __syncthreads();

  f32x4 pe2[6];
#pragma unroll
  for (int m = 0; m < 6; ++m) pe2[m] = (f32x4){0.f, 0.f, 0.f, 0.f};
  mfma_stage(WH, tw, n16, q4, pe2);
  __syncthreads();

  const int nbr = sid[w][n16];
  {
    const unsigned short* qt = QTh + (size_t)g * 96;
    const unsigned short* kt = KTh + ((size_t)b * N_ + nbr) * 96;
#pragma unroll
    for (int m = 0; m < 6; ++m) {
      int cb = m * 16 + q4 * 4;
      uint2 qu = *(const uint2*)&qt[cb];
      uint2 ku = *(const uint2*)&kt[cb];
      float v0 = h2f(qu.x & 0xffffu) - h2f(ku.x & 0xffffu) + pe2[m][0];
      float v1 = h2f(qu.x >> 16)     - h2f(ku.x >> 16)     + pe2[m][1];
      float v2 = h2f(qu.y & 0xffffu) - h2f(ku.y & 0xffffu) + pe2[m][2];
      float v3 = h2f(qu.y >> 16)     - h2f(ku.y >> 16)     + pe2[m][3];
      int idx = n16 * TSTR + cb;
      *(unsigned*)&tw[idx]     = (unsigned)f2h(v0) | ((unsigned)f2h(v1) << 16);
      *(unsigned*)&tw[idx + 2] = (unsigned)f2h(v2) | ((unsigned)f2h(v3) << 16);
    }
  }
  __syncthreads();

  {
    f32x4 t1[6];
#pragma unroll
    for (int m = 0; m < 6; ++m) t1[m] = (f32x4){0.f, 0.f, 0.f, 0.f};
    mfma_stage(WH + 9216, tw, n16, q4, t1);
    __syncthreads();
#pragma unroll
    for (int m = 0; m < 6; ++m) {
      int cb = m * 16 + q4 * 4;
      float v0 = fmaxf(bn1(t1[m][0], ag[cb], ab[cb], am[cb], av[cb]), 0.f);
      float v1 = fmaxf(bn1(t1[m][1], ag[cb + 1], ab[cb + 1], am[cb + 1], av[cb + 1]), 0.f);
      float v2 = fmaxf(bn1(t1[m][2], ag[cb + 2], ab[cb + 2], am[cb + 2], av[cb + 2]), 0.f);
      float v3 = fmaxf(bn1(t1[m][3], ag[cb + 3], ab[cb + 3], am[cb + 3], av[cb + 3]), 0.f);
      int idx = n16 * TSTR + cb;
      *(unsigned*)&tw[idx]     = (unsigned)f2h(v0) | ((unsigned)f2h(v1) << 16);
      *(unsigned*)&tw[idx + 2] = (unsigned)f2h(v2) | ((unsigned)f2h(v3) << 16);
    }
  }
  __syncthreads();

  {
    f32x4 a2[6];
#pragma unroll
    for (int m = 0; m < 6; ++m) a2[m] = (f32x4){0.f, 0.f, 0.f, 0.f};
    mfma_stage(WH + 18432, tw, n16, q4, a2);
    const unsigned short* vt = VTh + ((size_t)b * N_ + nbr) * 96;
#pragma unroll
    for (int m = 0; m < 6; ++m) {
      int cb = m * 16 + q4 * 4;
      uint2 vu = *(const uint2*)&vt[cb];
      float vvp[4];
      vvp[0] = h2f(vu.x & 0xffffu);
      vvp[1] = h2f(vu.x >> 16);
      vvp[2] = h2f(vu.y & 0xffffu);
      vvp[3] = h2f(vu.y >> 16);
      float ov[4];
#pragma unroll
      for (int r = 0; r < 4; ++r) {
        float a = a2[m][r];
        float mx = a;
        mx = fmaxf(mx, __shfl_xor(mx, 1));
        mx = fmaxf(mx, __shfl_xor(mx, 2));
        mx = fmaxf(mx, __shfl_xor(mx, 4));
        mx = fmaxf(mx, __shfl_xor(mx, 8));
        float e = expf(a - mx);
        float s = e;
        s += __shfl_xor(s, 1); s += __shfl_xor(s, 2); s += __shfl_xor(s, 4); s += __shfl_xor(s, 8);
        float c = e * (vvp[r] + pe2[m][r]);
        c += __shfl_xor(c, 1); c += __shfl_xor(c, 2); c += __shfl_xor(c, 4); c += __shfl_xor(c, 8);
        ov[r] = c / s;
      }
      if (n16 == 0) {
#pragma unroll
        for (int r = 0; r < 4; ++r) {
          int c = cb + r;
          size_t xi = ((size_t)b * D_ + c) * N_ + n;
          float t = X[xi] + ov[r];
          X[xi] = (t - m1[c]) * (g1[c] * (1.0f / sqrtf(v1[c] + EPS_))) + b1[c];
        }
      }
    }
  }
}

// ---------------- FFN: MFMA, 1 wave per 16 points, 4 waves/block (proven R14) ----------------
__global__ void __launch_bounds__(256) k_ffn(
    float* __restrict__ X, const unsigned short* __restrict__ WF,
    const float* __restrict__ fg, const float* __restrict__ fb,
    const float* __restrict__ fm, const float* __restrict__ fv,
    const float* __restrict__ g2, const float* __restrict__ b2,
    const float* __restrict__ m2, const float* __restrict__ v2) {
  __shared__ __align__(16) unsigned short t1s[4][16 * TSTR];   // x fp16: [pt][c]
  __shared__ __align__(16) unsigned short t2s[4][16 * T2STR];  // h fp16: [pt][j]
  const int tid = threadIdx.x;
  const int l = tid & 63, w = tid >> 6;
  const int n16 = l & 15, q4 = l >> 4;
  const int p0 = blockIdx.x * 64 + w * 16;
  const int b = p0 >> 13;
  const int nn = p0 & (N_ - 1);
  unsigned short* x1 = &t1s[w][0];
  unsigned short* h1 = &t2s[w][0];

  // phase 1: x tile -> fp16 LDS [point][channel]
  {
    const float* xb = X + (size_t)b * D_ * N_ + nn + n16;
    int c0 = q4 * 24;
#pragma unroll
    for (int i = 0; i < 24; ++i) {
      int c = c0 + i;
      x1[n16 * TSTR + c] = f2h(xb[(size_t)c * N_]);
    }
  }
  __syncthreads();

  // phase 2: h = relu(bn_f(W1 @ x))  (12 m-tiles x 3 k-steps) -> h tile
  {
    f32x4 acc[12];
#pragma unroll
    for (int m = 0; m < 12; ++m) acc[m] = (f32x4){0.f, 0.f, 0.f, 0.f};
    half8 bfr[3];
#pragma unroll
    for (int s = 0; s < 3; ++s) bfr[s] = *(const half8*)&x1[n16 * TSTR + s * 32 + q4 * 8];
#pragma unroll
    for (int m = 0; m < 12; ++m) {
#pragma unroll
      for (int s = 0; s < 3; ++s) {
        half8 av = *(const half8*)&WF[(m * 16 + n16) * 96 + s * 32 + q4 * 8];
        acc[m] = __builtin_amdgcn_mfma_f32_16x16x32_f16(av, bfr[s], acc[m], 0, 0, 0);
      }
    }
    __syncthreads();  // x tile fully consumed before h writes begin
#pragma unroll
    for (int m = 0; m < 12; ++m) {
      int jb = m * 16 + q4 * 4;
#pragma unroll
      for (int r = 0; r < 4; ++r) {
        int j = jb + r;
        float hv = fmaxf(bn1(acc[m][r], fg[j], fb[j], fm[j], fv[j]), 0.f);
        h1[n16 * T2STR + j] = f2h(hv);
      }
    }
  }
  __syncthreads();

  // phase 3: out = W2 @ h (6 m-tiles x 6 k-steps) ; residual + bn2 -> X
  {
    const unsigned short* W2h = WF + 18432;
    f32x4 acc[6];
#pragma unroll
    for (int m = 0; m < 6; ++m) acc[m] = (f32x4){0.f, 0.f, 0.f, 0.f};
    half8 bfr[6];
#pragma unroll
    for (int s = 0; s < 6; ++s) bfr[s] = *(const half8*)&h1[n16 * T2STR + s * 32 + q4 * 8];
#pragma unroll
    for (int m = 0; m < 6; ++m) {
#pragma unroll
      for (int s = 0; s < 6; ++s) {
        half8 av = *(const half8*)&W2h[(m * 16 + n16) * 192 + s * 32 + q4 * 8];
        acc[m] = __builtin_amdgcn_mfma_f32_16x16x32_f16(av, bfr[s], acc[m], 0, 0, 0);
      }
    }
#pragma unroll
    for (int m = 0; m < 6; ++m) {
      int cb = m * 16 + q4 * 4;
#pragma unroll
      for (int r = 0; r < 4; ++r) {
        int c = cb + r;
        size_t xi = ((size_t)b * D_ + c) * N_ + nn + n16;
        float t = X[xi] + acc[m][r];
        X[xi] = bn1(t, g2[c], b2[c], m2[c], v2[c]);
      }
    }
  }
}

// ---------------- head: proven baseline version ----------------
__global__ void k_head(const float* __restrict__ X, const float* __restrict__ w1,
                       const float* __restrict__ hg, const float* __restrict__ hbb,
                       const float* __restrict__ hm, const float* __restrict__ hv,
                       const float* __restrict__ w2, const float* __restrict__ hb2,
                       float* __restrict__ OUT) {
  int gid = blockIdx.x * 256 + threadIdx.x;
  int b = gid / N_, n = gid % N_;
  const float* xb = X + b * D_ * N_ + n;
  float xr[D_];
#pragma unroll
  for (int c = 0; c < D_; ++c) xr[c] = xb[c * N_];
  float a0 = 0.f, a1 = 0.f;
  for (int j = 0; j < 128; ++j) {
    float acc = 0.f;
#pragma unroll
    for (int c = 0; c < D_; ++c) acc += w1[j * D_ + c] * xr[c];
    float t = fmaxf(bn1(acc, hg[j], hbb[j], hm[j], hv[j]), 0.0f);
    a0 += w2[j] * t;
    a1 += w2[128 + j] * t;
  }
  OUT[(b * NC_ + 0) * N_ + n] = a0 + hb2[0];
  OUT[(b * NC_ + 1) * N_ + n] = a1 + hb2[1];
}

extern "C" void kernel_launch(void* const* d_in, const int* in_sizes, int n_in,
                              void* d_out, int out_size, void* d_ws, size_t ws_size,
                              hipStream_t stream) {
  (void)in_sizes; (void)n_in; (void)out_size;
  const float* pts     = (const float*)d_in[0];
  const float* embed_w = (const float*)d_in[1];
  const float* embed_g = (const float*)d_in[2];
  const float* embed_b = (const float*)d_in[3];
  const float* embed_m = (const float*)d_in[4];
  const float* embed_v = (const float*)d_in[5];
  const float* wq      = (const float*)d_in[6];
  const float* wk      = (const float*)d_in[7];
  const float* wv      = (const float*)d_in[8];
  const float* pe_w1   = (const float*)d_in[9];
  const float* pe_g    = (const float*)d_in[10];
  const float* pe_b    = (const float*)d_in[11];
  const float* pe_m    = (const float*)d_in[12];
  const float* pe_v    = (const float*)d_in[13];
  const float* pe_w2   = (const float*)d_in[14];
  const float* am_w1   = (const float*)d_in[15];
  const float* am_g    = (const float*)d_in[16];
  const float* am_b    = (const float*)d_in[17];
  const float* am_m    = (const float*)d_in[18];
  const float* am_v    = (const float*)d_in[19];
  const float* am_w2   = (const float*)d_in[20];
  const float* n1_g    = (const float*)d_in[21];
  const float* n1_b    = (const float*)d_in[22];
  const float* n1_m    = (const float*)d_in[23];
  const float* n1_v    = (const float*)d_in[24];
  const float* ffn_w1  = (const float*)d_in[25];
  const float* f_g     = (const float*)d_in[26];
  const float* f_b     = (const float*)d_in[27];
  const float* f_m     = (const float*)d_in[28];
  const float* f_v     = (const float*)d_in[29];
  const float* ffn_w2  = (const float*)d_in[30];
  const float* n2_g    = (const float*)d_in[31];
  const float* n2_b    = (const float*)d_in[32];
  const float* n2_m    = (const float*)d_in[33];
  const float* n2_v    = (const float*)d_in[34];
  const float* hd_w1   = (const float*)d_in[35];
  const float* hd_g    = (const float*)d_in[36];
  const float* hd_b    = (const float*)d_in[37];
  const float* hd_m    = (const float*)d_in[38];
  const float* hd_v    = (const float*)d_in[39];
  const float* hd_w2   = (const float*)d_in[40];
  const float* hd_b2   = (const float*)d_in[41];

  // ws layout (bytes, 16B-aligned, NO aliasing):
  //  X    fp32 B*D*N   @ 0           (6,291,456)
  //  QTh  fp16 B*N*D   @ 6,291,456   (3,145,728)
  //  KTh  fp16 B*N*D   @ 9,437,184   (3,145,728)
  //  VTh  fp16 B*N*D   @ 12,582,912  (3,145,728)
  //  P4   f4   B*N     @ 15,728,640  (  262,144)
  //  IDX  i32  B*N*K   @ 15,990,784  (1,048,576)
  //  WHa  fp16 L*3*D*D @ 17,039,360  (  221,184)
  //  WQa  fp16 L*3*D*D @ 17,260,544  (  221,184)
  //  WFa  fp16 L*2*H*D @ 17,481,728  (  294,912)
  //  total 17,776,640 B < 26,279,936 proven
  const size_t NEED = 17776640;
  if (ws_size < NEED) return;

  char* wsb = (char*)d_ws;
  float* X            = (float*)wsb;
  unsigned short* QTh = (unsigned short*)(wsb + 6291456);
  unsigned short* KTh = (unsigned short*)(wsb + 9437184);
  unsigned short* VTh = (unsigned short*)(wsb + 12582912);
  float4* P4          = (float4*)(wsb + 15728640);
  int* IDX            = (int*)(wsb + 15990784);
  unsigned short* WHa = (unsigned short*)(wsb + 17039360);
  unsigned short* WQa = (unsigned short*)(wsb + 17260544);
  unsigned short* WFa = (unsigned short*)(wsb + 17481728);

  k_prep_attn<<<144, 256, 0, stream>>>(pe_w2, am_w1, am_w2, WHa);
  k_prep_qkv<<<144, 256, 0, stream>>>(wq, wk, wv, WQa);
  k_prep_ffn<<<288, 256, 0, stream>>>(ffn_w1, ffn_w2, WFa);
  k_embed<<<B_ * N_ / 256, 256, 0, stream>>>(pts, embed_w, embed_g, embed_b, embed_m, embed_v, X, P4);
  k_knn<<<B_ * N_ / 4, 256, 0, stream>>>(P4, IDX);
  for (int l = 0; l < L_; ++l) {
    k_qkv<<<B_ * N_ / 64, 256, 0, stream>>>(X, WQa + l * 27648, QTh, KTh, VTh);
    k_attn<<<B_ * N_ / 4, 256, 0, stream>>>(X, QTh, KTh, VTh, pts, IDX,
        pe_w1 + l * D_ * 3, pe_g + l * D_, pe_b + l * D_, pe_m + l * D_, pe_v + l * D_,
        WHa + l * 27648,
        am_g + l * D_, am_b + l * D_, am_m + l * D_, am_v + l * D_,
        n1_g + l * D_, n1_b + l * D_, n1_m + l * D_, n1_v + l * D_);
    k_ffn<<<B_ * N_ / 64, 256, 0, stream>>>(X, WFa + l * 36864,
        f_g + l * H_, f_b + l * H_, f_m + l * H_, f_v + l * H_,
        n2_g + l * D_, n2_b + l * D_, n2_m + l * D_, n2_v + l * D_);
  }
  k_head<<<B_ * N_ / 256, 256, 0, stream>>>(X, hd_w1, hd_g, hd_b, hd_m, hd_v, hd_w2, hd_b2,
                                            (float*)d_out);
}